// Round 6
// baseline (512.138 us; speedup 1.0000x reference)
//
#include <hip/hip_runtime.h>
#include <hip/hip_bf16.h>
#include <stdint.h>

// ============================================================================
// MultiAttentionWithGating — compression branch (_kc/_vc) is DEAD CODE.
// Pipeline: qkv = x@W_attn^T ; causal SDPA (16 heads, hs=64) ; out = y@W_proj^T
// Inputs fp32 (runtime-probed); internal bf16 MFMA, fp32 accum.
//
// ROUND 12 (QKV gemm 92us = 560 TF stuck at the documented m97-structure
// ceiling; 2-phase dbuf only bought 8%):
//  - gemm8_qkv: 8-phase 256x256 template (T3+T4+T2+T5). BK=64, 512 thr,
//    8 waves (2Mx4N), LDS 128KiB [dbuf][khalf][256][32]. Per phase:
//    ds_read frags | stage 1 half-tile | barrier | lgkmcnt(0) | setprio(1)
//    16 MFMA | setprio(0) | barrier. vmcnt(6) ONLY at K-tile boundaries
//    (3 half-tiles in flight, never drain-0 mid-loop). Issue schedule
//    race-free vs region reads: B1(t+1)@ph1, A0/B0/A1(t+2)@ph2/3/4.
//  - LDS swizzle: 16B-slot XOR (q ^= (row>>1)&3), pre-swizzled global src
//    (gload_lds writes linear) + swizzled ds_read (both-sides, rule #21).
//  - XCD-bijective block swizzle (384%8==0).
//  - proj gemm + fp32 fallback stay on round-11 2-phase gemm_bt (N=1024
//    would starve a 256^2 grid: 128 blocks < 256 CUs).
//  - attn split-K (round 10) + combine unchanged.
// ============================================================================

typedef __bf16 bf16x8 __attribute__((ext_vector_type(8)));
typedef float f32x4 __attribute__((ext_vector_type(4)));
typedef __hip_bfloat16 bf16;

#define B_ 4
#define T_ 2048
#define C_ 1024
#define NH_ 16
#define HS_ 64
#define NEG_BIG (-30000.0f)
#define SCALE_LOG2E 0.180336880111f  // (1/sqrt(64)) * log2(e)

// Wave-uniform dtype probe on x (fp32 vs bf16), verified round 4.
__device__ __forceinline__ bool detect_fp32(const unsigned short* px) {
  const int lane = threadIdx.x & 63;
  const unsigned short u = px[2 * lane];
  const int e = (u >> 7) & 0xff;
  const bool plausible = (e >= 117) && (e <= 137);
  return __popcll(__ballot(plausible)) < 32;
}

// async global->LDS 16B per lane (m97). LDS dest: wave-uniform base + lane*16.
__device__ __forceinline__ void load_lds16(const bf16* g, bf16* l) {
  __builtin_amdgcn_global_load_lds(
      (const __attribute__((address_space(1))) void*)(uintptr_t)g,
      (__attribute__((address_space(3))) void*)(uintptr_t)l, 16, 0, 0);
}

// fp32 load of 8 elements -> 8 bf16 packed in uint4.
__device__ __forceinline__ uint4 ld8f(const void* base, size_t elt) {
  const float* fp = (const float*)base + elt;
  float4 f0 = *(const float4*)(fp);
  float4 f1 = *(const float4*)(fp + 4);
  union { bf16 h[8]; uint4 u; } r;
  r.h[0] = __float2bfloat16(f0.x); r.h[1] = __float2bfloat16(f0.y);
  r.h[2] = __float2bfloat16(f0.z); r.h[3] = __float2bfloat16(f0.w);
  r.h[4] = __float2bfloat16(f1.x); r.h[5] = __float2bfloat16(f1.y);
  r.h[6] = __float2bfloat16(f1.z); r.h[7] = __float2bfloat16(f1.w);
  return r.u;
}

// ----------------------------------------------------------------------------
// One-shot fp32->bf16 conversion of x, W_attn, W_proj (8 elems/thread).
// ----------------------------------------------------------------------------
__global__ __launch_bounds__(256) void convert3(
    const void* __restrict__ x, const void* __restrict__ wa,
    const void* __restrict__ wp, bf16* __restrict__ xb, bf16* __restrict__ wab,
    bf16* __restrict__ wpb, const unsigned short* __restrict__ probe) {
  const bool f32 = detect_fp32(probe);
  int blk = blockIdx.x;
  const void* src;
  bf16* dst;
  if (blk < 4096) {
    src = x; dst = xb;
  } else if (blk < 4096 + 1536) {
    blk -= 4096; src = wa; dst = wab;
  } else {
    blk -= 4096 + 1536; src = wp; dst = wpb;
  }
  const size_t i = ((size_t)blk * 256 + threadIdx.x) * 8;
  if (f32)
    *(uint4*)(dst + i) = ld8f(src, i);
  else
    *(uint4*)(dst + i) = *(const uint4*)((const bf16*)src + i);
}

// ----------------------------------------------------------------------------
// gemm8_qkv: 8-phase 256^2 bf16 GEMM for qkv = x_bf @ wa_bf^T.
// A = x_bf [8192][1024], B = wa_bf [3072][1024] (both K-major).
// Output scattered to q_ws/k_ws [b][h][t][d] and v_ws [b][h][d][t].
// ----------------------------------------------------------------------------
__global__ __launch_bounds__(512, 2) void gemm8_qkv(
    const bf16* __restrict__ A, const bf16* __restrict__ Bm,
    bf16* __restrict__ q_ws, bf16* __restrict__ k_ws,
    bf16* __restrict__ v_ws) {
  // LDS: [dbuf p][k-half h][row 256][k 32] bf16 for A and B = 128 KiB total.
  __shared__ bf16 Asm[2][2][256][32];
  __shared__ bf16 Bsm[2][2][256][32];

  const int tid = threadIdx.x;
  const int lane = tid & 63;
  const int wid = tid >> 6;    // 0..7
  const int wr = wid >> 2;     // 0..1  (M half: 128 rows each)
  const int wc = wid & 3;      // 0..3  (N quarter: 64 cols each)
  const int quad = lane >> 4;  // 0..3
  const int col = lane & 15;

  // XCD-bijective swizzle on flattened 12x32 grid (384 % 8 == 0).
  const int flat = (int)blockIdx.y * 12 + (int)blockIdx.x;
  const int swz = (flat & 7) * 48 + (flat >> 3);
  const int n0 = (swz % 12) * 256;
  const int m0 = (swz / 12) * 256;
  const bool vsec = (n0 >> 10) == 2;

  constexpr int NT = 1024 / 64;  // 16 K-tiles of BK=64

  // ---- staging map: thread covers 16B chunks c0=tid, c1=512+tid of a
  // 1024-chunk half-tile (256 rows x 2 16B-slots... rows x 4 slots of 8 bf16).
  // Swizzle (involution on 16B slots): slot ^= (row>>1)&3. gload_lds writes
  // LINEAR dest, so the XOR is applied to the global SOURCE slot; ds_read
  // applies the same XOR (rule #21).
  const int c0 = tid, c1 = 512 + tid;
  const int r0 = c0 >> 2, s0 = (c0 & 3) ^ ((r0 >> 1) & 3);
  const int r1 = c1 >> 2, s1 = (c1 & 3) ^ ((r1 >> 1) & 3);
  const size_t ga0 = (size_t)(m0 + r0) * 1024 + s0 * 8;
  const size_t ga1 = (size_t)(m0 + r1) * 1024 + s1 * 8;
  const size_t gb0 = (size_t)(n0 + r0) * 1024 + s0 * 8;
  const size_t gb1 = (size_t)(n0 + r1) * 1024 + s1 * 8;

  auto stageA = [&](int T, int h) {
    bf16* base = &Asm[T & 1][h][0][0];
    const int kk = T * 64 + h * 32;
    load_lds16(A + ga0 + kk, base + c0 * 8);
    load_lds16(A + ga1 + kk, base + c1 * 8);
  };
  auto stageB = [&](int T, int h) {
    bf16* base = &Bsm[T & 1][h][0][0];
    const int kk = T * 64 + h * 32;
    load_lds16(Bm + gb0 + kk, base + c0 * 8);
    load_lds16(Bm + gb1 + kk, base + c1 * 8);
  };

  // ds_read slot swizzle: q' = quad ^ ((row>>1)&3); row LSBs come from col.
  const int aq = quad ^ ((col >> 1) & 3);

  f32x4 acc[8][4] = {};
  bf16x8 pA[8];

  // ---- prologue: tile 0 (4 halves) + A0,B0,A1 of tile 1 = 14 loads ----
  stageA(0, 0); stageB(0, 0); stageA(0, 1); stageB(0, 1);
  stageA(1, 0); stageB(1, 0); stageA(1, 1);
  asm volatile("s_waitcnt vmcnt(6)" ::: "memory");  // tile 0 resident
  __builtin_amdgcn_s_barrier();

  for (int t = 0; t < NT; ++t) {
    const bf16* Ab = (const bf16*)Asm + (t & 1) * 16384;
    const bf16* Bb = (const bf16*)Bsm + (t & 1) * 16384;

    // ======== phase 1: ks=0, n0-1 ; stage B1(t+1) ========
#pragma unroll
    for (int m = 0; m < 8; ++m)
      pA[m] = *(const bf16x8*)(Ab + (wr * 128 + m * 16 + col) * 32 + aq * 8);
    bf16x8 b0 = *(const bf16x8*)(Bb + (wc * 64 + 0 + col) * 32 + aq * 8);
    bf16x8 b1 = *(const bf16x8*)(Bb + (wc * 64 + 16 + col) * 32 + aq * 8);
    if (t + 1 < NT) stageB(t + 1, 1);
    __builtin_amdgcn_s_barrier();
    asm volatile("s_waitcnt lgkmcnt(0)" ::: "memory");
    __builtin_amdgcn_s_setprio(1);
    if (vsec) {
#pragma unroll
      for (int m = 0; m < 8; ++m) {
        acc[m][0] = __builtin_amdgcn_mfma_f32_16x16x32_bf16(b0, pA[m], acc[m][0], 0, 0, 0);
        acc[m][1] = __builtin_amdgcn_mfma_f32_16x16x32_bf16(b1, pA[m], acc[m][1], 0, 0, 0);
      }
    } else {
#pragma unroll
      for (int m = 0; m < 8; ++m) {
        acc[m][0] = __builtin_amdgcn_mfma_f32_16x16x32_bf16(pA[m], b0, acc[m][0], 0, 0, 0);
        acc[m][1] = __builtin_amdgcn_mfma_f32_16x16x32_bf16(pA[m], b1, acc[m][1], 0, 0, 0);
      }
    }
    __builtin_amdgcn_s_setprio(0);
    __builtin_amdgcn_s_barrier();

    // ======== phase 2: ks=0, n2-3 (pA reused) ; stage A0(t+2) ========
    bf16x8 b2 = *(const bf16x8*)(Bb + (wc * 64 + 32 + col) * 32 + aq * 8);
    bf16x8 b3 = *(const bf16x8*)(Bb + (wc * 64 + 48 + col) * 32 + aq * 8);
    if (t + 2 < NT) stageA(t + 2, 0);
    __builtin_amdgcn_s_barrier();
    asm volatile("s_waitcnt lgkmcnt(0)" ::: "memory");
    __builtin_amdgcn_s_setprio(1);
    if (vsec) {
#pragma unroll
      for (int m = 0; m < 8; ++m) {
        acc[m][2] = __builtin_amdgcn_mfma_f32_16x16x32_bf16(b2, pA[m], acc[m][2], 0, 0, 0);
        acc[m][3] = __builtin_amdgcn_mfma_f32_16x16x32_bf16(b3, pA[m], acc[m][3], 0, 0, 0);
      }
    } else {
#pragma unroll
      for (int m = 0; m < 8; ++m) {
        acc[m][2] = __builtin_amdgcn_mfma_f32_16x16x32_bf16(pA[m], b2, acc[m][2], 0, 0, 0);
        acc[m][3] = __builtin_amdgcn_mfma_f32_16x16x32_bf16(pA[m], b3, acc[m][3], 0, 0, 0);
      }
    }
    __builtin_amdgcn_s_setprio(0);
    __builtin_amdgcn_s_barrier();

    // ======== phase 3: ks=1, n0-1 ; stage B0(t+2) ========
    Ab += 8192;
    Bb += 8192;
#pragma unroll
    for (int m = 0; m < 8; ++m)
      pA[m] = *(const bf16x8*)(Ab + (wr * 128 + m * 16 + col) * 32 + aq * 8);
    b0 = *(const bf16x8*)(Bb + (wc * 64 + 0 + col) * 32 + aq * 8);
    b1 = *(const bf16x8*)(Bb + (wc * 64 + 16 + col) * 32 + aq * 8);
    if (t + 2 < NT) stageB(t + 2, 0);
    __builtin_amdgcn_s_barrier();
    asm volatile("s_waitcnt lgkmcnt(0)" ::: "memory");
    __builtin_amdgcn_s_setprio(1);
    if (vsec) {
#pragma unroll
      for (int m = 0; m < 8; ++m) {
        acc[m][0] = __builtin_amdgcn_mfma_f32_16x16x32_bf16(b0, pA[m], acc[m][0], 0, 0, 0);
        acc[m][1] = __builtin_amdgcn_mfma_f32_16x16x32_bf16(b1, pA[m], acc[m][1], 0, 0, 0);
      }
    } else {
#pragma unroll
      for (int m = 0; m < 8; ++m) {
        acc[m][0] = __builtin_amdgcn_mfma_f32_16x16x32_bf16(pA[m], b0, acc[m][0], 0, 0, 0);
        acc[m][1] = __builtin_amdgcn_mfma_f32_16x16x32_bf16(pA[m], b1, acc[m][1], 0, 0, 0);
      }
    }
    __builtin_amdgcn_s_setprio(0);
    __builtin_amdgcn_s_barrier();

    // ======== phase 4: ks=1, n2-3 ; stage A1(t+2) ; boundary vmcnt ========
    b2 = *(const bf16x8*)(Bb + (wc * 64 + 32 + col) * 32 + aq * 8);
    b3 = *(const bf16x8*)(Bb + (wc * 64 + 48 + col) * 32 + aq * 8);
    if (t + 2 < NT) stageA(t + 2, 1);
    __builtin_amdgcn_s_barrier();
    asm volatile("s_waitcnt lgkmcnt(0)" ::: "memory");
    __builtin_amdgcn_s_setprio(1);
    if (vsec) {
#pragma unroll
      for (int m = 0; m < 8; ++m) {
        acc[m][2] = __builtin_amdgcn_mfma_f32_16x16x32_bf16(b2, pA[m], acc[m][2], 0, 0, 0);
        acc[m][3] = __builtin_amdgcn_mfma_f32_16x16x32_bf16(b3, pA[m], acc[m][3], 0, 0, 0);
      }
    } else {
#pragma unroll
      for (int m = 0; m < 8; ++m) {
        acc[m][2] = __builtin_amdgcn_mfma_f32_16x16x32_bf16(pA[m], b2, acc[m][2], 0, 0, 0);
        acc[m][3] = __builtin_amdgcn_mfma_f32_16x16x32_bf16(pA[m], b3, acc[m][3], 0, 0, 0);
      }
    }
    __builtin_amdgcn_s_setprio(0);
    // all of tile t+1 (through B1(t+1), issued ph1) done; 3 halves of t+2
    // (A0,B0,A1, issued ph2-4) may remain in flight.
    if (t + 2 < NT)
      asm volatile("s_waitcnt vmcnt(6)" ::: "memory");
    else
      asm volatile("s_waitcnt vmcnt(0)" ::: "memory");
    __builtin_amdgcn_s_barrier();
  }

  // ---- epilogue: scatter to q/k [b][h][t][d] or v [b][h][d][t] ----
  const int b = m0 >> 11;
  if (!vsec) {
    bf16* dst = ((n0 >> 10) == 0) ? q_ws : k_ws;
#pragma unroll
    for (int m = 0; m < 8; ++m) {
      const int mrow = (m0 & 2047) + wr * 128 + m * 16 + quad * 4;
#pragma unroll
      for (int n = 0; n < 4; ++n) {
        const int cc = (n0 & 1023) + wc * 64 + n * 16 + col;
        const int h = cc >> 6, d = cc & 63;
#pragma unroll
        for (int r = 0; r < 4; ++r)
          dst[(((size_t)b * NH_ + h) * T_ + mrow + r) * HS_ + d] =
              __float2bfloat16(acc[m][n][r]);
      }
    }
  } else {
#pragma unroll
    for (int m = 0; m < 8; ++m) {
      const int tloc = (m0 & 2047) + wr * 128 + m * 16 + col;
#pragma unroll
      for (int n = 0; n < 4; ++n) {
        const int vch = (n0 & 1023) + wc * 64 + n * 16 + quad * 4;
#pragma unroll
        for (int r = 0; r < 4; ++r) {
          const int h = (vch + r) >> 6, d = (vch + r) & 63;
          v_ws[(((size_t)b * NH_ + h) * HS_ + d) * T_ + tloc] =
              __float2bfloat16(acc[m][n][r]);
        }
      }
    }
  }
}

// ----------------------------------------------------------------------------
// gemm_bt (round 11): 128x128 tile, BK=32, double-buffered LDS, 2-phase.
// Used for the proj GEMM and the fp32 no-workspace fallback.
// ----------------------------------------------------------------------------
template <int IN_MODE, int OUT_MODE>
__global__ __launch_bounds__(256, 2) void gemm_bt(
    const void* __restrict__ A, const void* __restrict__ B, void* __restrict__ C,
    bf16* __restrict__ k_ws, bf16* __restrict__ v_ws,
    const unsigned short* __restrict__ in_probe,
    const unsigned short* __restrict__ out_probe, int M, int N, int K) {
  __shared__ bf16 As[2][128 * 32];
  __shared__ bf16 Bs[2][128 * 32];

  const bool f32b = in_probe ? detect_fp32(in_probe) : false;
  const bool f32a = (IN_MODE == 0) && f32b;
  const bool f32out =
      (OUT_MODE == 0) && (out_probe ? detect_fp32(out_probe) : false);

  const int tid = threadIdx.x;
  const int lane = tid & 63;
  const int wid = tid >> 6;
  const int quad = lane >> 4;
  const int col = lane & 15;
  const int m0 = blockIdx.y * 128;
  const int n0 = blockIdx.x * 128;
  const int wm = (wid >> 1) * 64;
  const int wn = (wid & 1) * 64;
  const bool vsec = (OUT_MODE == 1) && ((n0 >> 10) == 2);

  const size_t arow = (size_t)(m0 + (tid >> 2));
  const size_t brow = (size_t)(n0 + (tid >> 2));
  const int chunk = (tid & 3) * 8;
  const size_t astep = (IN_MODE == 0) ? (size_t)64 * K : (size_t)64 * HS_;

  f32x4 acc[4][4] = {};

  auto a_ptr = [&](int k0) -> const bf16* {
    if (IN_MODE == 0) return (const bf16*)A + arow * K + chunk + k0;
    const int b = m0 >> 11;
    const int tloc = (m0 & 2047) + (tid >> 2);
    return (const bf16*)A +
           ((((size_t)b * NH_) + (k0 >> 6)) * T_ + tloc) * HS_ + (k0 & 32) +
           chunk;
  };

  if (f32a) {
    uint4 a0 = ld8f(A, arow * K + chunk);
    uint4 a1 = ld8f(A, (arow + 64) * K + chunk);
    *(uint4*)(&As[0][0] + tid * 8) = a0;
    *(uint4*)(&As[0][0] + 2048 + tid * 8) = a1;
  } else {
    const bf16* ap = a_ptr(0);
    load_lds16(ap, &As[0][0] + tid * 8);
    load_lds16(ap + astep, &As[0][0] + 2048 + tid * 8);
  }
  if (f32b) {
    uint4 b0 = ld8f(B, brow * K + chunk);
    uint4 b1 = ld8f(B, (brow + 64) * K + chunk);
    *(uint4*)(&Bs[0][0] + tid * 8) = b0;
    *(uint4*)(&Bs[0][0] + 2048 + tid * 8) = b1;
  } else {
    load_lds16((const bf16*)B + brow * K + chunk, &Bs[0][0] + tid * 8);
    load_lds16((const bf16*)B + (brow + 64) * K + chunk,
               &Bs[0][0] + 2048 + tid * 8);
  }
  __syncthreads();

  int cur = 0;
  for (int k0 = 0; k0 < K; k0 += 32) {
    const int kn = k0 + 32;
    const bool hasn = kn < K;
    const int nxt = cur ^ 1;

    uint4 a0, a1, b0, b1;
    bool wra = false, wrb = false;
    if (hasn) {
      if (f32a) {
        a0 = ld8f(A, arow * K + chunk + kn);
        a1 = ld8f(A, (arow + 64) * K + chunk + kn);
        wra = true;
      } else {
        const bf16* ap = a_ptr(kn);
        load_lds16(ap, &As[nxt][0] + tid * 8);
        load_lds16(ap + astep, &As[nxt][0] + 2048 + tid * 8);
      }
      if (f32b) {
        b0 = ld8f(B, brow * K + chunk + kn);
        b1 = ld8f(B, (brow + 64) * K + chunk + kn);
        wrb = true;
      } else {
        load_lds16((const bf16*)B + brow * K + chunk + kn,
                   &Bs[nxt][0] + tid * 8);
        load_lds16((const bf16*)B + (brow + 64) * K + chunk + kn,
                   &Bs[nxt][0] + 2048 + tid * 8);
      }
    }

    bf16x8 af[4], bfr[4];
#pragma unroll
    for (int t = 0; t < 4; ++t) {
      af[t] = *(const bf16x8*)(&As[cur][0] + (wm + t * 16 + col) * 32 + quad * 8);
      bfr[t] = *(const bf16x8*)(&Bs[cur][0] + (wn + t * 16 + col) * 32 + quad * 8);
    }
    if (vsec) {
#pragma unroll
      for (int tm = 0; tm < 4; ++tm)
#pragma unroll
        for (int tn = 0; tn < 4; ++tn)
          acc[tm][tn] = __builtin_amdgcn_mfma_f32_16x16x32_bf16(
              bfr[tn], af[tm], acc[tm][tn], 0, 0, 0);
    } else {
#pragma unroll
      for (int tm = 0; tm < 4; ++tm)
#pragma unroll
        for (int tn = 0; tn < 4; ++tn)
          acc[tm][tn] = __builtin_amdgcn_mfma_f32_16x16x32_bf16(
              af[tm], bfr[tn], acc[tm][tn], 0, 0, 0);
    }

    if (wra) {
      *(uint4*)(&As[nxt][0] + tid * 8) = a0;
      *(uint4*)(&As[nxt][0] + 2048 + tid * 8) = a1;
    }
    if (wrb) {
      *(uint4*)(&Bs[nxt][0] + tid * 8) = b0;
      *(uint4*)(&Bs[nxt][0] + 2048 + tid * 8) = b1;
    }
    __syncthreads();
    cur = nxt;
  }

  if (OUT_MODE == 0) {
#pragma unroll
    for (int tm = 0; tm < 4; ++tm) {
      const int mrow = m0 + wm + tm * 16 + quad * 4;
#pragma unroll
      for (int tn = 0; tn < 4; ++tn) {
        const int ncol = n0 + wn + tn * 16 + col;
#pragma unroll
        for (int r = 0; r < 4; ++r) {
          if (f32out)
            ((float*)C)[(size_t)(mrow + r) * N + ncol] = acc[tm][tn][r];
          else
            ((bf16*)C)[(size_t)(mrow + r) * N + ncol] =
                __float2bfloat16(acc[tm][tn][r]);
        }
      }
    }
  } else if (vsec) {
    const int b = m0 >> 11;
#pragma unroll
    for (int tm = 0; tm < 4; ++tm) {
      const int tloc = (m0 & 2047) + wm + tm * 16 + col;
#pragma unroll
      for (int tn = 0; tn < 4; ++tn) {
        const int vch = (n0 & (C_ - 1)) + wn + tn * 16 + quad * 4;
#pragma unroll
        for (int r = 0; r < 4; ++r) {
          const int h = (vch + r) >> 6, d = (vch + r) & 63;
          v_ws[(((size_t)b * NH_ + h) * HS_ + d) * T_ + tloc] =
              __float2bfloat16(acc[tm][tn][r]);
        }
      }
    }
  } else {
    const int sect = n0 >> 10;  // 0:q 1:k
    bf16* dst = (sect == 0) ? (bf16*)C : k_ws;
#pragma unroll
    for (int tm = 0; tm < 4; ++tm) {
      const int mrow = m0 + wm + tm * 16 + quad * 4;
#pragma unroll
      for (int tn = 0; tn < 4; ++tn) {
        const int c = (n0 + wn + tn * 16 + col) & (C_ - 1);
        const int h = c >> 6, d = c & 63;
#pragma unroll
        for (int r = 0; r < 4; ++r) {
          const int t = (mrow + r) & (T_ - 1);
          const int b = (mrow + r) >> 11;
          dst[(((size_t)b * NH_ + h) * T_ + t) * HS_ + d] =
              __float2bfloat16(acc[tm][tn][r]);
        }
      }
    }
  }
}

// ----------------------------------------------------------------------------
// MFMA flash attention (causal), fixed-max softmax, split-K (round 10).
// ----------------------------------------------------------------------------
template <int SPLIT>
__global__ __launch_bounds__(256, 2) void attn(
    bf16* qy, const bf16* __restrict__ kws, const bf16* __restrict__ vws,
    float* __restrict__ po, float* __restrict__ pl) {
  __shared__ bf16 Ks[64 * 72];      // [key][d]
  __shared__ bf16 Vs[64 * 72];      // [d][key]
  __shared__ bf16 Ps[4][32 * 72];   // per-wave P [32 q][64 k], stride 72

  const int tid = threadIdx.x;
  const int lane = tid & 63;
  const int w = tid >> 6;
  const int quad = lane >> 4;
  const int col = lane & 15;
  const int x = (int)blockIdx.x;

  int qb, ck;
  if (SPLIT) {
    const unsigned long long lo = 0xC4D5E6F7FEDCBA98ULL;  // qb nibbles x0..15
    const unsigned int hi = 0xB3A29180u;                  // qb nibbles x16..23
    const unsigned int cmask = 0x00AAAA00u;               // chunk bit per x
    qb = (x < 16) ? (int)((lo >> (4 * x)) & 15)
                  : (int)((hi >> (4 * (x - 16))) & 15);
    ck = (int)((cmask >> x) & 1);
  } else {
    const int gx = (int)gridDim.x;  // 16
    const int hx = gx >> 1;
    qb = (x < hx) ? (gx - 1 - x) : (x - hx);
    ck = 0;
  }

  const int bh = blockIdx.y;
  const size_t head_off = (size_t)bh * T_ * HS_;

  const int ntall = 2 * (qb + 1);
  const int kt0 = SPLIT ? ck * 16 : 0;
  const int ntiles = SPLIT ? min(ntall - kt0, 16) : ntall;

  const int qrow = qb * 128 + w * 32 + col;
  const bf16* qp = qy + head_off + (size_t)qrow * HS_ + quad * 8;
  bf16x8 qf0a = *(const bf16x8*)(qp);
  bf16x8 qf1a = *(const bf16x8*)(qp + 32);
  bf16x8 qf0b = *(const bf16x8*)(qp + 16 * HS_);
  bf16x8 qf1b = *(const bf16x8*)(qp + 16 * HS_ + 32);
#pragma unroll
  for (int j = 0; j < 8; ++j) {
    qf0a[j] = (__bf16)((float)qf0a[j] * SCALE_LOG2E);
    qf1a[j] = (__bf16)((float)qf1a[j] * SCALE_LOG2E);
    qf0b[j] = (__bf16)((float)qf0b[j] * SCALE_LOG2E);
    qf1b[j] = (__bf16)((float)qf1b[j] * SCALE_LOG2E);
  }

  bf16x8 onesf;
#pragma unroll
  for (int j = 0; j < 8; ++j) onesf[j] = (__bf16)1.0f;

  f32x4 oa[4] = {}, ob[4] = {};
  f32x4 lacca = {}, laccb = {};

  bf16* pw = &Ps[w][0];

  const int srow = tid >> 3, sch = tid & 7;
  const bf16* kg = kws + head_off + (size_t)(kt0 * 64 + srow) * HS_ + sch * 8;
  const bf16* vg = vws + ((size_t)bh * HS_ + srow) * T_ + kt0 * 64 + sch * 8;
  bf16* kl0 = Ks + srow * 72 + sch * 8;
  bf16* kl1 = Ks + (srow + 32) * 72 + sch * 8;
  bf16* vl0 = Vs + srow * 72 + sch * 8;
  bf16* vl1 = Vs + (srow + 32) * 72 + sch * 8;

  uint4 kr0 = *(const uint4*)(kg);
  uint4 kr1 = *(const uint4*)(kg + (size_t)32 * HS_);
  uint4 vr0 = *(const uint4*)(vg);
  uint4 vr1 = *(const uint4*)(vg + (size_t)32 * T_);

  const int qga = qb * 128 + w * 32 + col;
  const int diag_start = 2 * qb;

  for (int kt = 0; kt < ntiles; ++kt) {
    const int ktg = kt0 + kt;
    const int k0 = ktg * 64;
    __syncthreads();
    *(uint4*)kl0 = kr0;
    *(uint4*)kl1 = kr1;
    *(uint4*)vl0 = vr0;
    *(uint4*)vl1 = vr1;
    __syncthreads();
    if (kt + 1 < ntiles) {
      kg += (size_t)64 * HS_;
      vg += 64;
      kr0 = *(const uint4*)(kg);
      kr1 = *(const uint4*)(kg + (size_t)32 * HS_);
      vr0 = *(const uint4*)(vg);
      vr1 = *(const uint4*)(vg + (size_t)32 * T_);
    }

    f32x4 sa[4], sb[4];
#pragma unroll
    for (int nt = 0; nt < 4; ++nt) {
      const bf16* kp = Ks + (nt * 16 + col) * 72 + quad * 8;
      bf16x8 kf0 = *(const bf16x8*)(kp);
      bf16x8 kf1 = *(const bf16x8*)(kp + 32);
      f32x4 a = {-32.0f, -32.0f, -32.0f, -32.0f};
      a = __builtin_amdgcn_mfma_f32_16x16x32_bf16(kf0, qf0a, a, 0, 0, 0);
      a = __builtin_amdgcn_mfma_f32_16x16x32_bf16(kf1, qf1a, a, 0, 0, 0);
      sa[nt] = a;
      f32x4 b = {-32.0f, -32.0f, -32.0f, -32.0f};
      b = __builtin_amdgcn_mfma_f32_16x16x32_bf16(kf0, qf0b, b, 0, 0, 0);
      b = __builtin_amdgcn_mfma_f32_16x16x32_bf16(kf1, qf1b, b, 0, 0, 0);
      sb[nt] = b;
    }

    if (ktg >= diag_start) {
#pragma unroll
      for (int nt = 0; nt < 4; ++nt) {
        const int key = k0 + nt * 16 + quad * 4;
#pragma unroll
        for (int r = 0; r < 4; ++r) {
          if (key + r > qga) sa[nt][r] = NEG_BIG;
          if (key + r > qga + 16) sb[nt][r] = NEG_BIG;
        }
      }
    }

#pragma unroll
    for (int nt = 0; nt < 4; ++nt) {
      union { ushort u[4]; uint2 v; } pa, pb;
#pragma unroll
      for (int r = 0; r < 4; ++r) {
        pa.u[r] = __bfloat16_as_ushort(__float2bfloat16(exp2f(sa[nt][r])));
        pb.u[r] = __bfloat16_as_ushort(__float2bfloat16(exp2f(sb[nt][r])));
      }
      *(uint2*)(pw + col * 72 + nt * 16 + quad * 4) = pa.v;
      *(uint2*)(pw + (col + 16) * 72 + nt * 16 + quad * 4) = pb.v;
    }

    __asm__ __volatile__("s_waitcnt lgkmcnt(0)" ::: "memory");

#pragma unroll
    for (int half = 0; half < 2; ++half) {
      bf16x8 pfa = *(const bf16x8*)(pw + col * 72 + half * 32 + quad * 8);
      bf16x8 pfb = *(const bf16x8*)(pw + (col + 16) * 72 + half * 32 + quad * 8);
      lacca = __builtin_amdgcn_mfma_f32_16x16x32_bf16(pfa, onesf, lacca, 0, 0, 0);
      laccb = __builtin_amdgcn_mfma_f32_16x16x32_bf16(pfb, onesf, laccb, 0, 0, 0);
#pragma unroll
      for (int dt = 0; dt < 4; ++dt) {
        bf16x8 vf = *(const bf16x8*)(Vs + (dt * 16 + col) * 72 + half * 32 +
                                     quad * 8);
        oa[dt] = __builtin_amdgcn_mfma_f32_16x16x32_bf16(pfa, vf, oa[dt], 0, 0, 0);
        ob[dt] = __builtin_amdgcn_mfma_f32_16x16x32_bf16(pfb, vf, ob[dt], 0, 0, 0);
      }
    }
  }

  const bool dosplit = SPLIT && (qb >= 8);
  if (!dosplit) {
    float inva[4], invb[4];
#pragma unroll
    for (int r = 0; r < 4; ++r) {
      inva[r] = 1.0f / lacca[r];
      invb[r] = 1.0f / laccb[r];
    }
#pragma unroll
    for (int dt = 0; dt < 4; ++dt)
#pragma unroll
      for (int r = 0; r < 4; ++r) {
        const int qa = qb * 128 + w * 32 + quad * 4 + r;
        qy[head_off + (size_t)qa * HS_ + dt * 16 + col] =
            __float2bfloat16(oa[dt][r] * inva[r]);
        qy[head_off + (size_t)(qa + 16) * HS_ + dt * 16 + col] =
            __float2bfloat16(ob[dt][r] * invb[r]);
      }
  } else {
    const int slot = ((qb - 8) * 64 + bh) * 2 + ck;
    float* o = po + (size_t)slot * (128 * 64);
#pragma unroll
    for (int dt = 0; dt < 4; ++dt)
#pragma unroll
      for (int r = 0; r < 4; ++r) {
        const int qa = w * 32 + quad * 4 + r;
        o[(size_t)qa * 64 + dt * 16 + col] = oa[dt][r];
        o[(size_t)(qa + 16) * 64 + dt * 16 + col] = ob[dt][r];
      }
    if (col == 0) {
      float* lp = pl + (size_t)slot * 128;
#pragma unroll
      for (int r = 0; r < 4; ++r) {
        lp[w * 32 + quad * 4 + r] = lacca[r];
        lp[w * 32 + 16 + quad * 4 + r] = laccb[r];
      }
    }
  }
}

// ----------------------------------------------------------------------------
// Combine: for qb>=8, y = (O0+O1)/(l0+l1).
// ----------------------------------------------------------------------------
__global__ __launch_bounds__(256) void attn_combine(
    bf16* __restrict__ qy, const float* __restrict__ po,
    const float* __restrict__ pl) {
  const int qb = 8 + (int)blockIdx.x;  // 8..15
  const int bh = (int)blockIdx.y;
  const int pair = ((qb - 8) * 64 + bh) * 2;
  const float* o0 = po + (size_t)pair * (128 * 64);
  const float* o1 = o0 + 128 * 64;
  const float* l0 = pl + (size_t)pair * 128;
  const float* l1 = l0 + 128;
  const int q = threadIdx.x >> 1;
  const int d0 = (threadIdx.x & 1) * 32;
  const float inv = 1.0f / (l0[q] + l1[q]);
  const size_t base =
      (size_t)bh * T_ * HS_ + (size_t)(qb * 128 + q) * HS_ + d0;
  const size_t ob = (size_t)q * 64 + d0;
#pragma unroll
  for (int j0 = 0; j0 < 32; j0 += 8) {
    union { bf16 h[8]; uint4 u; } out;
#pragma unroll
    for (int j = 0; j < 8; ++j)
      out.h[j] = __float2bfloat16((o0[ob + j0 + j] + o1[ob + j0 + j]) * inv);
    *(uint4*)(qy + base + j0) = out.u;
  }
}

// ----------------------------------------------------------------------------
extern "C" void kernel_launch(void* const* d_in, const int* in_sizes, int n_in,
                              void* d_out, int out_size, void* d_ws, size_t ws_size,
                              hipStream_t stream) {
  const void* x = d_in[0];       // [4,2048,1024] fp32 (probed)
  const void* W_attn = d_in[1];  // [3072,1024]
  const void* W_proj = d_in[2];  // [1024,1024]
  const unsigned short* probe = (const unsigned short*)d_in[0];
  // d_in[3..6]: dead code in the reference.

  const size_t qkv_elems = (size_t)B_ * NH_ * T_ * HS_;  // 8388608
  const size_t xe = (size_t)B_ * T_ * C_;                // 8388608
  const size_t wae = (size_t)3 * C_ * C_;                // 3145728
  const size_t wpe = (size_t)C_ * C_;                    // 1048576

  bf16* q_ws = (bf16*)d_ws;
  bf16* k_ws = q_ws + qkv_elems;
  bf16* v_ws = k_ws + qkv_elems;
  bf16* x_bf = v_ws + qkv_elems;
  bf16* wa_bf = x_bf + xe;
  bf16* wp_bf = wa_bf + wae;
  const size_t need = (3 * qkv_elems + xe + wae + wpe) * sizeof(bf16);  // 72 MiB

  // split-K partials: 1024 slots x (128x64 O + 128 l) f32 = 32.5 MiB
  float* po = (float*)(wp_bf + wpe);
  float* pl = po + (size_t)1024 * 128 * 64;
  const size_t need2 =
      need + ((size_t)1024 * 128 * 64 + (size_t)1024 * 128) * sizeof(float);

  const int M = B_ * T_;  // 8192

  if (ws_size >= need) {
    convert3<<<6144, 256, 0, stream>>>(x, W_attn, W_proj, x_bf, wa_bf, wp_bf,
                                       probe);
    gemm8_qkv<<<dim3(12, 32), 512, 0, stream>>>(x_bf, wa_bf, q_ws, k_ws, v_ws);
    if (ws_size >= need2) {
      attn<1><<<dim3(24, B_ * NH_), 256, 0, stream>>>(q_ws, k_ws, v_ws, po, pl);
      attn_combine<<<dim3(8, B_ * NH_), 256, 0, stream>>>(q_ws, po, pl);
    } else {
      attn<0><<<dim3(T_ / 128, B_ * NH_), 256, 0, stream>>>(q_ws, k_ws, v_ws,
                                                            nullptr, nullptr);
    }
    gemm_bt<1, 0><<<dim3(C_ / 128, M / 128), 256, 0, stream>>>(
        q_ws, wp_bf, d_out, nullptr, nullptr, nullptr, probe, M, C_, C_);
  } else {
    gemm_bt<0, 1><<<dim3(3 * C_ / 128, M / 128), 256, 0, stream>>>(
        x, W_attn, q_ws, k_ws, v_ws, probe, nullptr, M, 3 * C_, C_);
    attn<0><<<dim3(T_ / 128, B_ * NH_), 256, 0, stream>>>(q_ws, k_ws, v_ws,
                                                          nullptr, nullptr);
    gemm_bt<1, 0><<<dim3(C_ / 128, M / 128), 256, 0, stream>>>(
        q_ws, W_proj, d_out, nullptr, nullptr, probe, probe, M, C_, C_);
  }
}

// Round 7
// 509.184 us; speedup vs baseline: 1.0058x; 1.0058x over previous
//
#include <hip/hip_runtime.h>
#include <hip/hip_bf16.h>
#include <stdint.h>

// ============================================================================
// MultiAttentionWithGating — compression branch (_kc/_vc) is DEAD CODE.
// Pipeline: qkv = x@W_attn^T ; causal SDPA (16 heads, hs=64) ; out = y@W_proj^T
// Inputs fp32 (runtime-probed); internal bf16 MFMA, fp32 accum.
//
// ROUND 13 (gemm8_qkv spilled: launch_bounds(512,2) capped VGPR at 128 =
// exactly the accumulator size -> 520MB scratch traffic, 313us, MfmaUtil 6%):
//  - ONE CHANGE: __launch_bounds__(512, 1). 8 waves/block, 1 block/CU,
//    256 VGPR budget. The 256^2 8-phase template is a 1-block/CU design;
//    cross-phase overlap comes from the counted vmcnt pipeline, not
//    multi-block residency. Swizzle already verified (bank conflicts 0).
//  - Everything else byte-identical to round 12.
// ============================================================================

typedef __bf16 bf16x8 __attribute__((ext_vector_type(8)));
typedef float f32x4 __attribute__((ext_vector_type(4)));
typedef __hip_bfloat16 bf16;

#define B_ 4
#define T_ 2048
#define C_ 1024
#define NH_ 16
#define HS_ 64
#define NEG_BIG (-30000.0f)
#define SCALE_LOG2E 0.180336880111f  // (1/sqrt(64)) * log2(e)

// Wave-uniform dtype probe on x (fp32 vs bf16), verified round 4.
__device__ __forceinline__ bool detect_fp32(const unsigned short* px) {
  const int lane = threadIdx.x & 63;
  const unsigned short u = px[2 * lane];
  const int e = (u >> 7) & 0xff;
  const bool plausible = (e >= 117) && (e <= 137);
  return __popcll(__ballot(plausible)) < 32;
}

// async global->LDS 16B per lane (m97). LDS dest: wave-uniform base + lane*16.
__device__ __forceinline__ void load_lds16(const bf16* g, bf16* l) {
  __builtin_amdgcn_global_load_lds(
      (const __attribute__((address_space(1))) void*)(uintptr_t)g,
      (__attribute__((address_space(3))) void*)(uintptr_t)l, 16, 0, 0);
}

// fp32 load of 8 elements -> 8 bf16 packed in uint4.
__device__ __forceinline__ uint4 ld8f(const void* base, size_t elt) {
  const float* fp = (const float*)base + elt;
  float4 f0 = *(const float4*)(fp);
  float4 f1 = *(const float4*)(fp + 4);
  union { bf16 h[8]; uint4 u; } r;
  r.h[0] = __float2bfloat16(f0.x); r.h[1] = __float2bfloat16(f0.y);
  r.h[2] = __float2bfloat16(f0.z); r.h[3] = __float2bfloat16(f0.w);
  r.h[4] = __float2bfloat16(f1.x); r.h[5] = __float2bfloat16(f1.y);
  r.h[6] = __float2bfloat16(f1.z); r.h[7] = __float2bfloat16(f1.w);
  return r.u;
}

// ----------------------------------------------------------------------------
// One-shot fp32->bf16 conversion of x, W_attn, W_proj (8 elems/thread).
// ----------------------------------------------------------------------------
__global__ __launch_bounds__(256) void convert3(
    const void* __restrict__ x, const void* __restrict__ wa,
    const void* __restrict__ wp, bf16* __restrict__ xb, bf16* __restrict__ wab,
    bf16* __restrict__ wpb, const unsigned short* __restrict__ probe) {
  const bool f32 = detect_fp32(probe);
  int blk = blockIdx.x;
  const void* src;
  bf16* dst;
  if (blk < 4096) {
    src = x; dst = xb;
  } else if (blk < 4096 + 1536) {
    blk -= 4096; src = wa; dst = wab;
  } else {
    blk -= 4096 + 1536; src = wp; dst = wpb;
  }
  const size_t i = ((size_t)blk * 256 + threadIdx.x) * 8;
  if (f32)
    *(uint4*)(dst + i) = ld8f(src, i);
  else
    *(uint4*)(dst + i) = *(const uint4*)((const bf16*)src + i);
}

// ----------------------------------------------------------------------------
// gemm8_qkv: 8-phase 256^2 bf16 GEMM for qkv = x_bf @ wa_bf^T.
// A = x_bf [8192][1024], B = wa_bf [3072][1024] (both K-major).
// Output scattered to q_ws/k_ws [b][h][t][d] and v_ws [b][h][d][t].
// 1 block/CU, 256 VGPR budget (acc[8][4] f32x4 = 128 VGPR alone).
// ----------------------------------------------------------------------------
__global__ __launch_bounds__(512, 1) void gemm8_qkv(
    const bf16* __restrict__ A, const bf16* __restrict__ Bm,
    bf16* __restrict__ q_ws, bf16* __restrict__ k_ws,
    bf16* __restrict__ v_ws) {
  // LDS: [dbuf p][k-half h][row 256][k 32] bf16 for A and B = 128 KiB total.
  __shared__ bf16 Asm[2][2][256][32];
  __shared__ bf16 Bsm[2][2][256][32];

  const int tid = threadIdx.x;
  const int lane = tid & 63;
  const int wid = tid >> 6;    // 0..7
  const int wr = wid >> 2;     // 0..1  (M half: 128 rows each)
  const int wc = wid & 3;      // 0..3  (N quarter: 64 cols each)
  const int quad = lane >> 4;  // 0..3
  const int col = lane & 15;

  // XCD-bijective swizzle on flattened 12x32 grid (384 % 8 == 0).
  const int flat = (int)blockIdx.y * 12 + (int)blockIdx.x;
  const int swz = (flat & 7) * 48 + (flat >> 3);
  const int n0 = (swz % 12) * 256;
  const int m0 = (swz / 12) * 256;
  const bool vsec = (n0 >> 10) == 2;

  constexpr int NT = 1024 / 64;  // 16 K-tiles of BK=64

  // ---- staging map: thread covers 16B chunks c0=tid, c1=512+tid of a
  // 1024-chunk half-tile (256 rows x 4 slots of 8 bf16).
  // Swizzle (involution on 16B slots): slot ^= (row>>1)&3. gload_lds writes
  // LINEAR dest, so the XOR is applied to the global SOURCE slot; ds_read
  // applies the same XOR (rule #21).
  const int c0 = tid, c1 = 512 + tid;
  const int r0 = c0 >> 2, s0 = (c0 & 3) ^ ((r0 >> 1) & 3);
  const int r1 = c1 >> 2, s1 = (c1 & 3) ^ ((r1 >> 1) & 3);
  const size_t ga0 = (size_t)(m0 + r0) * 1024 + s0 * 8;
  const size_t ga1 = (size_t)(m0 + r1) * 1024 + s1 * 8;
  const size_t gb0 = (size_t)(n0 + r0) * 1024 + s0 * 8;
  const size_t gb1 = (size_t)(n0 + r1) * 1024 + s1 * 8;

  auto stageA = [&](int T, int h) {
    bf16* base = &Asm[T & 1][h][0][0];
    const int kk = T * 64 + h * 32;
    load_lds16(A + ga0 + kk, base + c0 * 8);
    load_lds16(A + ga1 + kk, base + c1 * 8);
  };
  auto stageB = [&](int T, int h) {
    bf16* base = &Bsm[T & 1][h][0][0];
    const int kk = T * 64 + h * 32;
    load_lds16(Bm + gb0 + kk, base + c0 * 8);
    load_lds16(Bm + gb1 + kk, base + c1 * 8);
  };

  // ds_read slot swizzle: q' = quad ^ ((row>>1)&3); row LSBs come from col.
  const int aq = quad ^ ((col >> 1) & 3);

  f32x4 acc[8][4] = {};
  bf16x8 pA[8];

  // ---- prologue: tile 0 (4 halves) + A0,B0,A1 of tile 1 = 14 loads ----
  stageA(0, 0); stageB(0, 0); stageA(0, 1); stageB(0, 1);
  stageA(1, 0); stageB(1, 0); stageA(1, 1);
  asm volatile("s_waitcnt vmcnt(6)" ::: "memory");  // tile 0 resident
  __builtin_amdgcn_s_barrier();

  for (int t = 0; t < NT; ++t) {
    const bf16* Ab = (const bf16*)Asm + (t & 1) * 16384;
    const bf16* Bb = (const bf16*)Bsm + (t & 1) * 16384;

    // ======== phase 1: ks=0, n0-1 ; stage B1(t+1) ========
#pragma unroll
    for (int m = 0; m < 8; ++m)
      pA[m] = *(const bf16x8*)(Ab + (wr * 128 + m * 16 + col) * 32 + aq * 8);
    bf16x8 b0 = *(const bf16x8*)(Bb + (wc * 64 + 0 + col) * 32 + aq * 8);
    bf16x8 b1 = *(const bf16x8*)(Bb + (wc * 64 + 16 + col) * 32 + aq * 8);
    if (t + 1 < NT) stageB(t + 1, 1);
    __builtin_amdgcn_s_barrier();
    asm volatile("s_waitcnt lgkmcnt(0)" ::: "memory");
    __builtin_amdgcn_s_setprio(1);
    if (vsec) {
#pragma unroll
      for (int m = 0; m < 8; ++m) {
        acc[m][0] = __builtin_amdgcn_mfma_f32_16x16x32_bf16(b0, pA[m], acc[m][0], 0, 0, 0);
        acc[m][1] = __builtin_amdgcn_mfma_f32_16x16x32_bf16(b1, pA[m], acc[m][1], 0, 0, 0);
      }
    } else {
#pragma unroll
      for (int m = 0; m < 8; ++m) {
        acc[m][0] = __builtin_amdgcn_mfma_f32_16x16x32_bf16(pA[m], b0, acc[m][0], 0, 0, 0);
        acc[m][1] = __builtin_amdgcn_mfma_f32_16x16x32_bf16(pA[m], b1, acc[m][1], 0, 0, 0);
      }
    }
    __builtin_amdgcn_s_setprio(0);
    __builtin_amdgcn_s_barrier();

    // ======== phase 2: ks=0, n2-3 (pA reused) ; stage A0(t+2) ========
    bf16x8 b2 = *(const bf16x8*)(Bb + (wc * 64 + 32 + col) * 32 + aq * 8);
    bf16x8 b3 = *(const bf16x8*)(Bb + (wc * 64 + 48 + col) * 32 + aq * 8);
    if (t + 2 < NT) stageA(t + 2, 0);
    __builtin_amdgcn_s_barrier();
    asm volatile("s_waitcnt lgkmcnt(0)" ::: "memory");
    __builtin_amdgcn_s_setprio(1);
    if (vsec) {
#pragma unroll
      for (int m = 0; m < 8; ++m) {
        acc[m][2] = __builtin_amdgcn_mfma_f32_16x16x32_bf16(b2, pA[m], acc[m][2], 0, 0, 0);
        acc[m][3] = __builtin_amdgcn_mfma_f32_16x16x32_bf16(b3, pA[m], acc[m][3], 0, 0, 0);
      }
    } else {
#pragma unroll
      for (int m = 0; m < 8; ++m) {
        acc[m][2] = __builtin_amdgcn_mfma_f32_16x16x32_bf16(pA[m], b2, acc[m][2], 0, 0, 0);
        acc[m][3] = __builtin_amdgcn_mfma_f32_16x16x32_bf16(pA[m], b3, acc[m][3], 0, 0, 0);
      }
    }
    __builtin_amdgcn_s_setprio(0);
    __builtin_amdgcn_s_barrier();

    // ======== phase 3: ks=1, n0-1 ; stage B0(t+2) ========
    Ab += 8192;
    Bb += 8192;
#pragma unroll
    for (int m = 0; m < 8; ++m)
      pA[m] = *(const bf16x8*)(Ab + (wr * 128 + m * 16 + col) * 32 + aq * 8);
    b0 = *(const bf16x8*)(Bb + (wc * 64 + 0 + col) * 32 + aq * 8);
    b1 = *(const bf16x8*)(Bb + (wc * 64 + 16 + col) * 32 + aq * 8);
    if (t + 2 < NT) stageB(t + 2, 0);
    __builtin_amdgcn_s_barrier();
    asm volatile("s_waitcnt lgkmcnt(0)" ::: "memory");
    __builtin_amdgcn_s_setprio(1);
    if (vsec) {
#pragma unroll
      for (int m = 0; m < 8; ++m) {
        acc[m][0] = __builtin_amdgcn_mfma_f32_16x16x32_bf16(b0, pA[m], acc[m][0], 0, 0, 0);
        acc[m][1] = __builtin_amdgcn_mfma_f32_16x16x32_bf16(b1, pA[m], acc[m][1], 0, 0, 0);
      }
    } else {
#pragma unroll
      for (int m = 0; m < 8; ++m) {
        acc[m][0] = __builtin_amdgcn_mfma_f32_16x16x32_bf16(pA[m], b0, acc[m][0], 0, 0, 0);
        acc[m][1] = __builtin_amdgcn_mfma_f32_16x16x32_bf16(pA[m], b1, acc[m][1], 0, 0, 0);
      }
    }
    __builtin_amdgcn_s_setprio(0);
    __builtin_amdgcn_s_barrier();

    // ======== phase 4: ks=1, n2-3 ; stage A1(t+2) ; boundary vmcnt ========
    b2 = *(const bf16x8*)(Bb + (wc * 64 + 32 + col) * 32 + aq * 8);
    b3 = *(const bf16x8*)(Bb + (wc * 64 + 48 + col) * 32 + aq * 8);
    if (t + 2 < NT) stageA(t + 2, 1);
    __builtin_amdgcn_s_barrier();
    asm volatile("s_waitcnt lgkmcnt(0)" ::: "memory");
    __builtin_amdgcn_s_setprio(1);
    if (vsec) {
#pragma unroll
      for (int m = 0; m < 8; ++m) {
        acc[m][2] = __builtin_amdgcn_mfma_f32_16x16x32_bf16(b2, pA[m], acc[m][2], 0, 0, 0);
        acc[m][3] = __builtin_amdgcn_mfma_f32_16x16x32_bf16(b3, pA[m], acc[m][3], 0, 0, 0);
      }
    } else {
#pragma unroll
      for (int m = 0; m < 8; ++m) {
        acc[m][2] = __builtin_amdgcn_mfma_f32_16x16x32_bf16(pA[m], b2, acc[m][2], 0, 0, 0);
        acc[m][3] = __builtin_amdgcn_mfma_f32_16x16x32_bf16(pA[m], b3, acc[m][3], 0, 0, 0);
      }
    }
    __builtin_amdgcn_s_setprio(0);
    // all of tile t+1 (through B1(t+1), issued ph1) done; 3 halves of t+2
    // (A0,B0,A1, issued ph2-4) may remain in flight.
    if (t + 2 < NT)
      asm volatile("s_waitcnt vmcnt(6)" ::: "memory");
    else
      asm volatile("s_waitcnt vmcnt(0)" ::: "memory");
    __builtin_amdgcn_s_barrier();
  }

  // ---- epilogue: scatter to q/k [b][h][t][d] or v [b][h][d][t] ----
  const int b = m0 >> 11;
  if (!vsec) {
    bf16* dst = ((n0 >> 10) == 0) ? q_ws : k_ws;
#pragma unroll
    for (int m = 0; m < 8; ++m) {
      const int mrow = (m0 & 2047) + wr * 128 + m * 16 + quad * 4;
#pragma unroll
      for (int n = 0; n < 4; ++n) {
        const int cc = (n0 & 1023) + wc * 64 + n * 16 + col;
        const int h = cc >> 6, d = cc & 63;
#pragma unroll
        for (int r = 0; r < 4; ++r)
          dst[(((size_t)b * NH_ + h) * T_ + mrow + r) * HS_ + d] =
              __float2bfloat16(acc[m][n][r]);
      }
    }
  } else {
#pragma unroll
    for (int m = 0; m < 8; ++m) {
      const int tloc = (m0 & 2047) + wr * 128 + m * 16 + col;
#pragma unroll
      for (int n = 0; n < 4; ++n) {
        const int vch = (n0 & 1023) + wc * 64 + n * 16 + quad * 4;
#pragma unroll
        for (int r = 0; r < 4; ++r) {
          const int h = (vch + r) >> 6, d = (vch + r) & 63;
          v_ws[(((size_t)b * NH_ + h) * HS_ + d) * T_ + tloc] =
              __float2bfloat16(acc[m][n][r]);
        }
      }
    }
  }
}

// ----------------------------------------------------------------------------
// gemm_bt (round 11): 128x128 tile, BK=32, double-buffered LDS, 2-phase.
// Used for the proj GEMM and the fp32 no-workspace fallback.
// ----------------------------------------------------------------------------
template <int IN_MODE, int OUT_MODE>
__global__ __launch_bounds__(256, 2) void gemm_bt(
    const void* __restrict__ A, const void* __restrict__ B, void* __restrict__ C,
    bf16* __restrict__ k_ws, bf16* __restrict__ v_ws,
    const unsigned short* __restrict__ in_probe,
    const unsigned short* __restrict__ out_probe, int M, int N, int K) {
  __shared__ bf16 As[2][128 * 32];
  __shared__ bf16 Bs[2][128 * 32];

  const bool f32b = in_probe ? detect_fp32(in_probe) : false;
  const bool f32a = (IN_MODE == 0) && f32b;
  const bool f32out =
      (OUT_MODE == 0) && (out_probe ? detect_fp32(out_probe) : false);

  const int tid = threadIdx.x;
  const int lane = tid & 63;
  const int wid = tid >> 6;
  const int quad = lane >> 4;
  const int col = lane & 15;
  const int m0 = blockIdx.y * 128;
  const int n0 = blockIdx.x * 128;
  const int wm = (wid >> 1) * 64;
  const int wn = (wid & 1) * 64;
  const bool vsec = (OUT_MODE == 1) && ((n0 >> 10) == 2);

  const size_t arow = (size_t)(m0 + (tid >> 2));
  const size_t brow = (size_t)(n0 + (tid >> 2));
  const int chunk = (tid & 3) * 8;
  const size_t astep = (IN_MODE == 0) ? (size_t)64 * K : (size_t)64 * HS_;

  f32x4 acc[4][4] = {};

  auto a_ptr = [&](int k0) -> const bf16* {
    if (IN_MODE == 0) return (const bf16*)A + arow * K + chunk + k0;
    const int b = m0 >> 11;
    const int tloc = (m0 & 2047) + (tid >> 2);
    return (const bf16*)A +
           ((((size_t)b * NH_) + (k0 >> 6)) * T_ + tloc) * HS_ + (k0 & 32) +
           chunk;
  };

  if (f32a) {
    uint4 a0 = ld8f(A, arow * K + chunk);
    uint4 a1 = ld8f(A, (arow + 64) * K + chunk);
    *(uint4*)(&As[0][0] + tid * 8) = a0;
    *(uint4*)(&As[0][0] + 2048 + tid * 8) = a1;
  } else {
    const bf16* ap = a_ptr(0);
    load_lds16(ap, &As[0][0] + tid * 8);
    load_lds16(ap + astep, &As[0][0] + 2048 + tid * 8);
  }
  if (f32b) {
    uint4 b0 = ld8f(B, brow * K + chunk);
    uint4 b1 = ld8f(B, (brow + 64) * K + chunk);
    *(uint4*)(&Bs[0][0] + tid * 8) = b0;
    *(uint4*)(&Bs[0][0] + 2048 + tid * 8) = b1;
  } else {
    load_lds16((const bf16*)B + brow * K + chunk, &Bs[0][0] + tid * 8);
    load_lds16((const bf16*)B + (brow + 64) * K + chunk,
               &Bs[0][0] + 2048 + tid * 8);
  }
  __syncthreads();

  int cur = 0;
  for (int k0 = 0; k0 < K; k0 += 32) {
    const int kn = k0 + 32;
    const bool hasn = kn < K;
    const int nxt = cur ^ 1;

    uint4 a0, a1, b0, b1;
    bool wra = false, wrb = false;
    if (hasn) {
      if (f32a) {
        a0 = ld8f(A, arow * K + chunk + kn);
        a1 = ld8f(A, (arow + 64) * K + chunk + kn);
        wra = true;
      } else {
        const bf16* ap = a_ptr(kn);
        load_lds16(ap, &As[nxt][0] + tid * 8);
        load_lds16(ap + astep, &As[nxt][0] + 2048 + tid * 8);
      }
      if (f32b) {
        b0 = ld8f(B, brow * K + chunk + kn);
        b1 = ld8f(B, (brow + 64) * K + chunk + kn);
        wrb = true;
      } else {
        load_lds16((const bf16*)B + brow * K + chunk + kn,
                   &Bs[nxt][0] + tid * 8);
        load_lds16((const bf16*)B + (brow + 64) * K + chunk + kn,
                   &Bs[nxt][0] + 2048 + tid * 8);
      }
    }

    bf16x8 af[4], bfr[4];
#pragma unroll
    for (int t = 0; t < 4; ++t) {
      af[t] = *(const bf16x8*)(&As[cur][0] + (wm + t * 16 + col) * 32 + quad * 8);
      bfr[t] = *(const bf16x8*)(&Bs[cur][0] + (wn + t * 16 + col) * 32 + quad * 8);
    }
    if (vsec) {
#pragma unroll
      for (int tm = 0; tm < 4; ++tm)
#pragma unroll
        for (int tn = 0; tn < 4; ++tn)
          acc[tm][tn] = __builtin_amdgcn_mfma_f32_16x16x32_bf16(
              bfr[tn], af[tm], acc[tm][tn], 0, 0, 0);
    } else {
#pragma unroll
      for (int tm = 0; tm < 4; ++tm)
#pragma unroll
        for (int tn = 0; tn < 4; ++tn)
          acc[tm][tn] = __builtin_amdgcn_mfma_f32_16x16x32_bf16(
              af[tm], bfr[tn], acc[tm][tn], 0, 0, 0);
    }

    if (wra) {
      *(uint4*)(&As[nxt][0] + tid * 8) = a0;
      *(uint4*)(&As[nxt][0] + 2048 + tid * 8) = a1;
    }
    if (wrb) {
      *(uint4*)(&Bs[nxt][0] + tid * 8) = b0;
      *(uint4*)(&Bs[nxt][0] + 2048 + tid * 8) = b1;
    }
    __syncthreads();
    cur = nxt;
  }

  if (OUT_MODE == 0) {
#pragma unroll
    for (int tm = 0; tm < 4; ++tm) {
      const int mrow = m0 + wm + tm * 16 + quad * 4;
#pragma unroll
      for (int tn = 0; tn < 4; ++tn) {
        const int ncol = n0 + wn + tn * 16 + col;
#pragma unroll
        for (int r = 0; r < 4; ++r) {
          if (f32out)
            ((float*)C)[(size_t)(mrow + r) * N + ncol] = acc[tm][tn][r];
          else
            ((bf16*)C)[(size_t)(mrow + r) * N + ncol] =
                __float2bfloat16(acc[tm][tn][r]);
        }
      }
    }
  } else if (vsec) {
    const int b = m0 >> 11;
#pragma unroll
    for (int tm = 0; tm < 4; ++tm) {
      const int tloc = (m0 & 2047) + wm + tm * 16 + col;
#pragma unroll
      for (int tn = 0; tn < 4; ++tn) {
        const int vch = (n0 & (C_ - 1)) + wn + tn * 16 + quad * 4;
#pragma unroll
        for (int r = 0; r < 4; ++r) {
          const int h = (vch + r) >> 6, d = (vch + r) & 63;
          v_ws[(((size_t)b * NH_ + h) * HS_ + d) * T_ + tloc] =
              __float2bfloat16(acc[tm][tn][r]);
        }
      }
    }
  } else {
    const int sect = n0 >> 10;  // 0:q 1:k
    bf16* dst = (sect == 0) ? (bf16*)C : k_ws;
#pragma unroll
    for (int tm = 0; tm < 4; ++tm) {
      const int mrow = m0 + wm + tm * 16 + quad * 4;
#pragma unroll
      for (int tn = 0; tn < 4; ++tn) {
        const int c = (n0 + wn + tn * 16 + col) & (C_ - 1);
        const int h = c >> 6, d = c & 63;
#pragma unroll
        for (int r = 0; r < 4; ++r) {
          const int t = (mrow + r) & (T_ - 1);
          const int b = (mrow + r) >> 11;
          dst[(((size_t)b * NH_ + h) * T_ + t) * HS_ + d] =
              __float2bfloat16(acc[tm][tn][r]);
        }
      }
    }
  }
}

// ----------------------------------------------------------------------------
// MFMA flash attention (causal), fixed-max softmax, split-K (round 10).
// ----------------------------------------------------------------------------
template <int SPLIT>
__global__ __launch_bounds__(256, 2) void attn(
    bf16* qy, const bf16* __restrict__ kws, const bf16* __restrict__ vws,
    float* __restrict__ po, float* __restrict__ pl) {
  __shared__ bf16 Ks[64 * 72];      // [key][d]
  __shared__ bf16 Vs[64 * 72];      // [d][key]
  __shared__ bf16 Ps[4][32 * 72];   // per-wave P [32 q][64 k], stride 72

  const int tid = threadIdx.x;
  const int lane = tid & 63;
  const int w = tid >> 6;
  const int quad = lane >> 4;
  const int col = lane & 15;
  const int x = (int)blockIdx.x;

  int qb, ck;
  if (SPLIT) {
    const unsigned long long lo = 0xC4D5E6F7FEDCBA98ULL;  // qb nibbles x0..15
    const unsigned int hi = 0xB3A29180u;                  // qb nibbles x16..23
    const unsigned int cmask = 0x00AAAA00u;               // chunk bit per x
    qb = (x < 16) ? (int)((lo >> (4 * x)) & 15)
                  : (int)((hi >> (4 * (x - 16))) & 15);
    ck = (int)((cmask >> x) & 1);
  } else {
    const int gx = (int)gridDim.x;  // 16
    const int hx = gx >> 1;
    qb = (x < hx) ? (gx - 1 - x) : (x - hx);
    ck = 0;
  }

  const int bh = blockIdx.y;
  const size_t head_off = (size_t)bh * T_ * HS_;

  const int ntall = 2 * (qb + 1);
  const int kt0 = SPLIT ? ck * 16 : 0;
  const int ntiles = SPLIT ? min(ntall - kt0, 16) : ntall;

  const int qrow = qb * 128 + w * 32 + col;
  const bf16* qp = qy + head_off + (size_t)qrow * HS_ + quad * 8;
  bf16x8 qf0a = *(const bf16x8*)(qp);
  bf16x8 qf1a = *(const bf16x8*)(qp + 32);
  bf16x8 qf0b = *(const bf16x8*)(qp + 16 * HS_);
  bf16x8 qf1b = *(const bf16x8*)(qp + 16 * HS_ + 32);
#pragma unroll
  for (int j = 0; j < 8; ++j) {
    qf0a[j] = (__bf16)((float)qf0a[j] * SCALE_LOG2E);
    qf1a[j] = (__bf16)((float)qf1a[j] * SCALE_LOG2E);
    qf0b[j] = (__bf16)((float)qf0b[j] * SCALE_LOG2E);
    qf1b[j] = (__bf16)((float)qf1b[j] * SCALE_LOG2E);
  }

  bf16x8 onesf;
#pragma unroll
  for (int j = 0; j < 8; ++j) onesf[j] = (__bf16)1.0f;

  f32x4 oa[4] = {}, ob[4] = {};
  f32x4 lacca = {}, laccb = {};

  bf16* pw = &Ps[w][0];

  const int srow = tid >> 3, sch = tid & 7;
  const bf16* kg = kws + head_off + (size_t)(kt0 * 64 + srow) * HS_ + sch * 8;
  const bf16* vg = vws + ((size_t)bh * HS_ + srow) * T_ + kt0 * 64 + sch * 8;
  bf16* kl0 = Ks + srow * 72 + sch * 8;
  bf16* kl1 = Ks + (srow + 32) * 72 + sch * 8;
  bf16* vl0 = Vs + srow * 72 + sch * 8;
  bf16* vl1 = Vs + (srow + 32) * 72 + sch * 8;

  uint4 kr0 = *(const uint4*)(kg);
  uint4 kr1 = *(const uint4*)(kg + (size_t)32 * HS_);
  uint4 vr0 = *(const uint4*)(vg);
  uint4 vr1 = *(const uint4*)(vg + (size_t)32 * T_);

  const int qga = qb * 128 + w * 32 + col;
  const int diag_start = 2 * qb;

  for (int kt = 0; kt < ntiles; ++kt) {
    const int ktg = kt0 + kt;
    const int k0 = ktg * 64;
    __syncthreads();
    *(uint4*)kl0 = kr0;
    *(uint4*)kl1 = kr1;
    *(uint4*)vl0 = vr0;
    *(uint4*)vl1 = vr1;
    __syncthreads();
    if (kt + 1 < ntiles) {
      kg += (size_t)64 * HS_;
      vg += 64;
      kr0 = *(const uint4*)(kg);
      kr1 = *(const uint4*)(kg + (size_t)32 * HS_);
      vr0 = *(const uint4*)(vg);
      vr1 = *(const uint4*)(vg + (size_t)32 * T_);
    }

    f32x4 sa[4], sb[4];
#pragma unroll
    for (int nt = 0; nt < 4; ++nt) {
      const bf16* kp = Ks + (nt * 16 + col) * 72 + quad * 8;
      bf16x8 kf0 = *(const bf16x8*)(kp);
      bf16x8 kf1 = *(const bf16x8*)(kp + 32);
      f32x4 a = {-32.0f, -32.0f, -32.0f, -32.0f};
      a = __builtin_amdgcn_mfma_f32_16x16x32_bf16(kf0, qf0a, a, 0, 0, 0);
      a = __builtin_amdgcn_mfma_f32_16x16x32_bf16(kf1, qf1a, a, 0, 0, 0);
      sa[nt] = a;
      f32x4 b = {-32.0f, -32.0f, -32.0f, -32.0f};
      b = __builtin_amdgcn_mfma_f32_16x16x32_bf16(kf0, qf0b, b, 0, 0, 0);
      b = __builtin_amdgcn_mfma_f32_16x16x32_bf16(kf1, qf1b, b, 0, 0, 0);
      sb[nt] = b;
    }

    if (ktg >= diag_start) {
#pragma unroll
      for (int nt = 0; nt < 4; ++nt) {
        const int key = k0 + nt * 16 + quad * 4;
#pragma unroll
        for (int r = 0; r < 4; ++r) {
          if (key + r > qga) sa[nt][r] = NEG_BIG;
          if (key + r > qga + 16) sb[nt][r] = NEG_BIG;
        }
      }
    }

#pragma unroll
    for (int nt = 0; nt < 4; ++nt) {
      union { ushort u[4]; uint2 v; } pa, pb;
#pragma unroll
      for (int r = 0; r < 4; ++r) {
        pa.u[r] = __bfloat16_as_ushort(__float2bfloat16(exp2f(sa[nt][r])));
        pb.u[r] = __bfloat16_as_ushort(__float2bfloat16(exp2f(sb[nt][r])));
      }
      *(uint2*)(pw + col * 72 + nt * 16 + quad * 4) = pa.v;
      *(uint2*)(pw + (col + 16) * 72 + nt * 16 + quad * 4) = pb.v;
    }

    __asm__ __volatile__("s_waitcnt lgkmcnt(0)" ::: "memory");

#pragma unroll
    for (int half = 0; half < 2; ++half) {
      bf16x8 pfa = *(const bf16x8*)(pw + col * 72 + half * 32 + quad * 8);
      bf16x8 pfb = *(const bf16x8*)(pw + (col + 16) * 72 + half * 32 + quad * 8);
      lacca = __builtin_amdgcn_mfma_f32_16x16x32_bf16(pfa, onesf, lacca, 0, 0, 0);
      laccb = __builtin_amdgcn_mfma_f32_16x16x32_bf16(pfb, onesf, laccb, 0, 0, 0);
#pragma unroll
      for (int dt = 0; dt < 4; ++dt) {
        bf16x8 vf = *(const bf16x8*)(Vs + (dt * 16 + col) * 72 + half * 32 +
                                     quad * 8);
        oa[dt] = __builtin_amdgcn_mfma_f32_16x16x32_bf16(pfa, vf, oa[dt], 0, 0, 0);
        ob[dt] = __builtin_amdgcn_mfma_f32_16x16x32_bf16(pfb, vf, ob[dt], 0, 0, 0);
      }
    }
  }

  const bool dosplit = SPLIT && (qb >= 8);
  if (!dosplit) {
    float inva[4], invb[4];
#pragma unroll
    for (int r = 0; r < 4; ++r) {
      inva[r] = 1.0f / lacca[r];
      invb[r] = 1.0f / laccb[r];
    }
#pragma unroll
    for (int dt = 0; dt < 4; ++dt)
#pragma unroll
      for (int r = 0; r < 4; ++r) {
        const int qa = qb * 128 + w * 32 + quad * 4 + r;
        qy[head_off + (size_t)qa * HS_ + dt * 16 + col] =
            __float2bfloat16(oa[dt][r] * inva[r]);
        qy[head_off + (size_t)(qa + 16) * HS_ + dt * 16 + col] =
            __float2bfloat16(ob[dt][r] * invb[r]);
      }
  } else {
    const int slot = ((qb - 8) * 64 + bh) * 2 + ck;
    float* o = po + (size_t)slot * (128 * 64);
#pragma unroll
    for (int dt = 0; dt < 4; ++dt)
#pragma unroll
      for (int r = 0; r < 4; ++r) {
        const int qa = w * 32 + quad * 4 + r;
        o[(size_t)qa * 64 + dt * 16 + col] = oa[dt][r];
        o[(size_t)(qa + 16) * 64 + dt * 16 + col] = ob[dt][r];
      }
    if (col == 0) {
      float* lp = pl + (size_t)slot * 128;
#pragma unroll
      for (int r = 0; r < 4; ++r) {
        lp[w * 32 + quad * 4 + r] = lacca[r];
        lp[w * 32 + 16 + quad * 4 + r] = laccb[r];
      }
    }
  }
}

// ----------------------------------------------------------------------------
// Combine: for qb>=8, y = (O0+O1)/(l0+l1).
// ----------------------------------------------------------------------------
__global__ __launch_bounds__(256) void attn_combine(
    bf16* __restrict__ qy, const float* __restrict__ po,
    const float* __restrict__ pl) {
  const int qb = 8 + (int)blockIdx.x;  // 8..15
  const int bh = (int)blockIdx.y;
  const int pair = ((qb - 8) * 64 + bh) * 2;
  const float* o0 = po + (size_t)pair * (128 * 64);
  const float* o1 = o0 + 128 * 64;
  const float* l0 = pl + (size_t)pair * 128;
  const float* l1 = l0 + 128;
  const int q = threadIdx.x >> 1;
  const int d0 = (threadIdx.x & 1) * 32;
  const float inv = 1.0f / (l0[q] + l1[q]);
  const size_t base =
      (size_t)bh * T_ * HS_ + (size_t)(qb * 128 + q) * HS_ + d0;
  const size_t ob = (size_t)q * 64 + d0;
#pragma unroll
  for (int j0 = 0; j0 < 32; j0 += 8) {
    union { bf16 h[8]; uint4 u; } out;
#pragma unroll
    for (int j = 0; j < 8; ++j)
      out.h[j] = __float2bfloat16((o0[ob + j0 + j] + o1[ob + j0 + j]) * inv);
    *(uint4*)(qy + base + j0) = out.u;
  }
}

// ----------------------------------------------------------------------------
extern "C" void kernel_launch(void* const* d_in, const int* in_sizes, int n_in,
                              void* d_out, int out_size, void* d_ws, size_t ws_size,
                              hipStream_t stream) {
  const void* x = d_in[0];       // [4,2048,1024] fp32 (probed)
  const void* W_attn = d_in[1];  // [3072,1024]
  const void* W_proj = d_in[2];  // [1024,1024]
  const unsigned short* probe = (const unsigned short*)d_in[0];
  // d_in[3..6]: dead code in the reference.

  const size_t qkv_elems = (size_t)B_ * NH_ * T_ * HS_;  // 8388608
  const size_t xe = (size_t)B_ * T_ * C_;                // 8388608
  const size_t wae = (size_t)3 * C_ * C_;                // 3145728
  const size_t wpe = (size_t)C_ * C_;                    // 1048576

  bf16* q_ws = (bf16*)d_ws;
  bf16* k_ws = q_ws + qkv_elems;
  bf16* v_ws = k_ws + qkv_elems;
  bf16* x_bf = v_ws + qkv_elems;
  bf16* wa_bf = x_bf + xe;
  bf16* wp_bf = wa_bf + wae;
  const size_t need = (3 * qkv_elems + xe + wae + wpe) * sizeof(bf16);  // 72 MiB

  // split-K partials: 1024 slots x (128x64 O + 128 l) f32 = 32.5 MiB
  float* po = (float*)(wp_bf + wpe);
  float* pl = po + (size_t)1024 * 128 * 64;
  const size_t need2 =
      need + ((size_t)1024 * 128 * 64 + (size_t)1024 * 128) * sizeof(float);

  const int M = B_ * T_;  // 8192

  if (ws_size >= need) {
    convert3<<<6144, 256, 0, stream>>>(x, W_attn, W_proj, x_bf, wa_bf, wp_bf,
                                       probe);
    gemm8_qkv<<<dim3(12, 32), 512, 0, stream>>>(x_bf, wa_bf, q_ws, k_ws, v_ws);
    if (ws_size >= need2) {
      attn<1><<<dim3(24, B_ * NH_), 256, 0, stream>>>(q_ws, k_ws, v_ws, po, pl);
      attn_combine<<<dim3(8, B_ * NH_), 256, 0, stream>>>(q_ws, po, pl);
    } else {
      attn<0><<<dim3(T_ / 128, B_ * NH_), 256, 0, stream>>>(q_ws, k_ws, v_ws,
                                                            nullptr, nullptr);
    }
    gemm_bt<1, 0><<<dim3(C_ / 128, M / 128), 256, 0, stream>>>(
        q_ws, wp_bf, d_out, nullptr, nullptr, nullptr, probe, M, C_, C_);
  } else {
    gemm_bt<0, 1><<<dim3(3 * C_ / 128, M / 128), 256, 0, stream>>>(
        x, W_attn, q_ws, k_ws, v_ws, probe, nullptr, M, 3 * C_, C_);
    attn<0><<<dim3(T_ / 128, B_ * NH_), 256, 0, stream>>>(q_ws, k_ws, v_ws,
                                                          nullptr, nullptr);
    gemm_bt<1, 0><<<dim3(C_ / 128, M / 128), 256, 0, stream>>>(
        q_ws, W_proj, d_out, nullptr, nullptr, probe, probe, M, C_, C_);
  }
}

// Round 8
// 279.373 us; speedup vs baseline: 1.8332x; 1.8226x over previous
//
#include <hip/hip_runtime.h>
#include <hip/hip_bf16.h>
#include <stdint.h>

// ============================================================================
// MultiAttentionWithGating — compression branch (_kc/_vc) is DEAD CODE.
// Pipeline: qkv = x@W_attn^T ; causal SDPA (16 heads, hs=64) ; out = y@W_proj^T
// Inputs fp32 (runtime-probed); internal bf16 MFMA, fp32 accum.
//
// ROUND 14 (launch_bounds(512,1) did NOT lift the 128-VGPR cap: counters
// bit-identical to round 12, acc[8][4]=128 VGPR = whole budget -> spill):
//  - Stop fighting the allocator; fit the cap. gemm8_qkv tile 256x256 ->
//    256x128 (BM=256, BN=128), 8 waves as 4Mx2N, per-wave 64x64:
//    acc[4][4] = 64 VGPR, total ~115 < 128 under ANY allocator behavior.
//  - LDS 96 KiB (A 64K + B 32K), still 1 WG/CU. Grid 24x32 = 768 blocks =
//    exactly 3 CU-rounds; XCD swizzle bijective (768%8==0).
//  - Staging: A 2 loads/half, B 1 load/half -> boundary vmcnt(5)
//    (A0+B0+A1 of t+2 in flight); prologue 11 loads, vmcnt(5).
//    Phase/barrier skeleton, both-sides LDS swizzle (conflicts 0, verified
//    r12), race schedule unchanged in structure.
//  - Everything else identical to round 13.
// ============================================================================

typedef __bf16 bf16x8 __attribute__((ext_vector_type(8)));
typedef float f32x4 __attribute__((ext_vector_type(4)));
typedef __hip_bfloat16 bf16;

#define B_ 4
#define T_ 2048
#define C_ 1024
#define NH_ 16
#define HS_ 64
#define NEG_BIG (-30000.0f)
#define SCALE_LOG2E 0.180336880111f  // (1/sqrt(64)) * log2(e)

// Wave-uniform dtype probe on x (fp32 vs bf16), verified round 4.
__device__ __forceinline__ bool detect_fp32(const unsigned short* px) {
  const int lane = threadIdx.x & 63;
  const unsigned short u = px[2 * lane];
  const int e = (u >> 7) & 0xff;
  const bool plausible = (e >= 117) && (e <= 137);
  return __popcll(__ballot(plausible)) < 32;
}

// async global->LDS 16B per lane (m97). LDS dest: wave-uniform base + lane*16.
__device__ __forceinline__ void load_lds16(const bf16* g, bf16* l) {
  __builtin_amdgcn_global_load_lds(
      (const __attribute__((address_space(1))) void*)(uintptr_t)g,
      (__attribute__((address_space(3))) void*)(uintptr_t)l, 16, 0, 0);
}

// fp32 load of 8 elements -> 8 bf16 packed in uint4.
__device__ __forceinline__ uint4 ld8f(const void* base, size_t elt) {
  const float* fp = (const float*)base + elt;
  float4 f0 = *(const float4*)(fp);
  float4 f1 = *(const float4*)(fp + 4);
  union { bf16 h[8]; uint4 u; } r;
  r.h[0] = __float2bfloat16(f0.x); r.h[1] = __float2bfloat16(f0.y);
  r.h[2] = __float2bfloat16(f0.z); r.h[3] = __float2bfloat16(f0.w);
  r.h[4] = __float2bfloat16(f1.x); r.h[5] = __float2bfloat16(f1.y);
  r.h[6] = __float2bfloat16(f1.z); r.h[7] = __float2bfloat16(f1.w);
  return r.u;
}

// ----------------------------------------------------------------------------
// One-shot fp32->bf16 conversion of x, W_attn, W_proj (8 elems/thread).
// ----------------------------------------------------------------------------
__global__ __launch_bounds__(256) void convert3(
    const void* __restrict__ x, const void* __restrict__ wa,
    const void* __restrict__ wp, bf16* __restrict__ xb, bf16* __restrict__ wab,
    bf16* __restrict__ wpb, const unsigned short* __restrict__ probe) {
  const bool f32 = detect_fp32(probe);
  int blk = blockIdx.x;
  const void* src;
  bf16* dst;
  if (blk < 4096) {
    src = x; dst = xb;
  } else if (blk < 4096 + 1536) {
    blk -= 4096; src = wa; dst = wab;
  } else {
    blk -= 4096 + 1536; src = wp; dst = wpb;
  }
  const size_t i = ((size_t)blk * 256 + threadIdx.x) * 8;
  if (f32)
    *(uint4*)(dst + i) = ld8f(src, i);
  else
    *(uint4*)(dst + i) = *(const uint4*)((const bf16*)src + i);
}

// ----------------------------------------------------------------------------
// gemm8_qkv: 8-phase 256x128 bf16 GEMM for qkv = x_bf @ wa_bf^T.
// A = x_bf [8192][1024], B = wa_bf [3072][1024] (both K-major).
// 8 waves = 4Mx2N, per-wave 64x64 out -> acc[4][4] = 64 VGPR (fits the
// observed 128-VGPR cap without spill). LDS 96 KiB.
// Output scattered to q_ws/k_ws [b][h][t][d] and v_ws [b][h][d][t].
// ----------------------------------------------------------------------------
__global__ __launch_bounds__(512, 1) void gemm8_qkv(
    const bf16* __restrict__ A, const bf16* __restrict__ Bm,
    bf16* __restrict__ q_ws, bf16* __restrict__ k_ws,
    bf16* __restrict__ v_ws) {
  __shared__ bf16 Asm[2][2][256][32];  // 64 KiB
  __shared__ bf16 Bsm[2][2][128][32];  // 32 KiB

  const int tid = threadIdx.x;
  const int lane = tid & 63;
  const int wid = tid >> 6;    // 0..7
  const int wr = wid >> 1;     // 0..3  (64-row band)
  const int wc = wid & 1;      // 0..1  (64-col band)
  const int quad = lane >> 4;  // 0..3
  const int col = lane & 15;

  // XCD-bijective swizzle on flattened 24x32 grid (768 % 8 == 0).
  const int flat = (int)blockIdx.y * 24 + (int)blockIdx.x;
  const int swz = (flat & 7) * 96 + (flat >> 3);
  const int n0 = (swz % 24) * 128;
  const int m0 = (swz / 24) * 256;
  const bool vsec = (n0 >> 10) == 2;

  constexpr int NT = 16;  // K-tiles of BK=64

  // A staging: 1024 16B chunks (256 rows x 4 slots); thread covers c0, c1.
  // Swizzle involution on 16B slots: slot ^= (row>>1)&3, applied to the
  // global SOURCE (gload_lds dest is linear) and to ds_read (rule #21).
  const int c0 = tid, c1 = 512 + tid;
  const int r0 = c0 >> 2, s0 = (c0 & 3) ^ ((r0 >> 1) & 3);
  const int r1 = c1 >> 2, s1 = (c1 & 3) ^ ((r1 >> 1) & 3);
  const size_t ga0 = (size_t)(m0 + r0) * 1024 + s0 * 8;
  const size_t ga1 = (size_t)(m0 + r1) * 1024 + s1 * 8;
  // B staging: 512 chunks (128 rows x 4 slots); thread covers chunk tid.
  const int rb = tid >> 2, sb = (tid & 3) ^ ((rb >> 1) & 3);
  const size_t gb = (size_t)(n0 + rb) * 1024 + sb * 8;

  auto stageA = [&](int T, int h) {
    bf16* base = &Asm[T & 1][h][0][0];
    const int kk = T * 64 + h * 32;
    load_lds16(A + ga0 + kk, base + c0 * 8);
    load_lds16(A + ga1 + kk, base + c1 * 8);
  };
  auto stageB = [&](int T, int h) {
    bf16* base = &Bsm[T & 1][h][0][0];
    const int kk = T * 64 + h * 32;
    load_lds16(Bm + gb + kk, base + tid * 8);
  };

  // ds_read slot swizzle: slot' = quad ^ ((row>>1)&3); row = 16*frag + col.
  const int aq = quad ^ ((col >> 1) & 3);

  f32x4 acc[4][4] = {};
  bf16x8 pA[4];

  // ---- prologue: tile 0 (6 loads) + A0,B0,A1 of tile 1 (5 loads) ----
  stageA(0, 0); stageB(0, 0); stageA(0, 1); stageB(0, 1);
  stageA(1, 0); stageB(1, 0); stageA(1, 1);
  asm volatile("s_waitcnt vmcnt(5)" ::: "memory");  // tile 0 resident
  __builtin_amdgcn_s_barrier();

  for (int t = 0; t < NT; ++t) {
    const bf16* Ab = (const bf16*)Asm + (t & 1) * 16384;
    const bf16* Bb = (const bf16*)Bsm + (t & 1) * 8192;

    // ======== phase 1: ks=0, n0-1 ; stage B1(t+1) ========
#pragma unroll
    for (int m = 0; m < 4; ++m)
      pA[m] = *(const bf16x8*)(Ab + (wr * 64 + m * 16 + col) * 32 + aq * 8);
    bf16x8 b0 = *(const bf16x8*)(Bb + (wc * 64 + 0 + col) * 32 + aq * 8);
    bf16x8 b1 = *(const bf16x8*)(Bb + (wc * 64 + 16 + col) * 32 + aq * 8);
    if (t + 1 < NT) stageB(t + 1, 1);
    __builtin_amdgcn_s_barrier();
    asm volatile("s_waitcnt lgkmcnt(0)" ::: "memory");
    __builtin_amdgcn_s_setprio(1);
    if (vsec) {
#pragma unroll
      for (int m = 0; m < 4; ++m) {
        acc[m][0] = __builtin_amdgcn_mfma_f32_16x16x32_bf16(b0, pA[m], acc[m][0], 0, 0, 0);
        acc[m][1] = __builtin_amdgcn_mfma_f32_16x16x32_bf16(b1, pA[m], acc[m][1], 0, 0, 0);
      }
    } else {
#pragma unroll
      for (int m = 0; m < 4; ++m) {
        acc[m][0] = __builtin_amdgcn_mfma_f32_16x16x32_bf16(pA[m], b0, acc[m][0], 0, 0, 0);
        acc[m][1] = __builtin_amdgcn_mfma_f32_16x16x32_bf16(pA[m], b1, acc[m][1], 0, 0, 0);
      }
    }
    __builtin_amdgcn_s_setprio(0);
    __builtin_amdgcn_s_barrier();

    // ======== phase 2: ks=0, n2-3 (pA reused) ; stage A0(t+2) ========
    bf16x8 b2 = *(const bf16x8*)(Bb + (wc * 64 + 32 + col) * 32 + aq * 8);
    bf16x8 b3 = *(const bf16x8*)(Bb + (wc * 64 + 48 + col) * 32 + aq * 8);
    if (t + 2 < NT) stageA(t + 2, 0);
    __builtin_amdgcn_s_barrier();
    asm volatile("s_waitcnt lgkmcnt(0)" ::: "memory");
    __builtin_amdgcn_s_setprio(1);
    if (vsec) {
#pragma unroll
      for (int m = 0; m < 4; ++m) {
        acc[m][2] = __builtin_amdgcn_mfma_f32_16x16x32_bf16(b2, pA[m], acc[m][2], 0, 0, 0);
        acc[m][3] = __builtin_amdgcn_mfma_f32_16x16x32_bf16(b3, pA[m], acc[m][3], 0, 0, 0);
      }
    } else {
#pragma unroll
      for (int m = 0; m < 4; ++m) {
        acc[m][2] = __builtin_amdgcn_mfma_f32_16x16x32_bf16(pA[m], b2, acc[m][2], 0, 0, 0);
        acc[m][3] = __builtin_amdgcn_mfma_f32_16x16x32_bf16(pA[m], b3, acc[m][3], 0, 0, 0);
      }
    }
    __builtin_amdgcn_s_setprio(0);
    __builtin_amdgcn_s_barrier();

    // ======== phase 3: ks=1, n0-1 ; stage B0(t+2) ========
    Ab += 8192;
    Bb += 4096;
#pragma unroll
    for (int m = 0; m < 4; ++m)
      pA[m] = *(const bf16x8*)(Ab + (wr * 64 + m * 16 + col) * 32 + aq * 8);
    b0 = *(const bf16x8*)(Bb + (wc * 64 + 0 + col) * 32 + aq * 8);
    b1 = *(const bf16x8*)(Bb + (wc * 64 + 16 + col) * 32 + aq * 8);
    if (t + 2 < NT) stageB(t + 2, 0);
    __builtin_amdgcn_s_barrier();
    asm volatile("s_waitcnt lgkmcnt(0)" ::: "memory");
    __builtin_amdgcn_s_setprio(1);
    if (vsec) {
#pragma unroll
      for (int m = 0; m < 4; ++m) {
        acc[m][0] = __builtin_amdgcn_mfma_f32_16x16x32_bf16(b0, pA[m], acc[m][0], 0, 0, 0);
        acc[m][1] = __builtin_amdgcn_mfma_f32_16x16x32_bf16(b1, pA[m], acc[m][1], 0, 0, 0);
      }
    } else {
#pragma unroll
      for (int m = 0; m < 4; ++m) {
        acc[m][0] = __builtin_amdgcn_mfma_f32_16x16x32_bf16(pA[m], b0, acc[m][0], 0, 0, 0);
        acc[m][1] = __builtin_amdgcn_mfma_f32_16x16x32_bf16(pA[m], b1, acc[m][1], 0, 0, 0);
      }
    }
    __builtin_amdgcn_s_setprio(0);
    __builtin_amdgcn_s_barrier();

    // ======== phase 4: ks=1, n2-3 ; stage A1(t+2) ; boundary vmcnt ========
    b2 = *(const bf16x8*)(Bb + (wc * 64 + 32 + col) * 32 + aq * 8);
    b3 = *(const bf16x8*)(Bb + (wc * 64 + 48 + col) * 32 + aq * 8);
    if (t + 2 < NT) stageA(t + 2, 1);
    __builtin_amdgcn_s_barrier();
    asm volatile("s_waitcnt lgkmcnt(0)" ::: "memory");
    __builtin_amdgcn_s_setprio(1);
    if (vsec) {
#pragma unroll
      for (int m = 0; m < 4; ++m) {
        acc[m][2] = __builtin_amdgcn_mfma_f32_16x16x32_bf16(b2, pA[m], acc[m][2], 0, 0, 0);
        acc[m][3] = __builtin_amdgcn_mfma_f32_16x16x32_bf16(b3, pA[m], acc[m][3], 0, 0, 0);
      }
    } else {
#pragma unroll
      for (int m = 0; m < 4; ++m) {
        acc[m][2] = __builtin_amdgcn_mfma_f32_16x16x32_bf16(pA[m], b2, acc[m][2], 0, 0, 0);
        acc[m][3] = __builtin_amdgcn_mfma_f32_16x16x32_bf16(pA[m], b3, acc[m][3], 0, 0, 0);
      }
    }
    __builtin_amdgcn_s_setprio(0);
    // tile t+1 fully resident (its last piece B1(t+1) was issued ph1 of t);
    // the 5 in-flight loads are A0,B0,A1 of t+2 (2+1+2), issued ph2-4.
    if (t + 2 < NT)
      asm volatile("s_waitcnt vmcnt(5)" ::: "memory");
    else
      asm volatile("s_waitcnt vmcnt(0)" ::: "memory");
    __builtin_amdgcn_s_barrier();
  }

  // ---- epilogue: scatter to q/k [b][h][t][d] or v [b][h][d][t] ----
  const int b = m0 >> 11;
  if (!vsec) {
    bf16* dst = ((n0 >> 10) == 0) ? q_ws : k_ws;
#pragma unroll
    for (int m = 0; m < 4; ++m) {
      const int mrow = (m0 & 2047) + wr * 64 + m * 16 + quad * 4;
#pragma unroll
      for (int n = 0; n < 4; ++n) {
        const int cc = (n0 & 1023) + wc * 64 + n * 16 + col;
        const int h = cc >> 6, d = cc & 63;
#pragma unroll
        for (int r = 0; r < 4; ++r)
          dst[(((size_t)b * NH_ + h) * T_ + mrow + r) * HS_ + d] =
              __float2bfloat16(acc[m][n][r]);
      }
    }
  } else {
#pragma unroll
    for (int m = 0; m < 4; ++m) {
      const int tloc = (m0 & 2047) + wr * 64 + m * 16 + col;
#pragma unroll
      for (int n = 0; n < 4; ++n) {
        const int vch = (n0 & 1023) + wc * 64 + n * 16 + quad * 4;
#pragma unroll
        for (int r = 0; r < 4; ++r) {
          const int h = (vch + r) >> 6, d = (vch + r) & 63;
          v_ws[(((size_t)b * NH_ + h) * HS_ + d) * T_ + tloc] =
              __float2bfloat16(acc[m][n][r]);
        }
      }
    }
  }
}

// ----------------------------------------------------------------------------
// gemm_bt (round 11): 128x128 tile, BK=32, double-buffered LDS, 2-phase.
// Used for the proj GEMM and the fp32 no-workspace fallback.
// ----------------------------------------------------------------------------
template <int IN_MODE, int OUT_MODE>
__global__ __launch_bounds__(256, 2) void gemm_bt(
    const void* __restrict__ A, const void* __restrict__ B, void* __restrict__ C,
    bf16* __restrict__ k_ws, bf16* __restrict__ v_ws,
    const unsigned short* __restrict__ in_probe,
    const unsigned short* __restrict__ out_probe, int M, int N, int K) {
  __shared__ bf16 As[2][128 * 32];
  __shared__ bf16 Bs[2][128 * 32];

  const bool f32b = in_probe ? detect_fp32(in_probe) : false;
  const bool f32a = (IN_MODE == 0) && f32b;
  const bool f32out =
      (OUT_MODE == 0) && (out_probe ? detect_fp32(out_probe) : false);

  const int tid = threadIdx.x;
  const int lane = tid & 63;
  const int wid = tid >> 6;
  const int quad = lane >> 4;
  const int col = lane & 15;
  const int m0 = blockIdx.y * 128;
  const int n0 = blockIdx.x * 128;
  const int wm = (wid >> 1) * 64;
  const int wn = (wid & 1) * 64;
  const bool vsec = (OUT_MODE == 1) && ((n0 >> 10) == 2);

  const size_t arow = (size_t)(m0 + (tid >> 2));
  const size_t brow = (size_t)(n0 + (tid >> 2));
  const int chunk = (tid & 3) * 8;
  const size_t astep = (IN_MODE == 0) ? (size_t)64 * K : (size_t)64 * HS_;

  f32x4 acc[4][4] = {};

  auto a_ptr = [&](int k0) -> const bf16* {
    if (IN_MODE == 0) return (const bf16*)A + arow * K + chunk + k0;
    const int b = m0 >> 11;
    const int tloc = (m0 & 2047) + (tid >> 2);
    return (const bf16*)A +
           ((((size_t)b * NH_) + (k0 >> 6)) * T_ + tloc) * HS_ + (k0 & 32) +
           chunk;
  };

  if (f32a) {
    uint4 a0 = ld8f(A, arow * K + chunk);
    uint4 a1 = ld8f(A, (arow + 64) * K + chunk);
    *(uint4*)(&As[0][0] + tid * 8) = a0;
    *(uint4*)(&As[0][0] + 2048 + tid * 8) = a1;
  } else {
    const bf16* ap = a_ptr(0);
    load_lds16(ap, &As[0][0] + tid * 8);
    load_lds16(ap + astep, &As[0][0] + 2048 + tid * 8);
  }
  if (f32b) {
    uint4 b0 = ld8f(B, brow * K + chunk);
    uint4 b1 = ld8f(B, (brow + 64) * K + chunk);
    *(uint4*)(&Bs[0][0] + tid * 8) = b0;
    *(uint4*)(&Bs[0][0] + 2048 + tid * 8) = b1;
  } else {
    load_lds16((const bf16*)B + brow * K + chunk, &Bs[0][0] + tid * 8);
    load_lds16((const bf16*)B + (brow + 64) * K + chunk,
               &Bs[0][0] + 2048 + tid * 8);
  }
  __syncthreads();

  int cur = 0;
  for (int k0 = 0; k0 < K; k0 += 32) {
    const int kn = k0 + 32;
    const bool hasn = kn < K;
    const int nxt = cur ^ 1;

    uint4 a0, a1, b0, b1;
    bool wra = false, wrb = false;
    if (hasn) {
      if (f32a) {
        a0 = ld8f(A, arow * K + chunk + kn);
        a1 = ld8f(A, (arow + 64) * K + chunk + kn);
        wra = true;
      } else {
        const bf16* ap = a_ptr(kn);
        load_lds16(ap, &As[nxt][0] + tid * 8);
        load_lds16(ap + astep, &As[nxt][0] + 2048 + tid * 8);
      }
      if (f32b) {
        b0 = ld8f(B, brow * K + chunk + kn);
        b1 = ld8f(B, (brow + 64) * K + chunk + kn);
        wrb = true;
      } else {
        load_lds16((const bf16*)B + brow * K + chunk + kn,
                   &Bs[nxt][0] + tid * 8);
        load_lds16((const bf16*)B + (brow + 64) * K + chunk + kn,
                   &Bs[nxt][0] + 2048 + tid * 8);
      }
    }

    bf16x8 af[4], bfr[4];
#pragma unroll
    for (int t = 0; t < 4; ++t) {
      af[t] = *(const bf16x8*)(&As[cur][0] + (wm + t * 16 + col) * 32 + quad * 8);
      bfr[t] = *(const bf16x8*)(&Bs[cur][0] + (wn + t * 16 + col) * 32 + quad * 8);
    }
    if (vsec) {
#pragma unroll
      for (int tm = 0; tm < 4; ++tm)
#pragma unroll
        for (int tn = 0; tn < 4; ++tn)
          acc[tm][tn] = __builtin_amdgcn_mfma_f32_16x16x32_bf16(
              bfr[tn], af[tm], acc[tm][tn], 0, 0, 0);
    } else {
#pragma unroll
      for (int tm = 0; tm < 4; ++tm)
#pragma unroll
        for (int tn = 0; tn < 4; ++tn)
          acc[tm][tn] = __builtin_amdgcn_mfma_f32_16x16x32_bf16(
              af[tm], bfr[tn], acc[tm][tn], 0, 0, 0);
    }

    if (wra) {
      *(uint4*)(&As[nxt][0] + tid * 8) = a0;
      *(uint4*)(&As[nxt][0] + 2048 + tid * 8) = a1;
    }
    if (wrb) {
      *(uint4*)(&Bs[nxt][0] + tid * 8) = b0;
      *(uint4*)(&Bs[nxt][0] + 2048 + tid * 8) = b1;
    }
    __syncthreads();
    cur = nxt;
  }

  if (OUT_MODE == 0) {
#pragma unroll
    for (int tm = 0; tm < 4; ++tm) {
      const int mrow = m0 + wm + tm * 16 + quad * 4;
#pragma unroll
      for (int tn = 0; tn < 4; ++tn) {
        const int ncol = n0 + wn + tn * 16 + col;
#pragma unroll
        for (int r = 0; r < 4; ++r) {
          if (f32out)
            ((float*)C)[(size_t)(mrow + r) * N + ncol] = acc[tm][tn][r];
          else
            ((bf16*)C)[(size_t)(mrow + r) * N + ncol] =
                __float2bfloat16(acc[tm][tn][r]);
        }
      }
    }
  } else if (vsec) {
    const int b = m0 >> 11;
#pragma unroll
    for (int tm = 0; tm < 4; ++tm) {
      const int tloc = (m0 & 2047) + wm + tm * 16 + col;
#pragma unroll
      for (int tn = 0; tn < 4; ++tn) {
        const int vch = (n0 & (C_ - 1)) + wn + tn * 16 + quad * 4;
#pragma unroll
        for (int r = 0; r < 4; ++r) {
          const int h = (vch + r) >> 6, d = (vch + r) & 63;
          v_ws[(((size_t)b * NH_ + h) * HS_ + d) * T_ + tloc] =
              __float2bfloat16(acc[tm][tn][r]);
        }
      }
    }
  } else {
    const int sect = n0 >> 10;  // 0:q 1:k
    bf16* dst = (sect == 0) ? (bf16*)C : k_ws;
#pragma unroll
    for (int tm = 0; tm < 4; ++tm) {
      const int mrow = m0 + wm + tm * 16 + quad * 4;
#pragma unroll
      for (int tn = 0; tn < 4; ++tn) {
        const int c = (n0 + wn + tn * 16 + col) & (C_ - 1);
        const int h = c >> 6, d = c & 63;
#pragma unroll
        for (int r = 0; r < 4; ++r) {
          const int t = (mrow + r) & (T_ - 1);
          const int b = (mrow + r) >> 11;
          dst[(((size_t)b * NH_ + h) * T_ + t) * HS_ + d] =
              __float2bfloat16(acc[tm][tn][r]);
        }
      }
    }
  }
}

// ----------------------------------------------------------------------------
// MFMA flash attention (causal), fixed-max softmax, split-K (round 10).
// ----------------------------------------------------------------------------
template <int SPLIT>
__global__ __launch_bounds__(256, 2) void attn(
    bf16* qy, const bf16* __restrict__ kws, const bf16* __restrict__ vws,
    float* __restrict__ po, float* __restrict__ pl) {
  __shared__ bf16 Ks[64 * 72];      // [key][d]
  __shared__ bf16 Vs[64 * 72];      // [d][key]
  __shared__ bf16 Ps[4][32 * 72];   // per-wave P [32 q][64 k], stride 72

  const int tid = threadIdx.x;
  const int lane = tid & 63;
  const int w = tid >> 6;
  const int quad = lane >> 4;
  const int col = lane & 15;
  const int x = (int)blockIdx.x;

  int qb, ck;
  if (SPLIT) {
    const unsigned long long lo = 0xC4D5E6F7FEDCBA98ULL;  // qb nibbles x0..15
    const unsigned int hi = 0xB3A29180u;                  // qb nibbles x16..23
    const unsigned int cmask = 0x00AAAA00u;               // chunk bit per x
    qb = (x < 16) ? (int)((lo >> (4 * x)) & 15)
                  : (int)((hi >> (4 * (x - 16))) & 15);
    ck = (int)((cmask >> x) & 1);
  } else {
    const int gx = (int)gridDim.x;  // 16
    const int hx = gx >> 1;
    qb = (x < hx) ? (gx - 1 - x) : (x - hx);
    ck = 0;
  }

  const int bh = blockIdx.y;
  const size_t head_off = (size_t)bh * T_ * HS_;

  const int ntall = 2 * (qb + 1);
  const int kt0 = SPLIT ? ck * 16 : 0;
  const int ntiles = SPLIT ? min(ntall - kt0, 16) : ntall;

  const int qrow = qb * 128 + w * 32 + col;
  const bf16* qp = qy + head_off + (size_t)qrow * HS_ + quad * 8;
  bf16x8 qf0a = *(const bf16x8*)(qp);
  bf16x8 qf1a = *(const bf16x8*)(qp + 32);
  bf16x8 qf0b = *(const bf16x8*)(qp + 16 * HS_);
  bf16x8 qf1b = *(const bf16x8*)(qp + 16 * HS_ + 32);
#pragma unroll
  for (int j = 0; j < 8; ++j) {
    qf0a[j] = (__bf16)((float)qf0a[j] * SCALE_LOG2E);
    qf1a[j] = (__bf16)((float)qf1a[j] * SCALE_LOG2E);
    qf0b[j] = (__bf16)((float)qf0b[j] * SCALE_LOG2E);
    qf1b[j] = (__bf16)((float)qf1b[j] * SCALE_LOG2E);
  }

  bf16x8 onesf;
#pragma unroll
  for (int j = 0; j < 8; ++j) onesf[j] = (__bf16)1.0f;

  f32x4 oa[4] = {}, ob[4] = {};
  f32x4 lacca = {}, laccb = {};

  bf16* pw = &Ps[w][0];

  const int srow = tid >> 3, sch = tid & 7;
  const bf16* kg = kws + head_off + (size_t)(kt0 * 64 + srow) * HS_ + sch * 8;
  const bf16* vg = vws + ((size_t)bh * HS_ + srow) * T_ + kt0 * 64 + sch * 8;
  bf16* kl0 = Ks + srow * 72 + sch * 8;
  bf16* kl1 = Ks + (srow + 32) * 72 + sch * 8;
  bf16* vl0 = Vs + srow * 72 + sch * 8;
  bf16* vl1 = Vs + (srow + 32) * 72 + sch * 8;

  uint4 kr0 = *(const uint4*)(kg);
  uint4 kr1 = *(const uint4*)(kg + (size_t)32 * HS_);
  uint4 vr0 = *(const uint4*)(vg);
  uint4 vr1 = *(const uint4*)(vg + (size_t)32 * T_);

  const int qga = qb * 128 + w * 32 + col;
  const int diag_start = 2 * qb;

  for (int kt = 0; kt < ntiles; ++kt) {
    const int ktg = kt0 + kt;
    const int k0 = ktg * 64;
    __syncthreads();
    *(uint4*)kl0 = kr0;
    *(uint4*)kl1 = kr1;
    *(uint4*)vl0 = vr0;
    *(uint4*)vl1 = vr1;
    __syncthreads();
    if (kt + 1 < ntiles) {
      kg += (size_t)64 * HS_;
      vg += 64;
      kr0 = *(const uint4*)(kg);
      kr1 = *(const uint4*)(kg + (size_t)32 * HS_);
      vr0 = *(const uint4*)(vg);
      vr1 = *(const uint4*)(vg + (size_t)32 * T_);
    }

    f32x4 sa[4], sb[4];
#pragma unroll
    for (int nt = 0; nt < 4; ++nt) {
      const bf16* kp = Ks + (nt * 16 + col) * 72 + quad * 8;
      bf16x8 kf0 = *(const bf16x8*)(kp);
      bf16x8 kf1 = *(const bf16x8*)(kp + 32);
      f32x4 a = {-32.0f, -32.0f, -32.0f, -32.0f};
      a = __builtin_amdgcn_mfma_f32_16x16x32_bf16(kf0, qf0a, a, 0, 0, 0);
      a = __builtin_amdgcn_mfma_f32_16x16x32_bf16(kf1, qf1a, a, 0, 0, 0);
      sa[nt] = a;
      f32x4 b = {-32.0f, -32.0f, -32.0f, -32.0f};
      b = __builtin_amdgcn_mfma_f32_16x16x32_bf16(kf0, qf0b, b, 0, 0, 0);
      b = __builtin_amdgcn_mfma_f32_16x16x32_bf16(kf1, qf1b, b, 0, 0, 0);
      sb[nt] = b;
    }

    if (ktg >= diag_start) {
#pragma unroll
      for (int nt = 0; nt < 4; ++nt) {
        const int key = k0 + nt * 16 + quad * 4;
#pragma unroll
        for (int r = 0; r < 4; ++r) {
          if (key + r > qga) sa[nt][r] = NEG_BIG;
          if (key + r > qga + 16) sb[nt][r] = NEG_BIG;
        }
      }
    }

#pragma unroll
    for (int nt = 0; nt < 4; ++nt) {
      union { ushort u[4]; uint2 v; } pa, pb;
#pragma unroll
      for (int r = 0; r < 4; ++r) {
        pa.u[r] = __bfloat16_as_ushort(__float2bfloat16(exp2f(sa[nt][r])));
        pb.u[r] = __bfloat16_as_ushort(__float2bfloat16(exp2f(sb[nt][r])));
      }
      *(uint2*)(pw + col * 72 + nt * 16 + quad * 4) = pa.v;
      *(uint2*)(pw + (col + 16) * 72 + nt * 16 + quad * 4) = pb.v;
    }

    __asm__ __volatile__("s_waitcnt lgkmcnt(0)" ::: "memory");

#pragma unroll
    for (int half = 0; half < 2; ++half) {
      bf16x8 pfa = *(const bf16x8*)(pw + col * 72 + half * 32 + quad * 8);
      bf16x8 pfb = *(const bf16x8*)(pw + (col + 16) * 72 + half * 32 + quad * 8);
      lacca = __builtin_amdgcn_mfma_f32_16x16x32_bf16(pfa, onesf, lacca, 0, 0, 0);
      laccb = __builtin_amdgcn_mfma_f32_16x16x32_bf16(pfb, onesf, laccb, 0, 0, 0);
#pragma unroll
      for (int dt = 0; dt < 4; ++dt) {
        bf16x8 vf = *(const bf16x8*)(Vs + (dt * 16 + col) * 72 + half * 32 +
                                     quad * 8);
        oa[dt] = __builtin_amdgcn_mfma_f32_16x16x32_bf16(pfa, vf, oa[dt], 0, 0, 0);
        ob[dt] = __builtin_amdgcn_mfma_f32_16x16x32_bf16(pfb, vf, ob[dt], 0, 0, 0);
      }
    }
  }

  const bool dosplit = SPLIT && (qb >= 8);
  if (!dosplit) {
    float inva[4], invb[4];
#pragma unroll
    for (int r = 0; r < 4; ++r) {
      inva[r] = 1.0f / lacca[r];
      invb[r] = 1.0f / laccb[r];
    }
#pragma unroll
    for (int dt = 0; dt < 4; ++dt)
#pragma unroll
      for (int r = 0; r < 4; ++r) {
        const int qa = qb * 128 + w * 32 + quad * 4 + r;
        qy[head_off + (size_t)qa * HS_ + dt * 16 + col] =
            __float2bfloat16(oa[dt][r] * inva[r]);
        qy[head_off + (size_t)(qa + 16) * HS_ + dt * 16 + col] =
            __float2bfloat16(ob[dt][r] * invb[r]);
      }
  } else {
    const int slot = ((qb - 8) * 64 + bh) * 2 + ck;
    float* o = po + (size_t)slot * (128 * 64);
#pragma unroll
    for (int dt = 0; dt < 4; ++dt)
#pragma unroll
      for (int r = 0; r < 4; ++r) {
        const int qa = w * 32 + quad * 4 + r;
        o[(size_t)qa * 64 + dt * 16 + col] = oa[dt][r];
        o[(size_t)(qa + 16) * 64 + dt * 16 + col] = ob[dt][r];
      }
    if (col == 0) {
      float* lp = pl + (size_t)slot * 128;
#pragma unroll
      for (int r = 0; r < 4; ++r) {
        lp[w * 32 + quad * 4 + r] = lacca[r];
        lp[w * 32 + 16 + quad * 4 + r] = laccb[r];
      }
    }
  }
}

// ----------------------------------------------------------------------------
// Combine: for qb>=8, y = (O0+O1)/(l0+l1).
// ----------------------------------------------------------------------------
__global__ __launch_bounds__(256) void attn_combine(
    bf16* __restrict__ qy, const float* __restrict__ po,
    const float* __restrict__ pl) {
  const int qb = 8 + (int)blockIdx.x;  // 8..15
  const int bh = (int)blockIdx.y;
  const int pair = ((qb - 8) * 64 + bh) * 2;
  const float* o0 = po + (size_t)pair * (128 * 64);
  const float* o1 = o0 + 128 * 64;
  const float* l0 = pl + (size_t)pair * 128;
  const float* l1 = l0 + 128;
  const int q = threadIdx.x >> 1;
  const int d0 = (threadIdx.x & 1) * 32;
  const float inv = 1.0f / (l0[q] + l1[q]);
  const size_t base =
      (size_t)bh * T_ * HS_ + (size_t)(qb * 128 + q) * HS_ + d0;
  const size_t ob = (size_t)q * 64 + d0;
#pragma unroll
  for (int j0 = 0; j0 < 32; j0 += 8) {
    union { bf16 h[8]; uint4 u; } out;
#pragma unroll
    for (int j = 0; j < 8; ++j)
      out.h[j] = __float2bfloat16((o0[ob + j0 + j] + o1[ob + j0 + j]) * inv);
    *(uint4*)(qy + base + j0) = out.u;
  }
}

// ----------------------------------------------------------------------------
extern "C" void kernel_launch(void* const* d_in, const int* in_sizes, int n_in,
                              void* d_out, int out_size, void* d_ws, size_t ws_size,
                              hipStream_t stream) {
  const void* x = d_in[0];       // [4,2048,1024] fp32 (probed)
  const void* W_attn = d_in[1];  // [3072,1024]
  const void* W_proj = d_in[2];  // [1024,1024]
  const unsigned short* probe = (const unsigned short*)d_in[0];
  // d_in[3..6]: dead code in the reference.

  const size_t qkv_elems = (size_t)B_ * NH_ * T_ * HS_;  // 8388608
  const size_t xe = (size_t)B_ * T_ * C_;                // 8388608
  const size_t wae = (size_t)3 * C_ * C_;                // 3145728
  const size_t wpe = (size_t)C_ * C_;                    // 1048576

  bf16* q_ws = (bf16*)d_ws;
  bf16* k_ws = q_ws + qkv_elems;
  bf16* v_ws = k_ws + qkv_elems;
  bf16* x_bf = v_ws + qkv_elems;
  bf16* wa_bf = x_bf + xe;
  bf16* wp_bf = wa_bf + wae;
  const size_t need = (3 * qkv_elems + xe + wae + wpe) * sizeof(bf16);  // 72 MiB

  // split-K partials: 1024 slots x (128x64 O + 128 l) f32 = 32.5 MiB
  float* po = (float*)(wp_bf + wpe);
  float* pl = po + (size_t)1024 * 128 * 64;
  const size_t need2 =
      need + ((size_t)1024 * 128 * 64 + (size_t)1024 * 128) * sizeof(float);

  const int M = B_ * T_;  // 8192

  if (ws_size >= need) {
    convert3<<<6144, 256, 0, stream>>>(x, W_attn, W_proj, x_bf, wa_bf, wp_bf,
                                       probe);
    gemm8_qkv<<<dim3(24, 32), 512, 0, stream>>>(x_bf, wa_bf, q_ws, k_ws, v_ws);
    if (ws_size >= need2) {
      attn<1><<<dim3(24, B_ * NH_), 256, 0, stream>>>(q_ws, k_ws, v_ws, po, pl);
      attn_combine<<<dim3(8, B_ * NH_), 256, 0, stream>>>(q_ws, po, pl);
    } else {
      attn<0><<<dim3(T_ / 128, B_ * NH_), 256, 0, stream>>>(q_ws, k_ws, v_ws,
                                                            nullptr, nullptr);
    }
    gemm_bt<1, 0><<<dim3(C_ / 128, M / 128), 256, 0, stream>>>(
        q_ws, wp_bf, d_out, nullptr, nullptr, nullptr, probe, M, C_, C_);
  } else {
    gemm_bt<0, 1><<<dim3(3 * C_ / 128, M / 128), 256, 0, stream>>>(
        x, W_attn, q_ws, k_ws, v_ws, probe, nullptr, M, 3 * C_, C_);
    attn<0><<<dim3(T_ / 128, B_ * NH_), 256, 0, stream>>>(q_ws, k_ws, v_ws,
                                                          nullptr, nullptr);
    gemm_bt<1, 0><<<dim3(C_ / 128, M / 128), 256, 0, stream>>>(
        q_ws, W_proj, d_out, nullptr, nullptr, probe, probe, M, C_, C_);
  }
}

// Round 10
// 267.761 us; speedup vs baseline: 1.9127x; 1.0434x over previous
//
#include <hip/hip_runtime.h>
#include <hip/hip_bf16.h>
#include <stdint.h>

// ============================================================================
// MultiAttentionWithGating — compression branch (_kc/_vc) is DEAD CODE.
// Pipeline: qkv = x@W_attn^T ; causal SDPA (16 heads, hs=64) ; out = y@W_proj^T
// Inputs fp32 (runtime-probed); internal bf16 MFMA, fp32 accum.
//
// ROUND 15 (total 279us; attn top at 82us: VALU 44%, conflicts 7.8M, staging
// is a reg round-trip; proj still on 2-phase gemm_bt ~32us):
// [2nd submit: first bench died to infra (container acquire/push), device-side
//  audit found no deadlock/OOB/race; gemm8 skeleton thrice-verified]
//  - attn: K/V staging via global_load_lds into linear [2][64][64] dbuf,
//    both-sides XOR swizzle (src slot (c&7)^(row&7), ds_read slot^(col&7)).
//    Loads for t+1 issued before compute(t); counted vmcnt(4) + raw s_barrier
//    (NOT __syncthreads — that drains vmcnt(0) and kills the pipeline).
//    Removes 8 uint4 loads + 8 ds_write_b128 per thread/tile + 16 VGPRs.
//  - gemm8_proj: 8-phase 256x128 template for out = y@W_proj^T. Grid 8x32 =
//    256 blocks = exactly 1 CU-round, XCD-bijective. A-gather from head
//    layout: c = T*64+h*32+s*8 stays within head T (h*32+s*8<=56).
//  - gemm8_qkv (round 14, verified), convert3, attn split-K, combine: as-is.
// ============================================================================

typedef __bf16 bf16x8 __attribute__((ext_vector_type(8)));
typedef float f32x4 __attribute__((ext_vector_type(4)));
typedef __hip_bfloat16 bf16;

#define B_ 4
#define T_ 2048
#define C_ 1024
#define NH_ 16
#define HS_ 64
#define NEG_BIG (-30000.0f)
#define SCALE_LOG2E 0.180336880111f  // (1/sqrt(64)) * log2(e)

// Wave-uniform dtype probe on x (fp32 vs bf16), verified round 4.
__device__ __forceinline__ bool detect_fp32(const unsigned short* px) {
  const int lane = threadIdx.x & 63;
  const unsigned short u = px[2 * lane];
  const int e = (u >> 7) & 0xff;
  const bool plausible = (e >= 117) && (e <= 137);
  return __popcll(__ballot(plausible)) < 32;
}

// async global->LDS 16B per lane (m97). LDS dest: wave-uniform base + lane*16.
__device__ __forceinline__ void load_lds16(const bf16* g, bf16* l) {
  __builtin_amdgcn_global_load_lds(
      (const __attribute__((address_space(1))) void*)(uintptr_t)g,
      (__attribute__((address_space(3))) void*)(uintptr_t)l, 16, 0, 0);
}

// fp32 load of 8 elements -> 8 bf16 packed in uint4.
__device__ __forceinline__ uint4 ld8f(const void* base, size_t elt) {
  const float* fp = (const float*)base + elt;
  float4 f0 = *(const float4*)(fp);
  float4 f1 = *(const float4*)(fp + 4);
  union { bf16 h[8]; uint4 u; } r;
  r.h[0] = __float2bfloat16(f0.x); r.h[1] = __float2bfloat16(f0.y);
  r.h[2] = __float2bfloat16(f0.z); r.h[3] = __float2bfloat16(f0.w);
  r.h[4] = __float2bfloat16(f1.x); r.h[5] = __float2bfloat16(f1.y);
  r.h[6] = __float2bfloat16(f1.z); r.h[7] = __float2bfloat16(f1.w);
  return r.u;
}

// ----------------------------------------------------------------------------
// One-shot fp32->bf16 conversion of x, W_attn, W_proj (8 elems/thread).
// ----------------------------------------------------------------------------
__global__ __launch_bounds__(256) void convert3(
    const void* __restrict__ x, const void* __restrict__ wa,
    const void* __restrict__ wp, bf16* __restrict__ xb, bf16* __restrict__ wab,
    bf16* __restrict__ wpb, const unsigned short* __restrict__ probe) {
  const bool f32 = detect_fp32(probe);
  int blk = blockIdx.x;
  const void* src;
  bf16* dst;
  if (blk < 4096) {
    src = x; dst = xb;
  } else if (blk < 4096 + 1536) {
    blk -= 4096; src = wa; dst = wab;
  } else {
    blk -= 4096 + 1536; src = wp; dst = wpb;
  }
  const size_t i = ((size_t)blk * 256 + threadIdx.x) * 8;
  if (f32)
    *(uint4*)(dst + i) = ld8f(src, i);
  else
    *(uint4*)(dst + i) = *(const uint4*)((const bf16*)src + i);
}

// ----------------------------------------------------------------------------
// gemm8_qkv: 8-phase 256x128 bf16 GEMM for qkv = x_bf @ wa_bf^T (round 14).
// 8 waves = 4Mx2N, per-wave 64x64 -> acc[4][4] = 64 VGPR. LDS 96 KiB.
// ----------------------------------------------------------------------------
__global__ __launch_bounds__(512, 1) void gemm8_qkv(
    const bf16* __restrict__ A, const bf16* __restrict__ Bm,
    bf16* __restrict__ q_ws, bf16* __restrict__ k_ws,
    bf16* __restrict__ v_ws) {
  __shared__ bf16 Asm[2][2][256][32];  // 64 KiB
  __shared__ bf16 Bsm[2][2][128][32];  // 32 KiB

  const int tid = threadIdx.x;
  const int lane = tid & 63;
  const int wid = tid >> 6;    // 0..7
  const int wr = wid >> 1;     // 0..3  (64-row band)
  const int wc = wid & 1;      // 0..1  (64-col band)
  const int quad = lane >> 4;  // 0..3
  const int col = lane & 15;

  // XCD-bijective swizzle on flattened 24x32 grid (768 % 8 == 0).
  const int flat = (int)blockIdx.y * 24 + (int)blockIdx.x;
  const int swz = (flat & 7) * 96 + (flat >> 3);
  const int n0 = (swz % 24) * 128;
  const int m0 = (swz / 24) * 256;
  const bool vsec = (n0 >> 10) == 2;

  constexpr int NT = 16;  // K-tiles of BK=64

  const int c0 = tid, c1 = 512 + tid;
  const int r0 = c0 >> 2, s0 = (c0 & 3) ^ ((r0 >> 1) & 3);
  const int r1 = c1 >> 2, s1 = (c1 & 3) ^ ((r1 >> 1) & 3);
  const size_t ga0 = (size_t)(m0 + r0) * 1024 + s0 * 8;
  const size_t ga1 = (size_t)(m0 + r1) * 1024 + s1 * 8;
  const int rb = tid >> 2, sb = (tid & 3) ^ ((rb >> 1) & 3);
  const size_t gb = (size_t)(n0 + rb) * 1024 + sb * 8;

  auto stageA = [&](int T, int h) {
    bf16* base = &Asm[T & 1][h][0][0];
    const int kk = T * 64 + h * 32;
    load_lds16(A + ga0 + kk, base + c0 * 8);
    load_lds16(A + ga1 + kk, base + c1 * 8);
  };
  auto stageB = [&](int T, int h) {
    bf16* base = &Bsm[T & 1][h][0][0];
    const int kk = T * 64 + h * 32;
    load_lds16(Bm + gb + kk, base + tid * 8);
  };

  const int aq = quad ^ ((col >> 1) & 3);

  f32x4 acc[4][4] = {};
  bf16x8 pA[4];

  stageA(0, 0); stageB(0, 0); stageA(0, 1); stageB(0, 1);
  stageA(1, 0); stageB(1, 0); stageA(1, 1);
  asm volatile("s_waitcnt vmcnt(5)" ::: "memory");  // tile 0 resident
  __builtin_amdgcn_s_barrier();

  for (int t = 0; t < NT; ++t) {
    const bf16* Ab = (const bf16*)Asm + (t & 1) * 16384;
    const bf16* Bb = (const bf16*)Bsm + (t & 1) * 8192;

    // phase 1: ks=0, n0-1 ; stage B1(t+1)
#pragma unroll
    for (int m = 0; m < 4; ++m)
      pA[m] = *(const bf16x8*)(Ab + (wr * 64 + m * 16 + col) * 32 + aq * 8);
    bf16x8 b0 = *(const bf16x8*)(Bb + (wc * 64 + 0 + col) * 32 + aq * 8);
    bf16x8 b1 = *(const bf16x8*)(Bb + (wc * 64 + 16 + col) * 32 + aq * 8);
    if (t + 1 < NT) stageB(t + 1, 1);
    __builtin_amdgcn_s_barrier();
    asm volatile("s_waitcnt lgkmcnt(0)" ::: "memory");
    __builtin_amdgcn_s_setprio(1);
    if (vsec) {
#pragma unroll
      for (int m = 0; m < 4; ++m) {
        acc[m][0] = __builtin_amdgcn_mfma_f32_16x16x32_bf16(b0, pA[m], acc[m][0], 0, 0, 0);
        acc[m][1] = __builtin_amdgcn_mfma_f32_16x16x32_bf16(b1, pA[m], acc[m][1], 0, 0, 0);
      }
    } else {
#pragma unroll
      for (int m = 0; m < 4; ++m) {
        acc[m][0] = __builtin_amdgcn_mfma_f32_16x16x32_bf16(pA[m], b0, acc[m][0], 0, 0, 0);
        acc[m][1] = __builtin_amdgcn_mfma_f32_16x16x32_bf16(pA[m], b1, acc[m][1], 0, 0, 0);
      }
    }
    __builtin_amdgcn_s_setprio(0);
    __builtin_amdgcn_s_barrier();

    // phase 2: ks=0, n2-3 ; stage A0(t+2)
    bf16x8 b2 = *(const bf16x8*)(Bb + (wc * 64 + 32 + col) * 32 + aq * 8);
    bf16x8 b3 = *(const bf16x8*)(Bb + (wc * 64 + 48 + col) * 32 + aq * 8);
    if (t + 2 < NT) stageA(t + 2, 0);
    __builtin_amdgcn_s_barrier();
    asm volatile("s_waitcnt lgkmcnt(0)" ::: "memory");
    __builtin_amdgcn_s_setprio(1);
    if (vsec) {
#pragma unroll
      for (int m = 0; m < 4; ++m) {
        acc[m][2] = __builtin_amdgcn_mfma_f32_16x16x32_bf16(b2, pA[m], acc[m][2], 0, 0, 0);
        acc[m][3] = __builtin_amdgcn_mfma_f32_16x16x32_bf16(b3, pA[m], acc[m][3], 0, 0, 0);
      }
    } else {
#pragma unroll
      for (int m = 0; m < 4; ++m) {
        acc[m][2] = __builtin_amdgcn_mfma_f32_16x16x32_bf16(pA[m], b2, acc[m][2], 0, 0, 0);
        acc[m][3] = __builtin_amdgcn_mfma_f32_16x16x32_bf16(pA[m], b3, acc[m][3], 0, 0, 0);
      }
    }
    __builtin_amdgcn_s_setprio(0);
    __builtin_amdgcn_s_barrier();

    // phase 3: ks=1, n0-1 ; stage B0(t+2)
    Ab += 8192;
    Bb += 4096;
#pragma unroll
    for (int m = 0; m < 4; ++m)
      pA[m] = *(const bf16x8*)(Ab + (wr * 64 + m * 16 + col) * 32 + aq * 8);
    bf16x8 b0n = *(const bf16x8*)(Bb + (wc * 64 + 0 + col) * 32 + aq * 8);
    bf16x8 b1n = *(const bf16x8*)(Bb + (wc * 64 + 16 + col) * 32 + aq * 8);
    if (t + 2 < NT) stageB(t + 2, 0);
    __builtin_amdgcn_s_barrier();
    asm volatile("s_waitcnt lgkmcnt(0)" ::: "memory");
    __builtin_amdgcn_s_setprio(1);
    if (vsec) {
#pragma unroll
      for (int m = 0; m < 4; ++m) {
        acc[m][0] = __builtin_amdgcn_mfma_f32_16x16x32_bf16(b0n, pA[m], acc[m][0], 0, 0, 0);
        acc[m][1] = __builtin_amdgcn_mfma_f32_16x16x32_bf16(b1n, pA[m], acc[m][1], 0, 0, 0);
      }
    } else {
#pragma unroll
      for (int m = 0; m < 4; ++m) {
        acc[m][0] = __builtin_amdgcn_mfma_f32_16x16x32_bf16(pA[m], b0n, acc[m][0], 0, 0, 0);
        acc[m][1] = __builtin_amdgcn_mfma_f32_16x16x32_bf16(pA[m], b1n, acc[m][1], 0, 0, 0);
      }
    }
    __builtin_amdgcn_s_setprio(0);
    __builtin_amdgcn_s_barrier();

    // phase 4: ks=1, n2-3 ; stage A1(t+2) ; boundary vmcnt
    bf16x8 b2n = *(const bf16x8*)(Bb + (wc * 64 + 32 + col) * 32 + aq * 8);
    bf16x8 b3n = *(const bf16x8*)(Bb + (wc * 64 + 48 + col) * 32 + aq * 8);
    if (t + 2 < NT) stageA(t + 2, 1);
    __builtin_amdgcn_s_barrier();
    asm volatile("s_waitcnt lgkmcnt(0)" ::: "memory");
    __builtin_amdgcn_s_setprio(1);
    if (vsec) {
#pragma unroll
      for (int m = 0; m < 4; ++m) {
        acc[m][2] = __builtin_amdgcn_mfma_f32_16x16x32_bf16(b2n, pA[m], acc[m][2], 0, 0, 0);
        acc[m][3] = __builtin_amdgcn_mfma_f32_16x16x32_bf16(b3n, pA[m], acc[m][3], 0, 0, 0);
      }
    } else {
#pragma unroll
      for (int m = 0; m < 4; ++m) {
        acc[m][2] = __builtin_amdgcn_mfma_f32_16x16x32_bf16(pA[m], b2n, acc[m][2], 0, 0, 0);
        acc[m][3] = __builtin_amdgcn_mfma_f32_16x16x32_bf16(pA[m], b3n, acc[m][3], 0, 0, 0);
      }
    }
    __builtin_amdgcn_s_setprio(0);
    if (t + 2 < NT)
      asm volatile("s_waitcnt vmcnt(5)" ::: "memory");
    else
      asm volatile("s_waitcnt vmcnt(0)" ::: "memory");
    __builtin_amdgcn_s_barrier();
  }

  const int b = m0 >> 11;
  if (!vsec) {
    bf16* dst = ((n0 >> 10) == 0) ? q_ws : k_ws;
#pragma unroll
    for (int m = 0; m < 4; ++m) {
      const int mrow = (m0 & 2047) + wr * 64 + m * 16 + quad * 4;
#pragma unroll
      for (int n = 0; n < 4; ++n) {
        const int cc = (n0 & 1023) + wc * 64 + n * 16 + col;
        const int h = cc >> 6, d = cc & 63;
#pragma unroll
        for (int r = 0; r < 4; ++r)
          dst[(((size_t)b * NH_ + h) * T_ + mrow + r) * HS_ + d] =
              __float2bfloat16(acc[m][n][r]);
      }
    }
  } else {
#pragma unroll
    for (int m = 0; m < 4; ++m) {
      const int tloc = (m0 & 2047) + wr * 64 + m * 16 + col;
#pragma unroll
      for (int n = 0; n < 4; ++n) {
        const int vch = (n0 & 1023) + wc * 64 + n * 16 + quad * 4;
#pragma unroll
        for (int r = 0; r < 4; ++r) {
          const int h = (vch + r) >> 6, d = (vch + r) & 63;
          v_ws[(((size_t)b * NH_ + h) * HS_ + d) * T_ + tloc] =
              __float2bfloat16(acc[m][n][r]);
        }
      }
    }
  }
}

// ----------------------------------------------------------------------------
// gemm8_proj: 8-phase 256x128 bf16 GEMM for out = y @ W_proj^T.
// A = y in head layout q_ws[b][h][t][64] (k = h*64+d; head = k-tile index T
// since h*32+s*8 <= 56). B = wp_bf [1024][1024]. Grid 8x32 = 256 blocks.
// Output fp32 or bf16 (probed), row-major [8192][1024].
// ----------------------------------------------------------------------------
__global__ __launch_bounds__(512, 1) void gemm8_proj(
    const bf16* __restrict__ A, const bf16* __restrict__ Bm,
    void* __restrict__ C, const unsigned short* __restrict__ out_probe) {
  __shared__ bf16 Asm[2][2][256][32];  // 64 KiB
  __shared__ bf16 Bsm[2][2][128][32];  // 32 KiB

  const bool f32out = detect_fp32(out_probe);

  const int tid = threadIdx.x;
  const int lane = tid & 63;
  const int wid = tid >> 6;
  const int wr = wid >> 1;     // 0..3
  const int wc = wid & 1;      // 0..1
  const int quad = lane >> 4;
  const int col = lane & 15;

  // XCD-bijective swizzle on flattened 8x32 grid (256 % 8 == 0).
  const int flat = (int)blockIdx.y * 8 + (int)blockIdx.x;
  const int swz = (flat & 7) * 32 + (flat >> 3);
  const int n0 = (swz % 8) * 128;
  const int m0 = (swz / 8) * 256;
  const int b = m0 >> 11;
  const int tloc0 = m0 & 2047;

  constexpr int NT = 16;

  const int c0 = tid, c1 = 512 + tid;
  const int r0 = c0 >> 2, s0 = (c0 & 3) ^ ((r0 >> 1) & 3);
  const int r1 = c1 >> 2, s1 = (c1 & 3) ^ ((r1 >> 1) & 3);
  // A per-thread offsets within a (T,h) panel: row-dependent part.
  const size_t aoff0 = (size_t)(tloc0 + r0) * 64 + s0 * 8;
  const size_t aoff1 = (size_t)(tloc0 + r1) * 64 + s1 * 8;
  const size_t abase = (size_t)b * NH_ * T_ * HS_;  // + T*131072 per k-tile
  const int rb = tid >> 2, sb = (tid & 3) ^ ((rb >> 1) & 3);
  const size_t gb = (size_t)(n0 + rb) * 1024 + sb * 8;

  auto stageA = [&](int T, int h) {
    bf16* base = &Asm[T & 1][h][0][0];
    const size_t pan = abase + (size_t)T * (T_ * HS_) + h * 32;
    load_lds16(A + pan + aoff0, base + c0 * 8);
    load_lds16(A + pan + aoff1, base + c1 * 8);
  };
  auto stageB = [&](int T, int h) {
    bf16* base = &Bsm[T & 1][h][0][0];
    const int kk = T * 64 + h * 32;
    load_lds16(Bm + gb + kk, base + tid * 8);
  };

  const int aq = quad ^ ((col >> 1) & 3);

  f32x4 acc[4][4] = {};
  bf16x8 pA[4];

  stageA(0, 0); stageB(0, 0); stageA(0, 1); stageB(0, 1);
  stageA(1, 0); stageB(1, 0); stageA(1, 1);
  asm volatile("s_waitcnt vmcnt(5)" ::: "memory");
  __builtin_amdgcn_s_barrier();

  for (int t = 0; t < NT; ++t) {
    const bf16* Ab = (const bf16*)Asm + (t & 1) * 16384;
    const bf16* Bb = (const bf16*)Bsm + (t & 1) * 8192;

    // phase 1
#pragma unroll
    for (int m = 0; m < 4; ++m)
      pA[m] = *(const bf16x8*)(Ab + (wr * 64 + m * 16 + col) * 32 + aq * 8);
    bf16x8 b0 = *(const bf16x8*)(Bb + (wc * 64 + 0 + col) * 32 + aq * 8);
    bf16x8 b1 = *(const bf16x8*)(Bb + (wc * 64 + 16 + col) * 32 + aq * 8);
    if (t + 1 < NT) stageB(t + 1, 1);
    __builtin_amdgcn_s_barrier();
    asm volatile("s_waitcnt lgkmcnt(0)" ::: "memory");
    __builtin_amdgcn_s_setprio(1);
#pragma unroll
    for (int m = 0; m < 4; ++m) {
      acc[m][0] = __builtin_amdgcn_mfma_f32_16x16x32_bf16(pA[m], b0, acc[m][0], 0, 0, 0);
      acc[m][1] = __builtin_amdgcn_mfma_f32_16x16x32_bf16(pA[m], b1, acc[m][1], 0, 0, 0);
    }
    __builtin_amdgcn_s_setprio(0);
    __builtin_amdgcn_s_barrier();

    // phase 2
    bf16x8 b2 = *(const bf16x8*)(Bb + (wc * 64 + 32 + col) * 32 + aq * 8);
    bf16x8 b3 = *(const bf16x8*)(Bb + (wc * 64 + 48 + col) * 32 + aq * 8);
    if (t + 2 < NT) stageA(t + 2, 0);
    __builtin_amdgcn_s_barrier();
    asm volatile("s_waitcnt lgkmcnt(0)" ::: "memory");
    __builtin_amdgcn_s_setprio(1);
#pragma unroll
    for (int m = 0; m < 4; ++m) {
      acc[m][2] = __builtin_amdgcn_mfma_f32_16x16x32_bf16(pA[m], b2, acc[m][2], 0, 0, 0);
      acc[m][3] = __builtin_amdgcn_mfma_f32_16x16x32_bf16(pA[m], b3, acc[m][3], 0, 0, 0);
    }
    __builtin_amdgcn_s_setprio(0);
    __builtin_amdgcn_s_barrier();

    // phase 3
    Ab += 8192;
    Bb += 4096;
#pragma unroll
    for (int m = 0; m < 4; ++m)
      pA[m] = *(const bf16x8*)(Ab + (wr * 64 + m * 16 + col) * 32 + aq * 8);
    b0 = *(const bf16x8*)(Bb + (wc * 64 + 0 + col) * 32 + aq * 8);
    b1 = *(const bf16x8*)(Bb + (wc * 64 + 16 + col) * 32 + aq * 8);
    if (t + 2 < NT) stageB(t + 2, 0);
    __builtin_amdgcn_s_barrier();
    asm volatile("s_waitcnt lgkmcnt(0)" ::: "memory");
    __builtin_amdgcn_s_setprio(1);
#pragma unroll
    for (int m = 0; m < 4; ++m) {
      acc[m][0] = __builtin_amdgcn_mfma_f32_16x16x32_bf16(pA[m], b0, acc[m][0], 0, 0, 0);
      acc[m][1] = __builtin_amdgcn_mfma_f32_16x16x32_bf16(pA[m], b1, acc[m][1], 0, 0, 0);
    }
    __builtin_amdgcn_s_setprio(0);
    __builtin_amdgcn_s_barrier();

    // phase 4
    b2 = *(const bf16x8*)(Bb + (wc * 64 + 32 + col) * 32 + aq * 8);
    b3 = *(const bf16x8*)(Bb + (wc * 64 + 48 + col) * 32 + aq * 8);
    if (t + 2 < NT) stageA(t + 2, 1);
    __builtin_amdgcn_s_barrier();
    asm volatile("s_waitcnt lgkmcnt(0)" ::: "memory");
    __builtin_amdgcn_s_setprio(1);
#pragma unroll
    for (int m = 0; m < 4; ++m) {
      acc[m][2] = __builtin_amdgcn_mfma_f32_16x16x32_bf16(pA[m], b2, acc[m][2], 0, 0, 0);
      acc[m][3] = __builtin_amdgcn_mfma_f32_16x16x32_bf16(pA[m], b3, acc[m][3], 0, 0, 0);
    }
    __builtin_amdgcn_s_setprio(0);
    if (t + 2 < NT)
      asm volatile("s_waitcnt vmcnt(5)" ::: "memory");
    else
      asm volatile("s_waitcnt vmcnt(0)" ::: "memory");
    __builtin_amdgcn_s_barrier();
  }

  // epilogue: row-major [8192][1024], fp32 or bf16
#pragma unroll
  for (int m = 0; m < 4; ++m) {
    const int mrow = m0 + wr * 64 + m * 16 + quad * 4;
#pragma unroll
    for (int n = 0; n < 4; ++n) {
      const int ncol = n0 + wc * 64 + n * 16 + col;
#pragma unroll
      for (int r = 0; r < 4; ++r) {
        if (f32out)
          ((float*)C)[(size_t)(mrow + r) * 1024 + ncol] = acc[m][n][r];
        else
          ((bf16*)C)[(size_t)(mrow + r) * 1024 + ncol] =
              __float2bfloat16(acc[m][n][r]);
      }
    }
  }
}

// ----------------------------------------------------------------------------
// gemm_bt (round 11): 128x128 tile, BK=32, double-buffered LDS, 2-phase.
// fp32 no-workspace fallback only.
// ----------------------------------------------------------------------------
template <int IN_MODE, int OUT_MODE>
__global__ __launch_bounds__(256, 2) void gemm_bt(
    const void* __restrict__ A, const void* __restrict__ B, void* __restrict__ C,
    bf16* __restrict__ k_ws, bf16* __restrict__ v_ws,
    const unsigned short* __restrict__ in_probe,
    const unsigned short* __restrict__ out_probe, int M, int N, int K) {
  __shared__ bf16 As[2][128 * 32];
  __shared__ bf16 Bs[2][128 * 32];

  const bool f32b = in_probe ? detect_fp32(in_probe) : false;
  const bool f32a = (IN_MODE == 0) && f32b;
  const bool f32out =
      (OUT_MODE == 0) && (out_probe ? detect_fp32(out_probe) : false);

  const int tid = threadIdx.x;
  const int lane = tid & 63;
  const int wid = tid >> 6;
  const int quad = lane >> 4;
  const int col = lane & 15;
  const int m0 = blockIdx.y * 128;
  const int n0 = blockIdx.x * 128;
  const int wm = (wid >> 1) * 64;
  const int wn = (wid & 1) * 64;
  const bool vsec = (OUT_MODE == 1) && ((n0 >> 10) == 2);

  const size_t arow = (size_t)(m0 + (tid >> 2));
  const size_t brow = (size_t)(n0 + (tid >> 2));
  const int chunk = (tid & 3) * 8;
  const size_t astep = (IN_MODE == 0) ? (size_t)64 * K : (size_t)64 * HS_;

  f32x4 acc[4][4] = {};

  auto a_ptr = [&](int k0) -> const bf16* {
    if (IN_MODE == 0) return (const bf16*)A + arow * K + chunk + k0;
    const int b = m0 >> 11;
    const int tloc = (m0 & 2047) + (tid >> 2);
    return (const bf16*)A +
           ((((size_t)b * NH_) + (k0 >> 6)) * T_ + tloc) * HS_ + (k0 & 32) +
           chunk;
  };

  if (f32a) {
    uint4 a0 = ld8f(A, arow * K + chunk);
    uint4 a1 = ld8f(A, (arow + 64) * K + chunk);
    *(uint4*)(&As[0][0] + tid * 8) = a0;
    *(uint4*)(&As[0][0] + 2048 + tid * 8) = a1;
  } else {
    const bf16* ap = a_ptr(0);
    load_lds16(ap, &As[0][0] + tid * 8);
    load_lds16(ap + astep, &As[0][0] + 2048 + tid * 8);
  }
  if (f32b) {
    uint4 b0 = ld8f(B, brow * K + chunk);
    uint4 b1 = ld8f(B, (brow + 64) * K + chunk);
    *(uint4*)(&Bs[0][0] + tid * 8) = b0;
    *(uint4*)(&Bs[0][0] + 2048 + tid * 8) = b1;
  } else {
    load_lds16((const bf16*)B + brow * K + chunk, &Bs[0][0] + tid * 8);
    load_lds16((const bf16*)B + (brow + 64) * K + chunk,
               &Bs[0][0] + 2048 + tid * 8);
  }
  __syncthreads();

  int cur = 0;
  for (int k0 = 0; k0 < K; k0 += 32) {
    const int kn = k0 + 32;
    const bool hasn = kn < K;
    const int nxt = cur ^ 1;

    uint4 a0, a1, b0, b1;
    bool wra = false, wrb = false;
    if (hasn) {
      if (f32a) {
        a0 = ld8f(A, arow * K + chunk + kn);
        a1 = ld8f(A, (arow + 64) * K + chunk + kn);
        wra = true;
      } else {
        const bf16* ap = a_ptr(kn);
        load_lds16(ap, &As[nxt][0] + tid * 8);
        load_lds16(ap + astep, &As[nxt][0] + 2048 + tid * 8);
      }
      if (f32b) {
        b0 = ld8f(B, brow * K + chunk + kn);
        b1 = ld8f(B, (brow + 64) * K + chunk + kn);
        wrb = true;
      } else {
        load_lds16((const bf16*)B + brow * K + chunk + kn,
                   &Bs[nxt][0] + tid * 8);
        load_lds16((const bf16*)B + (brow + 64) * K + chunk + kn,
                   &Bs[nxt][0] + 2048 + tid * 8);
      }
    }

    bf16x8 af[4], bfr[4];
#pragma unroll
    for (int t = 0; t < 4; ++t) {
      af[t] = *(const bf16x8*)(&As[cur][0] + (wm + t * 16 + col) * 32 + quad * 8);
      bfr[t] = *(const bf16x8*)(&Bs[cur][0] + (wn + t * 16 + col) * 32 + quad * 8);
    }
    if (vsec) {
#pragma unroll
      for (int tm = 0; tm < 4; ++tm)
#pragma unroll
        for (int tn = 0; tn < 4; ++tn)
          acc[tm][tn] = __builtin_amdgcn_mfma_f32_16x16x32_bf16(
              bfr[tn], af[tm], acc[tm][tn], 0, 0, 0);
    } else {
#pragma unroll
      for (int tm = 0; tm < 4; ++tm)
#pragma unroll
        for (int tn = 0; tn < 4; ++tn)
          acc[tm][tn] = __builtin_amdgcn_mfma_f32_16x16x32_bf16(
              af[tm], bfr[tn], acc[tm][tn], 0, 0, 0);
    }

    if (wra) {
      *(uint4*)(&As[nxt][0] + tid * 8) = a0;
      *(uint4*)(&As[nxt][0] + 2048 + tid * 8) = a1;
    }
    if (wrb) {
      *(uint4*)(&Bs[nxt][0] + tid * 8) = b0;
      *(uint4*)(&Bs[nxt][0] + 2048 + tid * 8) = b1;
    }
    __syncthreads();
    cur = nxt;
  }

  if (OUT_MODE == 0) {
#pragma unroll
    for (int tm = 0; tm < 4; ++tm) {
      const int mrow = m0 + wm + tm * 16 + quad * 4;
#pragma unroll
      for (int tn = 0; tn < 4; ++tn) {
        const int ncol = n0 + wn + tn * 16 + col;
#pragma unroll
        for (int r = 0; r < 4; ++r) {
          if (f32out)
            ((float*)C)[(size_t)(mrow + r) * N + ncol] = acc[tm][tn][r];
          else
            ((bf16*)C)[(size_t)(mrow + r) * N + ncol] =
                __float2bfloat16(acc[tm][tn][r]);
        }
      }
    }
  } else if (vsec) {
    const int b = m0 >> 11;
#pragma unroll
    for (int tm = 0; tm < 4; ++tm) {
      const int tloc = (m0 & 2047) + wm + tm * 16 + col;
#pragma unroll
      for (int tn = 0; tn < 4; ++tn) {
        const int vch = (n0 & (C_ - 1)) + wn + tn * 16 + quad * 4;
#pragma unroll
        for (int r = 0; r < 4; ++r) {
          const int h = (vch + r) >> 6, d = (vch + r) & 63;
          v_ws[(((size_t)b * NH_ + h) * HS_ + d) * T_ + tloc] =
              __float2bfloat16(acc[tm][tn][r]);
        }
      }
    }
  } else {
    const int sect = n0 >> 10;  // 0:q 1:k
    bf16* dst = (sect == 0) ? (bf16*)C : k_ws;
#pragma unroll
    for (int tm = 0; tm < 4; ++tm) {
      const int mrow = m0 + wm + tm * 16 + quad * 4;
#pragma unroll
      for (int tn = 0; tn < 4; ++tn) {
        const int c = (n0 + wn + tn * 16 + col) & (C_ - 1);
        const int h = c >> 6, d = c & 63;
#pragma unroll
        for (int r = 0; r < 4; ++r) {
          const int t = (mrow + r) & (T_ - 1);
          const int b = (mrow + r) >> 11;
          dst[(((size_t)b * NH_ + h) * T_ + t) * HS_ + d] =
              __float2bfloat16(acc[tm][tn][r]);
        }
      }
    }
  }
}

// ----------------------------------------------------------------------------
// MFMA flash attention (causal), fixed-max softmax, split-K (round 10).
// ROUND 15: K/V staged via global_load_lds into linear [2][64][64] dbuf with
// both-sides XOR swizzle; counted vmcnt(4) + raw s_barrier pipeline.
// ----------------------------------------------------------------------------
template <int SPLIT>
__global__ __launch_bounds__(256, 2) void attn(
    bf16* qy, const bf16* __restrict__ kws, const bf16* __restrict__ vws,
    float* __restrict__ po, float* __restrict__ pl) {
  __shared__ bf16 Ks[2][64][64];    // [buf][key][d], slot-XOR swizzled
  __shared__ bf16 Vs[2][64][64];    // [buf][d][key], slot-XOR swizzled
  __shared__ bf16 Ps[4][32 * 72];   // per-wave P [32 q][64 k], stride 72

  const int tid = threadIdx.x;
  const int lane = tid & 63;
  const int w = tid >> 6;
  const int quad = lane >> 4;
  const int col = lane & 15;
  const int x = (int)blockIdx.x;

  int qb, ck;
  if (SPLIT) {
    const unsigned long long lo = 0xC4D5E6F7FEDCBA98ULL;  // qb nibbles x0..15
    const unsigned int hi = 0xB3A29180u;                  // qb nibbles x16..23
    const unsigned int cmask = 0x00AAAA00u;               // chunk bit per x
    qb = (x < 16) ? (int)((lo >> (4 * x)) & 15)
                  : (int)((hi >> (4 * (x - 16))) & 15);
    ck = (int)((cmask >> x) & 1);
  } else {
    const int gx = (int)gridDim.x;  // 16
    const int hx = gx >> 1;
    qb = (x < hx) ? (gx - 1 - x) : (x - hx);
    ck = 0;
  }

  const int bh = blockIdx.y;
  const size_t head_off = (size_t)bh * T_ * HS_;

  const int ntall = 2 * (qb + 1);
  const int kt0 = SPLIT ? ck * 16 : 0;
  const int ntiles = SPLIT ? min(ntall - kt0, 16) : ntall;

  const int qrow = qb * 128 + w * 32 + col;
  const bf16* qp = qy + head_off + (size_t)qrow * HS_ + quad * 8;
  bf16x8 qf0a = *(const bf16x8*)(qp);
  bf16x8 qf1a = *(const bf16x8*)(qp + 32);
  bf16x8 qf0b = *(const bf16x8*)(qp + 16 * HS_);
  bf16x8 qf1b = *(const bf16x8*)(qp + 16 * HS_ + 32);
#pragma unroll
  for (int j = 0; j < 8; ++j) {
    qf0a[j] = (__bf16)((float)qf0a[j] * SCALE_LOG2E);
    qf1a[j] = (__bf16)((float)qf1a[j] * SCALE_LOG2E);
    qf0b[j] = (__bf16)((float)qf0b[j] * SCALE_LOG2E);
    qf1b[j] = (__bf16)((float)qf1b[j] * SCALE_LOG2E);
  }

  bf16x8 onesf;
#pragma unroll
  for (int j = 0; j < 8; ++j) onesf[j] = (__bf16)1.0f;

  f32x4 oa[4] = {}, ob[4] = {};
  f32x4 lacca = {}, laccb = {};

  bf16* pw = &Ps[w][0];

  // ---- gload_lds staging map: chunk c covers (row=c>>3, slot=c&7) of a
  // 64x128B tile; source slot pre-XOR'd by row&7 (dest is linear, rule #21).
  // Thread covers c0=tid, c1=256+tid; (256+tid)>>3 & 7 == (tid>>3)&7, so both
  // share the same slot XOR.
  const int srow = tid >> 3;
  const int ssl = (tid & 7) ^ (srow & 7);
  const size_t kb0 = head_off + (size_t)(kt0 * 64 + srow) * HS_ + ssl * 8;
  const size_t kb1 = kb0 + (size_t)32 * HS_;
  const size_t vb0 = ((size_t)bh * HS_ + srow) * T_ + kt0 * 64 + ssl * 8;
  const size_t vb1 = vb0 + (size_t)32 * T_;

  auto stageKV = [&](int kt, int buf) {  // kt is LOCAL tile index
    load_lds16(kws + kb0 + (size_t)kt * (64 * HS_), &Ks[buf][0][0] + tid * 8);
    load_lds16(kws + kb1 + (size_t)kt * (64 * HS_),
               &Ks[buf][0][0] + (256 + tid) * 8);
    load_lds16(vws + vb0 + kt * 64, &Vs[buf][0][0] + tid * 8);
    load_lds16(vws + vb1 + kt * 64, &Vs[buf][0][0] + (256 + tid) * 8);
  };

  const int c7 = col & 7;  // read-side slot XOR (row&7 == col&7 for our rows)

  const int qga = qb * 128 + w * 32 + col;
  const int diag_start = 2 * qb;

  stageKV(0, 0);

  for (int kt = 0; kt < ntiles; ++kt) {
    const int cur = kt & 1;
    const int ktg = kt0 + kt;
    const int k0 = ktg * 64;

    if (kt + 1 < ntiles) {
      stageKV(kt + 1, cur ^ 1);
      asm volatile("s_waitcnt vmcnt(4)" ::: "memory");  // tile kt resident
    } else {
      asm volatile("s_waitcnt vmcnt(0)" ::: "memory");
    }
    __builtin_amdgcn_s_barrier();

    const bf16* kb = &Ks[cur][0][0];
    const bf16* vb = &Vs[cur][0][0];

    // ---- S^T - 32 = (K Q^T) - 32 : lane -> (key=quad*4+r, q=col) ----
    f32x4 sa[4], sb[4];
#pragma unroll
    for (int nt = 0; nt < 4; ++nt) {
      const bf16* kp = kb + (nt * 16 + col) * 64;
      bf16x8 kf0 = *(const bf16x8*)(kp + ((quad ^ c7) * 8));
      bf16x8 kf1 = *(const bf16x8*)(kp + (((quad + 4) ^ c7) * 8));
      f32x4 a = {-32.0f, -32.0f, -32.0f, -32.0f};
      a = __builtin_amdgcn_mfma_f32_16x16x32_bf16(kf0, qf0a, a, 0, 0, 0);
      a = __builtin_amdgcn_mfma_f32_16x16x32_bf16(kf1, qf1a, a, 0, 0, 0);
      sa[nt] = a;
      f32x4 b = {-32.0f, -32.0f, -32.0f, -32.0f};
      b = __builtin_amdgcn_mfma_f32_16x16x32_bf16(kf0, qf0b, b, 0, 0, 0);
      b = __builtin_amdgcn_mfma_f32_16x16x32_bf16(kf1, qf1b, b, 0, 0, 0);
      sb[nt] = b;
    }

    // ---- causal mask (only tiles overlapping the diagonal) ----
    if (ktg >= diag_start) {
#pragma unroll
      for (int nt = 0; nt < 4; ++nt) {
        const int key = k0 + nt * 16 + quad * 4;
#pragma unroll
        for (int r = 0; r < 4; ++r) {
          if (key + r > qga) sa[nt][r] = NEG_BIG;
          if (key + r > qga + 16) sb[nt][r] = NEG_BIG;
        }
      }
    }

    // ---- P = exp2(S-32): 4 consecutive keys/lane -> packed b64 writes ----
#pragma unroll
    for (int nt = 0; nt < 4; ++nt) {
      union { ushort u[4]; uint2 v; } pa, pb;
#pragma unroll
      for (int r = 0; r < 4; ++r) {
        pa.u[r] = __bfloat16_as_ushort(__float2bfloat16(exp2f(sa[nt][r])));
        pb.u[r] = __bfloat16_as_ushort(__float2bfloat16(exp2f(sb[nt][r])));
      }
      *(uint2*)(pw + col * 72 + nt * 16 + quad * 4) = pa.v;
      *(uint2*)(pw + (col + 16) * 72 + nt * 16 + quad * 4) = pb.v;
    }

    __asm__ __volatile__("s_waitcnt lgkmcnt(0)" ::: "memory");  // P visible

    // ---- O += P V ; l += P*ones (V-frags shared across subtiles) ----
#pragma unroll
    for (int half = 0; half < 2; ++half) {
      bf16x8 pfa = *(const bf16x8*)(pw + col * 72 + half * 32 + quad * 8);
      bf16x8 pfb = *(const bf16x8*)(pw + (col + 16) * 72 + half * 32 + quad * 8);
      lacca = __builtin_amdgcn_mfma_f32_16x16x32_bf16(pfa, onesf, lacca, 0, 0, 0);
      laccb = __builtin_amdgcn_mfma_f32_16x16x32_bf16(pfb, onesf, laccb, 0, 0, 0);
#pragma unroll
      for (int dt = 0; dt < 4; ++dt) {
        const bf16* vp = vb + (dt * 16 + col) * 64;
        bf16x8 vf = *(const bf16x8*)(vp + (((half * 4 + quad) ^ c7) * 8));
        oa[dt] = __builtin_amdgcn_mfma_f32_16x16x32_bf16(pfa, vf, oa[dt], 0, 0, 0);
        ob[dt] = __builtin_amdgcn_mfma_f32_16x16x32_bf16(pfb, vf, ob[dt], 0, 0, 0);
      }
    }
    __builtin_amdgcn_s_barrier();  // all reads of buf[cur] complete
  }

  const bool dosplit = SPLIT && (qb >= 8);
  if (!dosplit) {
    float inva[4], invb[4];
#pragma unroll
    for (int r = 0; r < 4; ++r) {
      inva[r] = 1.0f / lacca[r];
      invb[r] = 1.0f / laccb[r];
    }
#pragma unroll
    for (int dt = 0; dt < 4; ++dt)
#pragma unroll
      for (int r = 0; r < 4; ++r) {
        const int qa = qb * 128 + w * 32 + quad * 4 + r;
        qy[head_off + (size_t)qa * HS_ + dt * 16 + col] =
            __float2bfloat16(oa[dt][r] * inva[r]);
        qy[head_off + (size_t)(qa + 16) * HS_ + dt * 16 + col] =
            __float2bfloat16(ob[dt][r] * invb[r]);
      }
  } else {
    const int slot = ((qb - 8) * 64 + bh) * 2 + ck;
    float* o = po + (size_t)slot * (128 * 64);
#pragma unroll
    for (int dt = 0; dt < 4; ++dt)
#pragma unroll
      for (int r = 0; r < 4; ++r) {
        const int qa = w * 32 + quad * 4 + r;
        o[(size_t)qa * 64 + dt * 16 + col] = oa[dt][r];
        o[(size_t)(qa + 16) * 64 + dt * 16 + col] = ob[dt][r];
      }
    if (col == 0) {
      float* lp = pl + (size_t)slot * 128;
#pragma unroll
      for (int r = 0; r < 4; ++r) {
        lp[w * 32 + quad * 4 + r] = lacca[r];
        lp[w * 32 + 16 + quad * 4 + r] = laccb[r];
      }
    }
  }
}

// ----------------------------------------------------------------------------
// Combine: for qb>=8, y = (O0+O1)/(l0+l1).
// ----------------------------------------------------------------------------
__global__ __launch_bounds__(256) void attn_combine(
    bf16* __restrict__ qy, const float* __restrict__ po,
    const float* __restrict__ pl) {
  const int qb = 8 + (int)blockIdx.x;  // 8..15
  const int bh = (int)blockIdx.y;
  const int pair = ((qb - 8) * 64 + bh) * 2;
  const float* o0 = po + (size_t)pair * (128 * 64);
  const float* o1 = o0 + 128 * 64;
  const float* l0 = pl + (size_t)pair * 128;
  const float* l1 = l0 + 128;
  const int q = threadIdx.x >> 1;
  const int d0 = (threadIdx.x & 1) * 32;
  const float inv = 1.0f / (l0[q] + l1[q]);
  const size_t base =
      (size_t)bh * T_ * HS_ + (size_t)(qb * 128 + q) * HS_ + d0;
  const size_t ob = (size_t)q * 64 + d0;
#pragma unroll
  for (int j0 = 0; j0 < 32; j0 += 8) {
    union { bf16 h[8]; uint4 u; } out;
#pragma unroll
    for (int j = 0; j < 8; ++j)
      out.h[j] = __float2bfloat16((o0[ob + j0 + j] + o1[ob + j0 + j]) * inv);
    *(uint4*)(qy + base + j0) = out.u;
  }
}

// ----------------------------------------------------------------------------
extern "C" void kernel_launch(void* const* d_in, const int* in_sizes, int n_in,
                              void* d_out, int out_size, void* d_ws, size_t ws_size,
                              hipStream_t stream) {
  const void* x = d_in[0];       // [4,2048,1024] fp32 (probed)
  const void* W_attn = d_in[1];  // [3072,1024]
  const void* W_proj = d_in[2];  // [1024,1024]
  const unsigned short* probe = (const unsigned short*)d_in[0];
  // d_in[3..6]: dead code in the reference.

  const size_t qkv_elems = (size_t)B_ * NH_ * T_ * HS_;  // 8388608
  const size_t xe = (size_t)B_ * T_ * C_;                // 8388608
  const size_t wae = (size_t)3 * C_ * C_;                // 3145728
  const size_t wpe = (size_t)C_ * C_;                    // 1048576

  bf16* q_ws = (bf16*)d_ws;
  bf16* k_ws = q_ws + qkv_elems;
  bf16* v_ws = k_ws + qkv_elems;
  bf16* x_bf = v_ws + qkv_elems;
  bf16* wa_bf = x_bf + xe;
  bf16* wp_bf = wa_bf + wae;
  const size_t need = (3 * qkv_elems + xe + wae + wpe) * sizeof(bf16);  // 72 MiB

  // split-K partials: 1024 slots x (128x64 O + 128 l) f32 = 32.5 MiB
  float* po = (float*)(wp_bf + wpe);
  float* pl = po + (size_t)1024 * 128 * 64;
  const size_t need2 =
      need + ((size_t)1024 * 128 * 64 + (size_t)1024 * 128) * sizeof(float);

  const int M = B_ * T_;  // 8192

  if (ws_size >= need) {
    convert3<<<6144, 256, 0, stream>>>(x, W_attn, W_proj, x_bf, wa_bf, wp_bf,
                                       probe);
    gemm8_qkv<<<dim3(24, 32), 512, 0, stream>>>(x_bf, wa_bf, q_ws, k_ws, v_ws);
    if (ws_size >= need2) {
      attn<1><<<dim3(24, B_ * NH_), 256, 0, stream>>>(q_ws, k_ws, v_ws, po, pl);
      attn_combine<<<dim3(8, B_ * NH_), 256, 0, stream>>>(q_ws, po, pl);
    } else {
      attn<0><<<dim3(T_ / 128, B_ * NH_), 256, 0, stream>>>(q_ws, k_ws, v_ws,
                                                            nullptr, nullptr);
    }
    gemm8_proj<<<dim3(8, 32), 512, 0, stream>>>(q_ws, wp_bf, d_out, probe);
  } else {
    gemm_bt<0, 1><<<dim3(3 * C_ / 128, M / 128), 256, 0, stream>>>(
        x, W_attn, q_ws, k_ws, v_ws, probe, nullptr, M, 3 * C_, C_);
    attn<0><<<dim3(T_ / 128, B_ * NH_), 256, 0, stream>>>(q_ws, k_ws, v_ws,
                                                          nullptr, nullptr);
    gemm_bt<1, 0><<<dim3(C_ / 128, M / 128), 256, 0, stream>>>(
        q_ws, W_proj, d_out, nullptr, nullptr, probe, probe, M, C_, C_);
  }
}

// Round 11
// 260.684 us; speedup vs baseline: 1.9646x; 1.0271x over previous
//
#include <hip/hip_runtime.h>
#include <hip/hip_bf16.h>
#include <stdint.h>

// ============================================================================
// MultiAttentionWithGating — compression branch (_kc/_vc) is DEAD CODE.
// Pipeline: qkv = x@W_attn^T ; causal SDPA (16 heads, hs=64) ; out = y@W_proj^T
// Inputs fp32 (runtime-probed); internal bf16 MFMA, fp32 accum.
//
// ROUND 16 (attn 79us: VALU 47%, occupancy 21% ~= 2 blocks/CU; LDS 51200
// likely rounds past 160KB/3 under allocation granularity):
//  - Ps: stride 72 -> stride 64 + 16B-slot XOR swizzle (phys = logical ^
//    (row&7)). b128 P-reads become free 2-way (32 slots covered 2x); b64
//    P-writes stay at the 4-lane/bank b64 floor. Ps 18KB -> 16KB.
//  - attn LDS total 49152 (16K Ks + 16K Vs + 16K Ps) -> 3 blocks/CU under
//    any granule; __launch_bounds__(256,3) so regalloc targets 12 waves/CU
//    (VGPR 68 << 170 cap).
//  - Everything else byte-identical to round 15 (passed, 267.8us).
// ============================================================================

typedef __bf16 bf16x8 __attribute__((ext_vector_type(8)));
typedef float f32x4 __attribute__((ext_vector_type(4)));
typedef __hip_bfloat16 bf16;

#define B_ 4
#define T_ 2048
#define C_ 1024
#define NH_ 16
#define HS_ 64
#define NEG_BIG (-30000.0f)
#define SCALE_LOG2E 0.180336880111f  // (1/sqrt(64)) * log2(e)

// Wave-uniform dtype probe on x (fp32 vs bf16), verified round 4.
__device__ __forceinline__ bool detect_fp32(const unsigned short* px) {
  const int lane = threadIdx.x & 63;
  const unsigned short u = px[2 * lane];
  const int e = (u >> 7) & 0xff;
  const bool plausible = (e >= 117) && (e <= 137);
  return __popcll(__ballot(plausible)) < 32;
}

// async global->LDS 16B per lane (m97). LDS dest: wave-uniform base + lane*16.
__device__ __forceinline__ void load_lds16(const bf16* g, bf16* l) {
  __builtin_amdgcn_global_load_lds(
      (const __attribute__((address_space(1))) void*)(uintptr_t)g,
      (__attribute__((address_space(3))) void*)(uintptr_t)l, 16, 0, 0);
}

// fp32 load of 8 elements -> 8 bf16 packed in uint4.
__device__ __forceinline__ uint4 ld8f(const void* base, size_t elt) {
  const float* fp = (const float*)base + elt;
  float4 f0 = *(const float4*)(fp);
  float4 f1 = *(const float4*)(fp + 4);
  union { bf16 h[8]; uint4 u; } r;
  r.h[0] = __float2bfloat16(f0.x); r.h[1] = __float2bfloat16(f0.y);
  r.h[2] = __float2bfloat16(f0.z); r.h[3] = __float2bfloat16(f0.w);
  r.h[4] = __float2bfloat16(f1.x); r.h[5] = __float2bfloat16(f1.y);
  r.h[6] = __float2bfloat16(f1.z); r.h[7] = __float2bfloat16(f1.w);
  return r.u;
}

// ----------------------------------------------------------------------------
// One-shot fp32->bf16 conversion of x, W_attn, W_proj (8 elems/thread).
// ----------------------------------------------------------------------------
__global__ __launch_bounds__(256) void convert3(
    const void* __restrict__ x, const void* __restrict__ wa,
    const void* __restrict__ wp, bf16* __restrict__ xb, bf16* __restrict__ wab,
    bf16* __restrict__ wpb, const unsigned short* __restrict__ probe) {
  const bool f32 = detect_fp32(probe);
  int blk = blockIdx.x;
  const void* src;
  bf16* dst;
  if (blk < 4096) {
    src = x; dst = xb;
  } else if (blk < 4096 + 1536) {
    blk -= 4096; src = wa; dst = wab;
  } else {
    blk -= 4096 + 1536; src = wp; dst = wpb;
  }
  const size_t i = ((size_t)blk * 256 + threadIdx.x) * 8;
  if (f32)
    *(uint4*)(dst + i) = ld8f(src, i);
  else
    *(uint4*)(dst + i) = *(const uint4*)((const bf16*)src + i);
}

// ----------------------------------------------------------------------------
// gemm8_qkv: 8-phase 256x128 bf16 GEMM for qkv = x_bf @ wa_bf^T (round 14).
// 8 waves = 4Mx2N, per-wave 64x64 -> acc[4][4] = 64 VGPR. LDS 96 KiB.
// ----------------------------------------------------------------------------
__global__ __launch_bounds__(512, 1) void gemm8_qkv(
    const bf16* __restrict__ A, const bf16* __restrict__ Bm,
    bf16* __restrict__ q_ws, bf16* __restrict__ k_ws,
    bf16* __restrict__ v_ws) {
  __shared__ bf16 Asm[2][2][256][32];  // 64 KiB
  __shared__ bf16 Bsm[2][2][128][32];  // 32 KiB

  const int tid = threadIdx.x;
  const int lane = tid & 63;
  const int wid = tid >> 6;    // 0..7
  const int wr = wid >> 1;     // 0..3  (64-row band)
  const int wc = wid & 1;      // 0..1  (64-col band)
  const int quad = lane >> 4;  // 0..3
  const int col = lane & 15;

  // XCD-bijective swizzle on flattened 24x32 grid (768 % 8 == 0).
  const int flat = (int)blockIdx.y * 24 + (int)blockIdx.x;
  const int swz = (flat & 7) * 96 + (flat >> 3);
  const int n0 = (swz % 24) * 128;
  const int m0 = (swz / 24) * 256;
  const bool vsec = (n0 >> 10) == 2;

  constexpr int NT = 16;  // K-tiles of BK=64

  const int c0 = tid, c1 = 512 + tid;
  const int r0 = c0 >> 2, s0 = (c0 & 3) ^ ((r0 >> 1) & 3);
  const int r1 = c1 >> 2, s1 = (c1 & 3) ^ ((r1 >> 1) & 3);
  const size_t ga0 = (size_t)(m0 + r0) * 1024 + s0 * 8;
  const size_t ga1 = (size_t)(m0 + r1) * 1024 + s1 * 8;
  const int rb = tid >> 2, sb = (tid & 3) ^ ((rb >> 1) & 3);
  const size_t gb = (size_t)(n0 + rb) * 1024 + sb * 8;

  auto stageA = [&](int T, int h) {
    bf16* base = &Asm[T & 1][h][0][0];
    const int kk = T * 64 + h * 32;
    load_lds16(A + ga0 + kk, base + c0 * 8);
    load_lds16(A + ga1 + kk, base + c1 * 8);
  };
  auto stageB = [&](int T, int h) {
    bf16* base = &Bsm[T & 1][h][0][0];
    const int kk = T * 64 + h * 32;
    load_lds16(Bm + gb + kk, base + tid * 8);
  };

  const int aq = quad ^ ((col >> 1) & 3);

  f32x4 acc[4][4] = {};
  bf16x8 pA[4];

  stageA(0, 0); stageB(0, 0); stageA(0, 1); stageB(0, 1);
  stageA(1, 0); stageB(1, 0); stageA(1, 1);
  asm volatile("s_waitcnt vmcnt(5)" ::: "memory");  // tile 0 resident
  __builtin_amdgcn_s_barrier();

  for (int t = 0; t < NT; ++t) {
    const bf16* Ab = (const bf16*)Asm + (t & 1) * 16384;
    const bf16* Bb = (const bf16*)Bsm + (t & 1) * 8192;

    // phase 1: ks=0, n0-1 ; stage B1(t+1)
#pragma unroll
    for (int m = 0; m < 4; ++m)
      pA[m] = *(const bf16x8*)(Ab + (wr * 64 + m * 16 + col) * 32 + aq * 8);
    bf16x8 b0 = *(const bf16x8*)(Bb + (wc * 64 + 0 + col) * 32 + aq * 8);
    bf16x8 b1 = *(const bf16x8*)(Bb + (wc * 64 + 16 + col) * 32 + aq * 8);
    if (t + 1 < NT) stageB(t + 1, 1);
    __builtin_amdgcn_s_barrier();
    asm volatile("s_waitcnt lgkmcnt(0)" ::: "memory");
    __builtin_amdgcn_s_setprio(1);
    if (vsec) {
#pragma unroll
      for (int m = 0; m < 4; ++m) {
        acc[m][0] = __builtin_amdgcn_mfma_f32_16x16x32_bf16(b0, pA[m], acc[m][0], 0, 0, 0);
        acc[m][1] = __builtin_amdgcn_mfma_f32_16x16x32_bf16(b1, pA[m], acc[m][1], 0, 0, 0);
      }
    } else {
#pragma unroll
      for (int m = 0; m < 4; ++m) {
        acc[m][0] = __builtin_amdgcn_mfma_f32_16x16x32_bf16(pA[m], b0, acc[m][0], 0, 0, 0);
        acc[m][1] = __builtin_amdgcn_mfma_f32_16x16x32_bf16(pA[m], b1, acc[m][1], 0, 0, 0);
      }
    }
    __builtin_amdgcn_s_setprio(0);
    __builtin_amdgcn_s_barrier();

    // phase 2: ks=0, n2-3 ; stage A0(t+2)
    bf16x8 b2 = *(const bf16x8*)(Bb + (wc * 64 + 32 + col) * 32 + aq * 8);
    bf16x8 b3 = *(const bf16x8*)(Bb + (wc * 64 + 48 + col) * 32 + aq * 8);
    if (t + 2 < NT) stageA(t + 2, 0);
    __builtin_amdgcn_s_barrier();
    asm volatile("s_waitcnt lgkmcnt(0)" ::: "memory");
    __builtin_amdgcn_s_setprio(1);
    if (vsec) {
#pragma unroll
      for (int m = 0; m < 4; ++m) {
        acc[m][2] = __builtin_amdgcn_mfma_f32_16x16x32_bf16(b2, pA[m], acc[m][2], 0, 0, 0);
        acc[m][3] = __builtin_amdgcn_mfma_f32_16x16x32_bf16(b3, pA[m], acc[m][3], 0, 0, 0);
      }
    } else {
#pragma unroll
      for (int m = 0; m < 4; ++m) {
        acc[m][2] = __builtin_amdgcn_mfma_f32_16x16x32_bf16(pA[m], b2, acc[m][2], 0, 0, 0);
        acc[m][3] = __builtin_amdgcn_mfma_f32_16x16x32_bf16(pA[m], b3, acc[m][3], 0, 0, 0);
      }
    }
    __builtin_amdgcn_s_setprio(0);
    __builtin_amdgcn_s_barrier();

    // phase 3: ks=1, n0-1 ; stage B0(t+2)
    Ab += 8192;
    Bb += 4096;
#pragma unroll
    for (int m = 0; m < 4; ++m)
      pA[m] = *(const bf16x8*)(Ab + (wr * 64 + m * 16 + col) * 32 + aq * 8);
    bf16x8 b0n = *(const bf16x8*)(Bb + (wc * 64 + 0 + col) * 32 + aq * 8);
    bf16x8 b1n = *(const bf16x8*)(Bb + (wc * 64 + 16 + col) * 32 + aq * 8);
    if (t + 2 < NT) stageB(t + 2, 0);
    __builtin_amdgcn_s_barrier();
    asm volatile("s_waitcnt lgkmcnt(0)" ::: "memory");
    __builtin_amdgcn_s_setprio(1);
    if (vsec) {
#pragma unroll
      for (int m = 0; m < 4; ++m) {
        acc[m][0] = __builtin_amdgcn_mfma_f32_16x16x32_bf16(b0n, pA[m], acc[m][0], 0, 0, 0);
        acc[m][1] = __builtin_amdgcn_mfma_f32_16x16x32_bf16(b1n, pA[m], acc[m][1], 0, 0, 0);
      }
    } else {
#pragma unroll
      for (int m = 0; m < 4; ++m) {
        acc[m][0] = __builtin_amdgcn_mfma_f32_16x16x32_bf16(pA[m], b0n, acc[m][0], 0, 0, 0);
        acc[m][1] = __builtin_amdgcn_mfma_f32_16x16x32_bf16(pA[m], b1n, acc[m][1], 0, 0, 0);
      }
    }
    __builtin_amdgcn_s_setprio(0);
    __builtin_amdgcn_s_barrier();

    // phase 4: ks=1, n2-3 ; stage A1(t+2) ; boundary vmcnt
    bf16x8 b2n = *(const bf16x8*)(Bb + (wc * 64 + 32 + col) * 32 + aq * 8);
    bf16x8 b3n = *(const bf16x8*)(Bb + (wc * 64 + 48 + col) * 32 + aq * 8);
    if (t + 2 < NT) stageA(t + 2, 1);
    __builtin_amdgcn_s_barrier();
    asm volatile("s_waitcnt lgkmcnt(0)" ::: "memory");
    __builtin_amdgcn_s_setprio(1);
    if (vsec) {
#pragma unroll
      for (int m = 0; m < 4; ++m) {
        acc[m][2] = __builtin_amdgcn_mfma_f32_16x16x32_bf16(b2n, pA[m], acc[m][2], 0, 0, 0);
        acc[m][3] = __builtin_amdgcn_mfma_f32_16x16x32_bf16(b3n, pA[m], acc[m][3], 0, 0, 0);
      }
    } else {
#pragma unroll
      for (int m = 0; m < 4; ++m) {
        acc[m][2] = __builtin_amdgcn_mfma_f32_16x16x32_bf16(pA[m], b2n, acc[m][2], 0, 0, 0);
        acc[m][3] = __builtin_amdgcn_mfma_f32_16x16x32_bf16(pA[m], b3n, acc[m][3], 0, 0, 0);
      }
    }
    __builtin_amdgcn_s_setprio(0);
    if (t + 2 < NT)
      asm volatile("s_waitcnt vmcnt(5)" ::: "memory");
    else
      asm volatile("s_waitcnt vmcnt(0)" ::: "memory");
    __builtin_amdgcn_s_barrier();
  }

  const int b = m0 >> 11;
  if (!vsec) {
    bf16* dst = ((n0 >> 10) == 0) ? q_ws : k_ws;
#pragma unroll
    for (int m = 0; m < 4; ++m) {
      const int mrow = (m0 & 2047) + wr * 64 + m * 16 + quad * 4;
#pragma unroll
      for (int n = 0; n < 4; ++n) {
        const int cc = (n0 & 1023) + wc * 64 + n * 16 + col;
        const int h = cc >> 6, d = cc & 63;
#pragma unroll
        for (int r = 0; r < 4; ++r)
          dst[(((size_t)b * NH_ + h) * T_ + mrow + r) * HS_ + d] =
              __float2bfloat16(acc[m][n][r]);
      }
    }
  } else {
#pragma unroll
    for (int m = 0; m < 4; ++m) {
      const int tloc = (m0 & 2047) + wr * 64 + m * 16 + col;
#pragma unroll
      for (int n = 0; n < 4; ++n) {
        const int vch = (n0 & 1023) + wc * 64 + n * 16 + quad * 4;
#pragma unroll
        for (int r = 0; r < 4; ++r) {
          const int h = (vch + r) >> 6, d = (vch + r) & 63;
          v_ws[(((size_t)b * NH_ + h) * HS_ + d) * T_ + tloc] =
              __float2bfloat16(acc[m][n][r]);
        }
      }
    }
  }
}

// ----------------------------------------------------------------------------
// gemm8_proj: 8-phase 256x128 bf16 GEMM for out = y @ W_proj^T.
// A = y in head layout q_ws[b][h][t][64] (k = h*64+d; head = k-tile index T
// since h*32+s*8 <= 56). B = wp_bf [1024][1024]. Grid 8x32 = 256 blocks.
// Output fp32 or bf16 (probed), row-major [8192][1024].
// ----------------------------------------------------------------------------
__global__ __launch_bounds__(512, 1) void gemm8_proj(
    const bf16* __restrict__ A, const bf16* __restrict__ Bm,
    void* __restrict__ C, const unsigned short* __restrict__ out_probe) {
  __shared__ bf16 Asm[2][2][256][32];  // 64 KiB
  __shared__ bf16 Bsm[2][2][128][32];  // 32 KiB

  const bool f32out = detect_fp32(out_probe);

  const int tid = threadIdx.x;
  const int lane = tid & 63;
  const int wid = tid >> 6;
  const int wr = wid >> 1;     // 0..3
  const int wc = wid & 1;      // 0..1
  const int quad = lane >> 4;
  const int col = lane & 15;

  // XCD-bijective swizzle on flattened 8x32 grid (256 % 8 == 0).
  const int flat = (int)blockIdx.y * 8 + (int)blockIdx.x;
  const int swz = (flat & 7) * 32 + (flat >> 3);
  const int n0 = (swz % 8) * 128;
  const int m0 = (swz / 8) * 256;
  const int b = m0 >> 11;
  const int tloc0 = m0 & 2047;

  constexpr int NT = 16;

  const int c0 = tid, c1 = 512 + tid;
  const int r0 = c0 >> 2, s0 = (c0 & 3) ^ ((r0 >> 1) & 3);
  const int r1 = c1 >> 2, s1 = (c1 & 3) ^ ((r1 >> 1) & 3);
  // A per-thread offsets within a (T,h) panel: row-dependent part.
  const size_t aoff0 = (size_t)(tloc0 + r0) * 64 + s0 * 8;
  const size_t aoff1 = (size_t)(tloc0 + r1) * 64 + s1 * 8;
  const size_t abase = (size_t)b * NH_ * T_ * HS_;  // + T*131072 per k-tile
  const int rb = tid >> 2, sb = (tid & 3) ^ ((rb >> 1) & 3);
  const size_t gb = (size_t)(n0 + rb) * 1024 + sb * 8;

  auto stageA = [&](int T, int h) {
    bf16* base = &Asm[T & 1][h][0][0];
    const size_t pan = abase + (size_t)T * (T_ * HS_) + h * 32;
    load_lds16(A + pan + aoff0, base + c0 * 8);
    load_lds16(A + pan + aoff1, base + c1 * 8);
  };
  auto stageB = [&](int T, int h) {
    bf16* base = &Bsm[T & 1][h][0][0];
    const int kk = T * 64 + h * 32;
    load_lds16(Bm + gb + kk, base + tid * 8);
  };

  const int aq = quad ^ ((col >> 1) & 3);

  f32x4 acc[4][4] = {};
  bf16x8 pA[4];

  stageA(0, 0); stageB(0, 0); stageA(0, 1); stageB(0, 1);
  stageA(1, 0); stageB(1, 0); stageA(1, 1);
  asm volatile("s_waitcnt vmcnt(5)" ::: "memory");
  __builtin_amdgcn_s_barrier();

  for (int t = 0; t < NT; ++t) {
    const bf16* Ab = (const bf16*)Asm + (t & 1) * 16384;
    const bf16* Bb = (const bf16*)Bsm + (t & 1) * 8192;

    // phase 1
#pragma unroll
    for (int m = 0; m < 4; ++m)
      pA[m] = *(const bf16x8*)(Ab + (wr * 64 + m * 16 + col) * 32 + aq * 8);
    bf16x8 b0 = *(const bf16x8*)(Bb + (wc * 64 + 0 + col) * 32 + aq * 8);
    bf16x8 b1 = *(const bf16x8*)(Bb + (wc * 64 + 16 + col) * 32 + aq * 8);
    if (t + 1 < NT) stageB(t + 1, 1);
    __builtin_amdgcn_s_barrier();
    asm volatile("s_waitcnt lgkmcnt(0)" ::: "memory");
    __builtin_amdgcn_s_setprio(1);
#pragma unroll
    for (int m = 0; m < 4; ++m) {
      acc[m][0] = __builtin_amdgcn_mfma_f32_16x16x32_bf16(pA[m], b0, acc[m][0], 0, 0, 0);
      acc[m][1] = __builtin_amdgcn_mfma_f32_16x16x32_bf16(pA[m], b1, acc[m][1], 0, 0, 0);
    }
    __builtin_amdgcn_s_setprio(0);
    __builtin_amdgcn_s_barrier();

    // phase 2
    bf16x8 b2 = *(const bf16x8*)(Bb + (wc * 64 + 32 + col) * 32 + aq * 8);
    bf16x8 b3 = *(const bf16x8*)(Bb + (wc * 64 + 48 + col) * 32 + aq * 8);
    if (t + 2 < NT) stageA(t + 2, 0);
    __builtin_amdgcn_s_barrier();
    asm volatile("s_waitcnt lgkmcnt(0)" ::: "memory");
    __builtin_amdgcn_s_setprio(1);
#pragma unroll
    for (int m = 0; m < 4; ++m) {
      acc[m][2] = __builtin_amdgcn_mfma_f32_16x16x32_bf16(pA[m], b2, acc[m][2], 0, 0, 0);
      acc[m][3] = __builtin_amdgcn_mfma_f32_16x16x32_bf16(pA[m], b3, acc[m][3], 0, 0, 0);
    }
    __builtin_amdgcn_s_setprio(0);
    __builtin_amdgcn_s_barrier();

    // phase 3
    Ab += 8192;
    Bb += 4096;
#pragma unroll
    for (int m = 0; m < 4; ++m)
      pA[m] = *(const bf16x8*)(Ab + (wr * 64 + m * 16 + col) * 32 + aq * 8);
    b0 = *(const bf16x8*)(Bb + (wc * 64 + 0 + col) * 32 + aq * 8);
    b1 = *(const bf16x8*)(Bb + (wc * 64 + 16 + col) * 32 + aq * 8);
    if (t + 2 < NT) stageB(t + 2, 0);
    __builtin_amdgcn_s_barrier();
    asm volatile("s_waitcnt lgkmcnt(0)" ::: "memory");
    __builtin_amdgcn_s_setprio(1);
#pragma unroll
    for (int m = 0; m < 4; ++m) {
      acc[m][0] = __builtin_amdgcn_mfma_f32_16x16x32_bf16(pA[m], b0, acc[m][0], 0, 0, 0);
      acc[m][1] = __builtin_amdgcn_mfma_f32_16x16x32_bf16(pA[m], b1, acc[m][1], 0, 0, 0);
    }
    __builtin_amdgcn_s_setprio(0);
    __builtin_amdgcn_s_barrier();

    // phase 4
    b2 = *(const bf16x8*)(Bb + (wc * 64 + 32 + col) * 32 + aq * 8);
    b3 = *(const bf16x8*)(Bb + (wc * 64 + 48 + col) * 32 + aq * 8);
    if (t + 2 < NT) stageA(t + 2, 1);
    __builtin_amdgcn_s_barrier();
    asm volatile("s_waitcnt lgkmcnt(0)" ::: "memory");
    __builtin_amdgcn_s_setprio(1);
#pragma unroll
    for (int m = 0; m < 4; ++m) {
      acc[m][2] = __builtin_amdgcn_mfma_f32_16x16x32_bf16(pA[m], b2, acc[m][2], 0, 0, 0);
      acc[m][3] = __builtin_amdgcn_mfma_f32_16x16x32_bf16(pA[m], b3, acc[m][3], 0, 0, 0);
    }
    __builtin_amdgcn_s_setprio(0);
    if (t + 2 < NT)
      asm volatile("s_waitcnt vmcnt(5)" ::: "memory");
    else
      asm volatile("s_waitcnt vmcnt(0)" ::: "memory");
    __builtin_amdgcn_s_barrier();
  }

  // epilogue: row-major [8192][1024], fp32 or bf16
#pragma unroll
  for (int m = 0; m < 4; ++m) {
    const int mrow = m0 + wr * 64 + m * 16 + quad * 4;
#pragma unroll
    for (int n = 0; n < 4; ++n) {
      const int ncol = n0 + wc * 64 + n * 16 + col;
#pragma unroll
      for (int r = 0; r < 4; ++r) {
        if (f32out)
          ((float*)C)[(size_t)(mrow + r) * 1024 + ncol] = acc[m][n][r];
        else
          ((bf16*)C)[(size_t)(mrow + r) * 1024 + ncol] =
              __float2bfloat16(acc[m][n][r]);
      }
    }
  }
}

// ----------------------------------------------------------------------------
// gemm_bt (round 11): 128x128 tile, BK=32, double-buffered LDS, 2-phase.
// fp32 no-workspace fallback only.
// ----------------------------------------------------------------------------
template <int IN_MODE, int OUT_MODE>
__global__ __launch_bounds__(256, 2) void gemm_bt(
    const void* __restrict__ A, const void* __restrict__ B, void* __restrict__ C,
    bf16* __restrict__ k_ws, bf16* __restrict__ v_ws,
    const unsigned short* __restrict__ in_probe,
    const unsigned short* __restrict__ out_probe, int M, int N, int K) {
  __shared__ bf16 As[2][128 * 32];
  __shared__ bf16 Bs[2][128 * 32];

  const bool f32b = in_probe ? detect_fp32(in_probe) : false;
  const bool f32a = (IN_MODE == 0) && f32b;
  const bool f32out =
      (OUT_MODE == 0) && (out_probe ? detect_fp32(out_probe) : false);

  const int tid = threadIdx.x;
  const int lane = tid & 63;
  const int wid = tid >> 6;
  const int quad = lane >> 4;
  const int col = lane & 15;
  const int m0 = blockIdx.y * 128;
  const int n0 = blockIdx.x * 128;
  const int wm = (wid >> 1) * 64;
  const int wn = (wid & 1) * 64;
  const bool vsec = (OUT_MODE == 1) && ((n0 >> 10) == 2);

  const size_t arow = (size_t)(m0 + (tid >> 2));
  const size_t brow = (size_t)(n0 + (tid >> 2));
  const int chunk = (tid & 3) * 8;
  const size_t astep = (IN_MODE == 0) ? (size_t)64 * K : (size_t)64 * HS_;

  f32x4 acc[4][4] = {};

  auto a_ptr = [&](int k0) -> const bf16* {
    if (IN_MODE == 0) return (const bf16*)A + arow * K + chunk + k0;
    const int b = m0 >> 11;
    const int tloc = (m0 & 2047) + (tid >> 2);
    return (const bf16*)A +
           ((((size_t)b * NH_) + (k0 >> 6)) * T_ + tloc) * HS_ + (k0 & 32) +
           chunk;
  };

  if (f32a) {
    uint4 a0 = ld8f(A, arow * K + chunk);
    uint4 a1 = ld8f(A, (arow + 64) * K + chunk);
    *(uint4*)(&As[0][0] + tid * 8) = a0;
    *(uint4*)(&As[0][0] + 2048 + tid * 8) = a1;
  } else {
    const bf16* ap = a_ptr(0);
    load_lds16(ap, &As[0][0] + tid * 8);
    load_lds16(ap + astep, &As[0][0] + 2048 + tid * 8);
  }
  if (f32b) {
    uint4 b0 = ld8f(B, brow * K + chunk);
    uint4 b1 = ld8f(B, (brow + 64) * K + chunk);
    *(uint4*)(&Bs[0][0] + tid * 8) = b0;
    *(uint4*)(&Bs[0][0] + 2048 + tid * 8) = b1;
  } else {
    load_lds16((const bf16*)B + brow * K + chunk, &Bs[0][0] + tid * 8);
    load_lds16((const bf16*)B + (brow + 64) * K + chunk,
               &Bs[0][0] + 2048 + tid * 8);
  }
  __syncthreads();

  int cur = 0;
  for (int k0 = 0; k0 < K; k0 += 32) {
    const int kn = k0 + 32;
    const bool hasn = kn < K;
    const int nxt = cur ^ 1;

    uint4 a0, a1, b0, b1;
    bool wra = false, wrb = false;
    if (hasn) {
      if (f32a) {
        a0 = ld8f(A, arow * K + chunk + kn);
        a1 = ld8f(A, (arow + 64) * K + chunk + kn);
        wra = true;
      } else {
        const bf16* ap = a_ptr(kn);
        load_lds16(ap, &As[nxt][0] + tid * 8);
        load_lds16(ap + astep, &As[nxt][0] + 2048 + tid * 8);
      }
      if (f32b) {
        b0 = ld8f(B, brow * K + chunk + kn);
        b1 = ld8f(B, (brow + 64) * K + chunk + kn);
        wrb = true;
      } else {
        load_lds16((const bf16*)B + brow * K + chunk + kn,
                   &Bs[nxt][0] + tid * 8);
        load_lds16((const bf16*)B + (brow + 64) * K + chunk + kn,
                   &Bs[nxt][0] + 2048 + tid * 8);
      }
    }

    bf16x8 af[4], bfr[4];
#pragma unroll
    for (int t = 0; t < 4; ++t) {
      af[t] = *(const bf16x8*)(&As[cur][0] + (wm + t * 16 + col) * 32 + quad * 8);
      bfr[t] = *(const bf16x8*)(&Bs[cur][0] + (wn + t * 16 + col) * 32 + quad * 8);
    }
    if (vsec) {
#pragma unroll
      for (int tm = 0; tm < 4; ++tm)
#pragma unroll
        for (int tn = 0; tn < 4; ++tn)
          acc[tm][tn] = __builtin_amdgcn_mfma_f32_16x16x32_bf16(
              bfr[tn], af[tm], acc[tm][tn], 0, 0, 0);
    } else {
#pragma unroll
      for (int tm = 0; tm < 4; ++tm)
#pragma unroll
        for (int tn = 0; tn < 4; ++tn)
          acc[tm][tn] = __builtin_amdgcn_mfma_f32_16x16x32_bf16(
              af[tm], bfr[tn], acc[tm][tn], 0, 0, 0);
    }

    if (wra) {
      *(uint4*)(&As[nxt][0] + tid * 8) = a0;
      *(uint4*)(&As[nxt][0] + 2048 + tid * 8) = a1;
    }
    if (wrb) {
      *(uint4*)(&Bs[nxt][0] + tid * 8) = b0;
      *(uint4*)(&Bs[nxt][0] + 2048 + tid * 8) = b1;
    }
    __syncthreads();
    cur = nxt;
  }

  if (OUT_MODE == 0) {
#pragma unroll
    for (int tm = 0; tm < 4; ++tm) {
      const int mrow = m0 + wm + tm * 16 + quad * 4;
#pragma unroll
      for (int tn = 0; tn < 4; ++tn) {
        const int ncol = n0 + wn + tn * 16 + col;
#pragma unroll
        for (int r = 0; r < 4; ++r) {
          if (f32out)
            ((float*)C)[(size_t)(mrow + r) * N + ncol] = acc[tm][tn][r];
          else
            ((bf16*)C)[(size_t)(mrow + r) * N + ncol] =
                __float2bfloat16(acc[tm][tn][r]);
        }
      }
    }
  } else if (vsec) {
    const int b = m0 >> 11;
#pragma unroll
    for (int tm = 0; tm < 4; ++tm) {
      const int tloc = (m0 & 2047) + wm + tm * 16 + col;
#pragma unroll
      for (int tn = 0; tn < 4; ++tn) {
        const int vch = (n0 & (C_ - 1)) + wn + tn * 16 + quad * 4;
#pragma unroll
        for (int r = 0; r < 4; ++r) {
          const int h = (vch + r) >> 6, d = (vch + r) & 63;
          v_ws[(((size_t)b * NH_ + h) * HS_ + d) * T_ + tloc] =
              __float2bfloat16(acc[tm][tn][r]);
        }
      }
    }
  } else {
    const int sect = n0 >> 10;  // 0:q 1:k
    bf16* dst = (sect == 0) ? (bf16*)C : k_ws;
#pragma unroll
    for (int tm = 0; tm < 4; ++tm) {
      const int mrow = m0 + wm + tm * 16 + quad * 4;
#pragma unroll
      for (int tn = 0; tn < 4; ++tn) {
        const int c = (n0 + wn + tn * 16 + col) & (C_ - 1);
        const int h = c >> 6, d = c & 63;
#pragma unroll
        for (int r = 0; r < 4; ++r) {
          const int t = (mrow + r) & (T_ - 1);
          const int b = (mrow + r) >> 11;
          dst[(((size_t)b * NH_ + h) * T_ + t) * HS_ + d] =
              __float2bfloat16(acc[tm][tn][r]);
        }
      }
    }
  }
}

// ----------------------------------------------------------------------------
// MFMA flash attention (causal), fixed-max softmax, split-K (round 10).
// K/V staged via global_load_lds into linear [2][64][64] dbuf (round 15).
// ROUND 16: Ps stride 64 + 16B-slot XOR (phys = logical ^ (row&7)); LDS
// 49152 total -> 3 blocks/CU; launch_bounds(256,3).
// ----------------------------------------------------------------------------
template <int SPLIT>
__global__ __launch_bounds__(256, 3) void attn(
    bf16* qy, const bf16* __restrict__ kws, const bf16* __restrict__ vws,
    float* __restrict__ po, float* __restrict__ pl) {
  __shared__ bf16 Ks[2][64][64];    // [buf][key][d], slot-XOR swizzled
  __shared__ bf16 Vs[2][64][64];    // [buf][d][key], slot-XOR swizzled
  __shared__ bf16 Ps[4][32 * 64];   // per-wave P [32 q][64 k], slot-XOR

  const int tid = threadIdx.x;
  const int lane = tid & 63;
  const int w = tid >> 6;
  const int quad = lane >> 4;
  const int col = lane & 15;
  const int x = (int)blockIdx.x;

  int qb, ck;
  if (SPLIT) {
    const unsigned long long lo = 0xC4D5E6F7FEDCBA98ULL;  // qb nibbles x0..15
    const unsigned int hi = 0xB3A29180u;                  // qb nibbles x16..23
    const unsigned int cmask = 0x00AAAA00u;               // chunk bit per x
    qb = (x < 16) ? (int)((lo >> (4 * x)) & 15)
                  : (int)((hi >> (4 * (x - 16))) & 15);
    ck = (int)((cmask >> x) & 1);
  } else {
    const int gx = (int)gridDim.x;  // 16
    const int hx = gx >> 1;
    qb = (x < hx) ? (gx - 1 - x) : (x - hx);
    ck = 0;
  }

  const int bh = blockIdx.y;
  const size_t head_off = (size_t)bh * T_ * HS_;

  const int ntall = 2 * (qb + 1);
  const int kt0 = SPLIT ? ck * 16 : 0;
  const int ntiles = SPLIT ? min(ntall - kt0, 16) : ntall;

  const int qrow = qb * 128 + w * 32 + col;
  const bf16* qp = qy + head_off + (size_t)qrow * HS_ + quad * 8;
  bf16x8 qf0a = *(const bf16x8*)(qp);
  bf16x8 qf1a = *(const bf16x8*)(qp + 32);
  bf16x8 qf0b = *(const bf16x8*)(qp + 16 * HS_);
  bf16x8 qf1b = *(const bf16x8*)(qp + 16 * HS_ + 32);
#pragma unroll
  for (int j = 0; j < 8; ++j) {
    qf0a[j] = (__bf16)((float)qf0a[j] * SCALE_LOG2E);
    qf1a[j] = (__bf16)((float)qf1a[j] * SCALE_LOG2E);
    qf0b[j] = (__bf16)((float)qf0b[j] * SCALE_LOG2E);
    qf1b[j] = (__bf16)((float)qf1b[j] * SCALE_LOG2E);
  }

  bf16x8 onesf;
#pragma unroll
  for (int j = 0; j < 8; ++j) onesf[j] = (__bf16)1.0f;

  f32x4 oa[4] = {}, ob[4] = {};
  f32x4 lacca = {}, laccb = {};

  bf16* pw = &Ps[w][0];

  // ---- gload_lds staging map: chunk c covers (row=c>>3, slot=c&7) of a
  // 64x128B tile; source slot pre-XOR'd by row&7 (dest is linear, rule #21).
  const int srow = tid >> 3;
  const int ssl = (tid & 7) ^ (srow & 7);
  const size_t kb0 = head_off + (size_t)(kt0 * 64 + srow) * HS_ + ssl * 8;
  const size_t kb1 = kb0 + (size_t)32 * HS_;
  const size_t vb0 = ((size_t)bh * HS_ + srow) * T_ + kt0 * 64 + ssl * 8;
  const size_t vb1 = vb0 + (size_t)32 * T_;

  auto stageKV = [&](int kt, int buf) {  // kt is LOCAL tile index
    load_lds16(kws + kb0 + (size_t)kt * (64 * HS_), &Ks[buf][0][0] + tid * 8);
    load_lds16(kws + kb1 + (size_t)kt * (64 * HS_),
               &Ks[buf][0][0] + (256 + tid) * 8);
    load_lds16(vws + vb0 + kt * 64, &Vs[buf][0][0] + tid * 8);
    load_lds16(vws + vb1 + kt * 64, &Vs[buf][0][0] + (256 + tid) * 8);
  };

  const int c7 = col & 7;  // read/write slot XOR key (row&7 == col&7)

  const int qga = qb * 128 + w * 32 + col;
  const int diag_start = 2 * qb;

  stageKV(0, 0);

  for (int kt = 0; kt < ntiles; ++kt) {
    const int cur = kt & 1;
    const int ktg = kt0 + kt;
    const int k0 = ktg * 64;

    if (kt + 1 < ntiles) {
      stageKV(kt + 1, cur ^ 1);
      asm volatile("s_waitcnt vmcnt(4)" ::: "memory");  // tile kt resident
    } else {
      asm volatile("s_waitcnt vmcnt(0)" ::: "memory");
    }
    __builtin_amdgcn_s_barrier();

    const bf16* kb = &Ks[cur][0][0];
    const bf16* vb = &Vs[cur][0][0];

    // ---- S^T - 32 = (K Q^T) - 32 : lane -> (key=quad*4+r, q=col) ----
    f32x4 sa[4], sb[4];
#pragma unroll
    for (int nt = 0; nt < 4; ++nt) {
      const bf16* kp = kb + (nt * 16 + col) * 64;
      bf16x8 kf0 = *(const bf16x8*)(kp + ((quad ^ c7) * 8));
      bf16x8 kf1 = *(const bf16x8*)(kp + (((quad + 4) ^ c7) * 8));
      f32x4 a = {-32.0f, -32.0f, -32.0f, -32.0f};
      a = __builtin_amdgcn_mfma_f32_16x16x32_bf16(kf0, qf0a, a, 0, 0, 0);
      a = __builtin_amdgcn_mfma_f32_16x16x32_bf16(kf1, qf1a, a, 0, 0, 0);
      sa[nt] = a;
      f32x4 b = {-32.0f, -32.0f, -32.0f, -32.0f};
      b = __builtin_amdgcn_mfma_f32_16x16x32_bf16(kf0, qf0b, b, 0, 0, 0);
      b = __builtin_amdgcn_mfma_f32_16x16x32_bf16(kf1, qf1b, b, 0, 0, 0);
      sb[nt] = b;
    }

    // ---- causal mask (only tiles overlapping the diagonal) ----
    if (ktg >= diag_start) {
#pragma unroll
      for (int nt = 0; nt < 4; ++nt) {
        const int key = k0 + nt * 16 + quad * 4;
#pragma unroll
        for (int r = 0; r < 4; ++r) {
          if (key + r > qga) sa[nt][r] = NEG_BIG;
          if (key + r > qga + 16) sb[nt][r] = NEG_BIG;
        }
      }
    }

    // ---- P = exp2(S-32): packed b64 writes to slot-XOR'd Ps ----
    // logical 16B slot for (nt,quad) = 2*nt + (quad>>1); inner b64 = quad&1;
    // physical slot = logical ^ (row&7), row&7 == col&7 for both subtiles.
#pragma unroll
    for (int nt = 0; nt < 4; ++nt) {
      union { ushort u[4]; uint2 v; } pa, pb;
#pragma unroll
      for (int r = 0; r < 4; ++r) {
        pa.u[r] = __bfloat16_as_ushort(__float2bfloat16(exp2f(sa[nt][r])));
        pb.u[r] = __bfloat16_as_ushort(__float2bfloat16(exp2f(sb[nt][r])));
      }
      const int off = (((2 * nt + (quad >> 1)) ^ c7) << 3) + ((quad & 1) << 2);
      *(uint2*)(pw + col * 64 + off) = pa.v;
      *(uint2*)(pw + (col + 16) * 64 + off) = pb.v;
    }

    __asm__ __volatile__("s_waitcnt lgkmcnt(0)" ::: "memory");  // P visible

    // ---- O += P V ; l += P*ones (V-frags shared across subtiles) ----
#pragma unroll
    for (int half = 0; half < 2; ++half) {
      const int ps = ((half * 4 + quad) ^ c7) << 3;  // physical 16B slot
      bf16x8 pfa = *(const bf16x8*)(pw + col * 64 + ps);
      bf16x8 pfb = *(const bf16x8*)(pw + (col + 16) * 64 + ps);
      lacca = __builtin_amdgcn_mfma_f32_16x16x32_bf16(pfa, onesf, lacca, 0, 0, 0);
      laccb = __builtin_amdgcn_mfma_f32_16x16x32_bf16(pfb, onesf, laccb, 0, 0, 0);
#pragma unroll
      for (int dt = 0; dt < 4; ++dt) {
        const bf16* vp = vb + (dt * 16 + col) * 64;
        bf16x8 vf = *(const bf16x8*)(vp + (((half * 4 + quad) ^ c7) * 8));
        oa[dt] = __builtin_amdgcn_mfma_f32_16x16x32_bf16(pfa, vf, oa[dt], 0, 0, 0);
        ob[dt] = __builtin_amdgcn_mfma_f32_16x16x32_bf16(pfb, vf, ob[dt], 0, 0, 0);
      }
    }
    __builtin_amdgcn_s_barrier();  // all reads of buf[cur] complete
  }

  const bool dosplit = SPLIT && (qb >= 8);
  if (!dosplit) {
    float inva[4], invb[4];
#pragma unroll
    for (int r = 0; r < 4; ++r) {
      inva[r] = 1.0f / lacca[r];
      invb[r] = 1.0f / laccb[r];
    }
#pragma unroll
    for (int dt = 0; dt < 4; ++dt)
#pragma unroll
      for (int r = 0; r < 4; ++r) {
        const int qa = qb * 128 + w * 32 + quad * 4 + r;
        qy[head_off + (size_t)qa * HS_ + dt * 16 + col] =
            __float2bfloat16(oa[dt][r] * inva[r]);
        qy[head_off + (size_t)(qa + 16) * HS_ + dt * 16 + col] =
            __float2bfloat16(ob[dt][r] * invb[r]);
      }
  } else {
    const int slot = ((qb - 8) * 64 + bh) * 2 + ck;
    float* o = po + (size_t)slot * (128 * 64);
#pragma unroll
    for (int dt = 0; dt < 4; ++dt)
#pragma unroll
      for (int r = 0; r < 4; ++r) {
        const int qa = w * 32 + quad * 4 + r;
        o[(size_t)qa * 64 + dt * 16 + col] = oa[dt][r];
        o[(size_t)(qa + 16) * 64 + dt * 16 + col] = ob[dt][r];
      }
    if (col == 0) {
      float* lp = pl + (size_t)slot * 128;
#pragma unroll
      for (int r = 0; r < 4; ++r) {
        lp[w * 32 + quad * 4 + r] = lacca[r];
        lp[w * 32 + 16 + quad * 4 + r] = laccb[r];
      }
    }
  }
}

// ----------------------------------------------------------------------------
// Combine: for qb>=8, y = (O0+O1)/(l0+l1).
// ----------------------------------------------------------------------------
__global__ __launch_bounds__(256) void attn_combine(
    bf16* __restrict__ qy, const float* __restrict__ po,
    const float* __restrict__ pl) {
  const int qb = 8 + (int)blockIdx.x;  // 8..15
  const int bh = (int)blockIdx.y;
  const int pair = ((qb - 8) * 64 + bh) * 2;
  const float* o0 = po + (size_t)pair * (128 * 64);
  const float* o1 = o0 + 128 * 64;
  const float* l0 = pl + (size_t)pair * 128;
  const float* l1 = l0 + 128;
  const int q = threadIdx.x >> 1;
  const int d0 = (threadIdx.x & 1) * 32;
  const float inv = 1.0f / (l0[q] + l1[q]);
  const size_t base =
      (size_t)bh * T_ * HS_ + (size_t)(qb * 128 + q) * HS_ + d0;
  const size_t ob = (size_t)q * 64 + d0;
#pragma unroll
  for (int j0 = 0; j0 < 32; j0 += 8) {
    union { bf16 h[8]; uint4 u; } out;
#pragma unroll
    for (int j = 0; j < 8; ++j)
      out.h[j] = __float2bfloat16((o0[ob + j0 + j] + o1[ob + j0 + j]) * inv);
    *(uint4*)(qy + base + j0) = out.u;
  }
}

// ----------------------------------------------------------------------------
extern "C" void kernel_launch(void* const* d_in, const int* in_sizes, int n_in,
                              void* d_out, int out_size, void* d_ws, size_t ws_size,
                              hipStream_t stream) {
  const void* x = d_in[0];       // [4,2048,1024] fp32 (probed)
  const void* W_attn = d_in[1];  // [3072,1024]
  const void* W_proj = d_in[2];  // [1024,1024]
  const unsigned short* probe = (const unsigned short*)d_in[0];
  // d_in[3..6]: dead code in the reference.

  const size_t qkv_elems = (size_t)B_ * NH_ * T_ * HS_;  // 8388608
  const size_t xe = (size_t)B_ * T_ * C_;                // 8388608
  const size_t wae = (size_t)3 * C_ * C_;                // 3145728
  const size_t wpe = (size_t)C_ * C_;                    // 1048576

  bf16* q_ws = (bf16*)d_ws;
  bf16* k_ws = q_ws + qkv_elems;
  bf16* v_ws = k_ws + qkv_elems;
  bf16* x_bf = v_ws + qkv_elems;
  bf16* wa_bf = x_bf + xe;
  bf16* wp_bf = wa_bf + wae;
  const size_t need = (3 * qkv_elems + xe + wae + wpe) * sizeof(bf16);  // 72 MiB

  // split-K partials: 1024 slots x (128x64 O + 128 l) f32 = 32.5 MiB
  float* po = (float*)(wp_bf + wpe);
  float* pl = po + (size_t)1024 * 128 * 64;
  const size_t need2 =
      need + ((size_t)1024 * 128 * 64 + (size_t)1024 * 128) * sizeof(float);

  const int M = B_ * T_;  // 8192

  if (ws_size >= need) {
    convert3<<<6144, 256, 0, stream>>>(x, W_attn, W_proj, x_bf, wa_bf, wp_bf,
                                       probe);
    gemm8_qkv<<<dim3(24, 32), 512, 0, stream>>>(x_bf, wa_bf, q_ws, k_ws, v_ws);
    if (ws_size >= need2) {
      attn<1><<<dim3(24, B_ * NH_), 256, 0, stream>>>(q_ws, k_ws, v_ws, po, pl);
      attn_combine<<<dim3(8, B_ * NH_), 256, 0, stream>>>(q_ws, po, pl);
    } else {
      attn<0><<<dim3(T_ / 128, B_ * NH_), 256, 0, stream>>>(q_ws, k_ws, v_ws,
                                                            nullptr, nullptr);
    }
    gemm8_proj<<<dim3(8, 32), 512, 0, stream>>>(q_ws, wp_bf, d_out, probe);
  } else {
    gemm_bt<0, 1><<<dim3(3 * C_ / 128, M / 128), 256, 0, stream>>>(
        x, W_attn, q_ws, k_ws, v_ws, probe, nullptr, M, 3 * C_, C_);
    attn<0><<<dim3(T_ / 128, B_ * NH_), 256, 0, stream>>>(q_ws, k_ws, v_ws,
                                                          nullptr, nullptr);
    gemm_bt<1, 0><<<dim3(C_ / 128, M / 128), 256, 0, stream>>>(
        q_ws, W_proj, d_out, nullptr, nullptr, probe, probe, M, C_, C_);
  }
}